// Round 9
// baseline (387.669 us; speedup 1.0000x reference)
//
#include <hip/hip_runtime.h>
#include <hip/hip_bf16.h>
#include <math.h>

// ---------------------------------------------------------------------------
#define B 8
#define NP 1000
#define NK 56
#define DP 768
#define DV 43
#define DD 256
#define NT 999

typedef __attribute__((ext_vector_type(8))) short bf16x8;
typedef __attribute__((ext_vector_type(4))) float f32x4;

__device__ inline short f2bf(float x) {
    __hip_bfloat16 h = __float2bfloat16(x);
    return __builtin_bit_cast(short, h);
}

// ---------------------------------------------------------------------------
// prep: [0,96) wcvt W_prot ; [96,128) wcvt Wjp ; [128,640) fusedcvt ; 640 zero accums
// accums layout: [0..8)S [8..16)A=Sum v^2 [16..24)C=Sum v*lab [24..32)D=Sum lab^2
//                [32..40)fusedAbsRaw [40..48)groupReg
__global__ __launch_bounds__(256) void prep_kernel(
    const float* __restrict__ W_prot, short* __restrict__ Wb1,
    const float* __restrict__ Wjp, short* __restrict__ Wb2,
    const float* __restrict__ fusedM, short* __restrict__ fMb,
    float* __restrict__ accums) {
    int blk = blockIdx.x, tid = threadIdx.x;
    if (blk < 96) {
        int idx = blk * 256 + tid;                 // (768/8)*256 exact
        int koct = idx / DD, n = idx % DD;
        bf16x8 v;
        #pragma unroll
        for (int e = 0; e < 8; ++e)
            v[e] = f2bf(W_prot[(size_t)(koct * 8 + e) * DD + n]);
        *reinterpret_cast<bf16x8*>(Wb1 + (size_t)idx * 8) = v;
    } else if (blk < 128) {
        int idx = (blk - 96) * 256 + tid;          // (256/8)*256 exact
        int koct = idx / DD, n = idx % DD;
        bf16x8 v;
        #pragma unroll
        for (int e = 0; e < 8; ++e)
            v[e] = f2bf(Wjp[(size_t)(koct * 8 + e) * DD + n]);
        *reinterpret_cast<bf16x8*>(Wb2 + (size_t)idx * 8) = v;
    } else if (blk < 640) {
        int idx = (blk - 128) * 256 + tid;         // 128*1024 exact
        int oct = idx >> 10, t = idx & 1023;
        bf16x8 v;
        #pragma unroll
        for (int e = 0; e < 8; ++e) {
            int i = oct * 8 + e;
            float x = (t < NT && i < NP) ? fusedM[(size_t)t * NP + i] : 0.f;
            v[e] = f2bf(x);
        }
        *reinterpret_cast<bf16x8*>(fMb + (size_t)idx * 8) = v;
    } else {
        if (tid < 48) accums[tid] = 0.f;
    }
}

// ---------------------------------------------------------------------------
// MFMA GEMM: C = act_in(A) @ Wb + bias. Block 4 waves; tile 32(M) x 128(N).
template<bool RELU_IN>
__global__ __launch_bounds__(256) void mfma_gemm_bias_kernel(
    const float* __restrict__ A, const short* __restrict__ Wb,
    const float* __restrict__ bias, float* __restrict__ C,
    int M, int N, int K) {
    int tid = threadIdx.x;
    int lane = tid & 63, w = tid >> 6;
    int m0 = blockIdx.x * 32 + (w >> 1) * 16;
    int n0 = blockIdx.y * 128 + (w & 1) * 64;
    int lrow = lane & 15, lk = lane >> 4;
    f32x4 acc[4] = {{0.f,0.f,0.f,0.f},{0.f,0.f,0.f,0.f},
                    {0.f,0.f,0.f,0.f},{0.f,0.f,0.f,0.f}};
    const float* arow = A + (size_t)(m0 + lrow) * K + lk * 8;
    for (int k0 = 0; k0 < K; k0 += 32) {
        f32x4 a0 = *reinterpret_cast<const f32x4*>(arow + k0);
        f32x4 a1 = *reinterpret_cast<const f32x4*>(arow + k0 + 4);
        bf16x8 af;
        #pragma unroll
        for (int e = 0; e < 4; ++e) {
            float v0 = a0[e], v1 = a1[e];
            if (RELU_IN) { v0 = fmaxf(v0, 0.f); v1 = fmaxf(v1, 0.f); }
            af[e] = f2bf(v0); af[4 + e] = f2bf(v1);
        }
        const short* bbase = Wb + ((size_t)((k0 >> 3) + lk) * N + n0 + lrow) * 8;
        #pragma unroll
        for (int nt = 0; nt < 4; ++nt) {
            bf16x8 bf = *reinterpret_cast<const bf16x8*>(bbase + nt * 128);
            acc[nt] = __builtin_amdgcn_mfma_f32_16x16x32_bf16(af, bf, acc[nt], 0, 0, 0);
        }
    }
    #pragma unroll
    for (int nt = 0; nt < 4; ++nt) {
        int col = n0 + nt * 16 + lrow;
        float bv = bias[col];
        #pragma unroll
        for (int r = 0; r < 4; ++r) {
            int row = m0 + lk * 4 + r;
            C[(size_t)row * N + col] = acc[nt][r] + bv;
        }
    }
}

// ---------------------------------------------------------------------------
template<bool RELU_IN>
__global__ __launch_bounds__(256) void rowmm_kernel(
    const float* __restrict__ in, const float* __restrict__ W,
    const float* __restrict__ bias, float* __restrict__ out, int K) {
    extern __shared__ float srow[];
    int r = blockIdx.x, d = threadIdx.x;
    for (int k = d; k < K; k += 256) {
        float v = in[(size_t)r * K + k];
        if (RELU_IN) v = fmaxf(v, 0.f);
        srow[k] = v;
    }
    __syncthreads();
    float acc = bias[d];
    for (int k = 0; k < K; ++k)
        acc = fmaf(srow[k], W[(size_t)k * DD + d], acc);
    out[(size_t)r * DD + d] = acc;
}

__global__ __launch_bounds__(256) void adjmul_relu_kernel(
    const float* __restrict__ adj, const float* __restrict__ t,
    float* __restrict__ y) {
    int b = blockIdx.x / NK, i = blockIdx.x % NK, d = threadIdx.x;
    __shared__ float arow[NK];
    if (d < NK) arow[d] = adj[((size_t)b * NK + i) * NK + d];
    __syncthreads();
    float acc = 0.f;
    #pragma unroll 8
    for (int j = 0; j < NK; ++j)
        acc = fmaf(arow[j], t[((size_t)b * NK + j) * DD + d], acc);
    y[((size_t)b * NK + i) * DD + d] = fmaxf(acc, 0.f);
}

// ---------------------------------------------------------------------------
// inter_all: raw inter = sigmoid(qp.qc); accumulate S,A,C,D; s_bi raw; iTb bf16.
__global__ __launch_bounds__(256) void inter_all_kernel(
    const float* __restrict__ qp, const float* __restrict__ qc,
    const float* __restrict__ prot_inter, const float* __restrict__ exist,
    float* __restrict__ inter, float* __restrict__ s_bi,
    short* __restrict__ iTb, float* __restrict__ accums) {
    int b = blockIdx.x / 125, chunk = blockIdx.x % 125;
    __shared__ float qcT[DD * 57];
    __shared__ float vS[8][57];
    __shared__ float wred[4][4];
    int tid = threadIdx.x;
    for (int l = tid; l < NK * DD; l += 256) {
        int k = l / DD, d = l % DD;
        qcT[d * 57 + k] = qc[((size_t)b * NK + k) * DD + d];
    }
    __syncthreads();
    int w = tid >> 6, lane = tid & 63;
    float ex = exist[b];
    float aV = 0.f, aA = 0.f, aC = 0.f, aD = 0.f;
    for (int ii = 0; ii < 2; ++ii) {
        int i = chunk * 8 + w * 2 + ii;
        float v = 0.f, lab = 0.f;
        if (lane < NK) {
            const float* qrow = qp + ((size_t)b * NP + i) * DD;
            float acc = 0.f;
            for (int d = 0; d < DD; ++d)
                acc = fmaf(qrow[d], qcT[d * 57 + lane], acc);
            v = 1.f / (1.f + __expf(-acc));
            lab = ex * prot_inter[((size_t)b * NP + i) * NK + lane];
            inter[((size_t)b * NP + i) * NK + lane] = v;
            vS[w * 2 + ii][lane] = v;
        }
        float v2 = v * v;
        float r = v2;
        #pragma unroll
        for (int off = 32; off; off >>= 1) r += __shfl_down(r, off);
        if (lane == 0) s_bi[(size_t)b * NP + i] = r;
        aV += v; aA += v2; aC += v * lab; aD += lab * lab;
    }
    #pragma unroll
    for (int off = 32; off; off >>= 1) {
        aV += __shfl_down(aV, off);
        aA += __shfl_down(aA, off);
        aC += __shfl_down(aC, off);
        aD += __shfl_down(aD, off);
    }
    if (lane == 0) {
        wred[w][0] = aV; wred[w][1] = aA; wred[w][2] = aC; wred[w][3] = aD;
    }
    __syncthreads();
    if (tid < 4) {
        float s = wred[0][tid] + wred[1][tid] + wred[2][tid] + wred[3][tid];
        atomicAdd(&accums[tid * 8 + b], s);
    }
    // iTb slice for this block's 8 i-rows (oct == chunk)
    if (tid < NK) {
        bf16x8 pk;
        #pragma unroll
        for (int e = 0; e < 8; ++e) pk[e] = f2bf(vS[e][tid]);
        *reinterpret_cast<bf16x8*>(iTb + ((size_t)chunk * 448 + b * NK + tid) * 8) = pk;
        if (chunk == 124) {   // zero the i-pad octs 125..127
            bf16x8 z = {0,0,0,0,0,0,0,0};
            #pragma unroll
            for (int oct = 125; oct < 128; ++oct)
                *reinterpret_cast<bf16x8*>(iTb + ((size_t)oct * 448 + b * NK + tid) * 8) = z;
        }
    }
}

// ---------------------------------------------------------------------------
// cp partials: raw inter (1/S folded later).  t = 1 - 2*rcp(exp2(p*2log2e*c)+1)
__global__ __launch_bounds__(128) void cp_partial_kernel(
    const float* __restrict__ prot, const float* __restrict__ comp,
    const float* __restrict__ inter, float* __restrict__ part) {
    int bc = blockIdx.x;
    int b = bc / 125, chunk = bc % 125;
    int dh = blockIdx.y;
    int tid = threadIdx.x;
    int d = dh * 128 + tid;
    __shared__ float irow[8][NK];
    float creg[NK];
    #pragma unroll
    for (int k = 0; k < NK; ++k)
        creg[k] = comp[((size_t)b * NK + k) * DD + d];
    for (int l = tid; l < 8 * NK; l += 128) {
        int ii = l / NK, k = l % NK;
        irow[ii][k] = inter[((size_t)b * NP + chunk * 8 + ii) * NK + k];
    }
    const float C2LOG2E = 2.8853900817779268f;
    float p2l[8];
    #pragma unroll
    for (int ii = 0; ii < 8; ++ii)
        p2l[ii] = C2LOG2E * prot[((size_t)b * NP + chunk * 8 + ii) * DD + d];
    __syncthreads();
    float acc0 = 0.f, acc1 = 0.f;
    #pragma unroll 1
    for (int ii = 0; ii < 8; ++ii) {
        float p = p2l[ii];
        #pragma unroll
        for (int k = 0; k < NK; k += 2) {
            float e0 = __builtin_amdgcn_exp2f(p * creg[k]);
            float e1 = __builtin_amdgcn_exp2f(p * creg[k + 1]);
            float r0 = __builtin_amdgcn_rcpf(e0 + 1.f);
            float r1 = __builtin_amdgcn_rcpf(e1 + 1.f);
            acc0 = fmaf(fmaf(-2.f, r0, 1.f), irow[ii][k],     acc0);
            acc1 = fmaf(fmaf(-2.f, r1, 1.f), irow[ii][k + 1], acc1);
        }
    }
    part[((size_t)b * 125 + chunk) * DD + d] = acc0 + acc1;
}

// ---------------------------------------------------------------------------
// fused reg MFMA: E = iT @ fM^T ; fusedAbsRaw[b] += sum|E|  (1/S folded at final)
__global__ __launch_bounds__(256) void fused_mfma_abs_kernel(
    const short* __restrict__ iTb, const short* __restrict__ fMb,
    float* __restrict__ fusedAbs) {
    __shared__ float sb[8];
    int tid = threadIdx.x;
    int lane = tid & 63, w = tid >> 6;
    if (tid < 8) sb[tid] = 0.f;
    __syncthreads();
    int m0 = blockIdx.x * 32 + (w >> 1) * 16;
    int n0 = blockIdx.y * 128 + (w & 1) * 64;
    int lrow = lane & 15, lk = lane >> 4;
    f32x4 acc[4] = {{0.f,0.f,0.f,0.f},{0.f,0.f,0.f,0.f},
                    {0.f,0.f,0.f,0.f},{0.f,0.f,0.f,0.f}};
    for (int koct0 = 0; koct0 < 128; koct0 += 4) {
        int koct = koct0 + lk;
        bf16x8 af = *reinterpret_cast<const bf16x8*>(
            iTb + ((size_t)koct * 448 + m0 + lrow) * 8);
        const short* bb = fMb + ((size_t)koct * 1024 + n0 + lrow) * 8;
        #pragma unroll
        for (int nt = 0; nt < 4; ++nt) {
            bf16x8 bf = *reinterpret_cast<const bf16x8*>(bb + nt * 128);
            acc[nt] = __builtin_amdgcn_mfma_f32_16x16x32_bf16(af, bf, acc[nt], 0, 0, 0);
        }
    }
    #pragma unroll
    for (int r = 0; r < 4; ++r) {
        float part = fabsf(acc[0][r]) + fabsf(acc[1][r]) +
                     fabsf(acc[2][r]) + fabsf(acc[3][r]);
        #pragma unroll
        for (int off = 1; off < 16; off <<= 1)
            part += __shfl_xor(part, off);
        if (lrow == 0) {
            int row = m0 + lk * 4 + r;
            atomicAdd(&sb[row / NK], part);
        }
    }
    __syncthreads();
    if (tid < 8 && sb[tid] != 0.f) atomicAdd(&fusedAbs[tid], sb[tid]);
}

// ---------------------------------------------------------------------------
// convfc: per-batch block. cp_reduce + /S + conv + pool + fc1 + fc2 + fc3.
__global__ __launch_bounds__(1024) void convfc_kernel(
    const float* __restrict__ cp_part, const float* __restrict__ accums,
    const float* __restrict__ conv_w, const float* __restrict__ conv_b,
    const float* __restrict__ W_r1, const float* __restrict__ b_r1,
    const float* __restrict__ W_r2, const float* __restrict__ b_r2,
    const float* __restrict__ W_r3, const float* __restrict__ b_r3,
    float* __restrict__ affn) {
    int b = blockIdx.x, t = threadIdx.x;
    __shared__ float xS[258];
    __shared__ float convo[8192];
    __shared__ float pooled[2048];
    __shared__ float f1[600];
    __shared__ float red[512];
    float invS = 1.f / accums[b];
    if (t < 256) {
        float s = 0.f;
        for (int c = 0; c < 125; ++c) s += cp_part[((size_t)b * 125 + c) * DD + t];
        xS[t + 1] = s * invS;
    }
    if (t == 0) { xS[0] = 0.f; xS[257] = 0.f; }
    __syncthreads();
    for (int l = t; l < 8192; l += 1024) {
        int o = l >> 7, pos = l & 127;
        float acc = conv_b[o];
        int base = pos * 2;
        #pragma unroll
        for (int h = 0; h < 4; ++h)
            acc = fmaf(xS[base + h], conv_w[o * 4 + h], acc);
        convo[l] = (acc > 0.f) ? acc : 0.1f * acc;
    }
    __syncthreads();
    for (int l = t; l < 2048; l += 1024) {
        int o = l >> 5, p = l & 31;
        float m = convo[o * 128 + p * 4];
        m = fmaxf(m, convo[o * 128 + p * 4 + 1]);
        m = fmaxf(m, convo[o * 128 + p * 4 + 2]);
        m = fmaxf(m, convo[o * 128 + p * 4 + 3]);
        pooled[l] = m;
    }
    __syncthreads();
    if (t < 600) {
        float acc = b_r1[t];
        for (int k = 0; k < 2048; ++k)
            acc = fmaf(pooled[k], W_r1[(size_t)k * 600 + t], acc);
        f1[t] = (acc > 0.f) ? acc : 0.1f * acc;
    }
    __syncthreads();
    float p3 = 0.f;
    if (t < 300) {
        float acc = b_r2[t];
        for (int k = 0; k < 600; ++k)
            acc = fmaf(f1[k], W_r2[(size_t)k * 300 + t], acc);
        acc = (acc > 0.f) ? acc : 0.1f * acc;
        p3 = acc * W_r3[t];
    }
    if (t < 512) red[t] = p3;
    __syncthreads();
    for (int s = 256; s; s >>= 1) {
        if (t < s) red[t] += red[t + s];
        __syncthreads();
    }
    if (t == 0) affn[b] = red[0] + b_r3[0];
}

// ---------------------------------------------------------------------------
// group: g_raw = contacts.s_bi_raw ; val = sqrt(g/S^2)*sqrt(rs) ; atomic add.
__global__ __launch_bounds__(64) void group_kernel(
    const float* __restrict__ contacts, const float* __restrict__ s_bi,
    const float* __restrict__ accums, float* __restrict__ groupReg) {
    int bk = blockIdx.x;
    int b = bk / NP, k = bk % NP;
    const float* row = contacts + ((size_t)b * NP + k) * NP;
    const float* sv = s_bi + b * NP;
    float g = 0.f, rs = 0.f;
    for (int i = threadIdx.x; i < NP; i += 64) {
        float c = row[i];
        g = fmaf(c, sv[i], g);
        rs += c;
    }
    #pragma unroll
    for (int off = 32; off; off >>= 1) {
        g += __shfl_down(g, off);
        rs += __shfl_down(rs, off);
    }
    if (threadIdx.x == 0) {
        float val;
        if (g == 0.f) val = sqrtf(1e10f) * sqrtf(rs);
        else          val = sqrtf(g) / accums[b] * sqrtf(rs);
        atomicAdd(&groupReg[b], val);
    }
}

// ---------------------------------------------------------------------------
__global__ void final_kernel(const float* __restrict__ accums,
                             const float* __restrict__ affn,
                             const float* __restrict__ label,
                             float* __restrict__ out) {
    if (threadIdx.x == 0 && blockIdx.x == 0) {
        float l0 = 0.f, l1 = 0.f, l2 = 0.f;
        for (int b = 0; b < B; ++b) {
            float S = accums[b];
            float A = accums[8 + b], C = accums[16 + b], D = accums[24 + b];
            float fA = accums[32 + b], gR = accums[40 + b];
            l0 += 1.f + fA / S + gR;
            float bind = A / (S * S) - 2.f * C / S + D;
            l1 += sqrtf(fmaxf(bind, 0.f));
            float dd = affn[b] - label[b];
            l2 += dd * dd;
        }
        out[0] = (l0 + l1 + l2) * 0.125f;
    }
}

// ---------------------------------------------------------------------------
extern "C" void kernel_launch(void* const* d_in, const int* in_sizes, int n_in,
                              void* d_out, int out_size, void* d_ws, size_t ws_size,
                              hipStream_t stream) {
    const float* prot_data   = (const float*)d_in[0];
    const float* drug_ver    = (const float*)d_in[1];
    const float* drug_adj    = (const float*)d_in[2];
    const float* contacts    = (const float*)d_in[3];
    const float* prot_inter  = (const float*)d_in[4];
    const float* exist       = (const float*)d_in[5];
    const float* label       = (const float*)d_in[6];
    const float* fused       = (const float*)d_in[7];
    const float* W_prot      = (const float*)d_in[8];
    const float* b_prot      = (const float*)d_in[9];
    const float* gcn_W0      = (const float*)d_in[10];
    const float* gcn_b0      = (const float*)d_in[11];
    const float* gcn_W1      = (const float*)d_in[12];
    const float* gcn_b1      = (const float*)d_in[13];
    const float* gcn_W2      = (const float*)d_in[14];
    const float* gcn_b2      = (const float*)d_in[15];
    const float* gcn_Wf      = (const float*)d_in[16];
    const float* gcn_bf      = (const float*)d_in[17];
    const float* Wjp         = (const float*)d_in[18];
    const float* bjp         = (const float*)d_in[19];
    const float* Wjc         = (const float*)d_in[20];
    const float* bjc         = (const float*)d_in[21];
    const float* conv_w      = (const float*)d_in[22];
    const float* conv_b      = (const float*)d_in[23];
    const float* W_r1        = (const float*)d_in[24];
    const float* b_r1        = (const float*)d_in[25];
    const float* W_r2        = (const float*)d_in[26];
    const float* b_r2        = (const float*)d_in[27];
    const float* W_r3        = (const float*)d_in[28];
    const float* b_r3        = (const float*)d_in[29];

    float* ws = (float*)d_ws;
    size_t off = 0;
    auto alloc = [&](size_t n) { float* p = ws + off; off += n; return p; };
    float* prot     = alloc((size_t)B * NP * DD);
    float* qp       = alloc((size_t)B * NP * DD);
    float* tbuf     = alloc((size_t)B * NK * DD);   // + ybuf below = iTb alias
    float* ybuf     = alloc((size_t)B * NK * DD);
    float* comp     = alloc((size_t)B * NK * DD);
    float* qc       = alloc((size_t)B * NK * DD);
    float* inter    = alloc((size_t)B * NP * NK);
    float* s_bi     = alloc((size_t)B * NP);
    float* cp_part  = alloc((size_t)B * 125 * DD);
    float* affn     = alloc((size_t)B);
    short* Wb1      = (short*)alloc((DP / 8) * DD * 8 / 2);
    short* Wb2      = (short*)alloc((DD / 8) * DD * 8 / 2);
    short* fMb      = (short*)alloc((size_t)128 * 1024 * 8 / 2);
    float* accums   = alloc(48);

    // iTb[128][448][8] bf16 = 229,376 f32-equiv, aliases tbuf+ybuf (dead after GCN)
    short* iTb = (short*)tbuf;
    (void)ybuf;

    // 1. prep: weight cvts + fused cvt + accums zero
    prep_kernel<<<641, 256, 0, stream>>>(W_prot, Wb1, Wjp, Wb2, fused, fMb, accums);

    // 2. prot = prot_data @ W_prot + b_prot   (bf16 MFMA)
    mfma_gemm_bias_kernel<false><<<dim3(250, 2), 256, 0, stream>>>(
        prot_data, Wb1, b_prot, prot, B * NP, DD, DP);

    // 3-10. GCN stack
    rowmm_kernel<false><<<B * NK, 256, DV * sizeof(float), stream>>>(drug_ver, gcn_W0, gcn_b0, tbuf, DV);
    adjmul_relu_kernel<<<B * NK, 256, 0, stream>>>(drug_adj, tbuf, ybuf);
    rowmm_kernel<false><<<B * NK, 256, DD * sizeof(float), stream>>>(ybuf, gcn_W1, gcn_b1, tbuf, DD);
    adjmul_relu_kernel<<<B * NK, 256, 0, stream>>>(drug_adj, tbuf, ybuf);
    rowmm_kernel<false><<<B * NK, 256, DD * sizeof(float), stream>>>(ybuf, gcn_W2, gcn_b2, tbuf, DD);
    adjmul_relu_kernel<<<B * NK, 256, 0, stream>>>(drug_adj, tbuf, ybuf);
    rowmm_kernel<false><<<B * NK, 256, DD * sizeof(float), stream>>>(ybuf, gcn_Wf, gcn_bf, comp, DD);
    rowmm_kernel<true ><<<B * NK, 256, DD * sizeof(float), stream>>>(comp, Wjc, bjc, qc, DD);

    // 11. qp = relu(prot) @ Wjp + bjp   (bf16 MFMA)
    mfma_gemm_bias_kernel<true><<<dim3(250, 2), 256, 0, stream>>>(
        prot, Wb2, bjp, qp, B * NP, DD, DD);

    // 12. inter (raw) + moments + s_bi + iTb   (writes iTb over dead tbuf/ybuf)
    inter_all_kernel<<<B * 125, 256, 0, stream>>>(
        qp, qc, prot_inter, exist, inter, s_bi, iTb, accums);

    // 13. cp partials (raw inter)
    cp_partial_kernel<<<dim3(B * 125, 2), 128, 0, stream>>>(prot, comp, inter, cp_part);

    // 14. fused regularizer MFMA + abs
    fused_mfma_abs_kernel<<<dim3(14, 8), 256, 0, stream>>>(iTb, fMb, accums + 32);

    // 15. cp reduce + /S + conv + pool + fc1..fc3
    convfc_kernel<<<B, 1024, 0, stream>>>(cp_part, accums, conv_w, conv_b,
                                          W_r1, b_r1, W_r2, b_r2, W_r3, b_r3, affn);

    // 16. group regularizer (direct atomic accumulate)
    group_kernel<<<B * NP, 64, 0, stream>>>(contacts, s_bi, accums, accums + 40);

    // 17. final loss
    final_kernel<<<1, 64, 0, stream>>>(accums, affn, label, (float*)d_out);
}

// Round 10
// 238.589 us; speedup vs baseline: 1.6248x; 1.6248x over previous
//
#include <hip/hip_runtime.h>
#include <hip/hip_bf16.h>
#include <math.h>

// ---------------------------------------------------------------------------
#define B 8
#define NP 1000
#define NK 56
#define DP 768
#define DV 43
#define DD 256
#define NT 999

typedef __attribute__((ext_vector_type(8))) short bf16x8;
typedef __attribute__((ext_vector_type(4))) float f32x4;

__device__ inline short f2bf(float x) {
    __hip_bfloat16 h = __float2bfloat16(x);
    return __builtin_bit_cast(short, h);
}

// ---------------------------------------------------------------------------
// prep: [0,96) wcvt W_prot ; [96,128) wcvt Wjp ; [128,640) fusedcvt ;
//       [640,670) zero region (accums 48 + raw1 4800 + raw2 2400 = 7248)
// accums layout: [0..8)S [8..16)A=Sum v^2 [16..24)C=Sum v*lab [24..32)D=Sum lab^2
//                [32..40)fusedAbsRaw [40..48)groupReg
__global__ __launch_bounds__(256) void prep_kernel(
    const float* __restrict__ W_prot, short* __restrict__ Wb1,
    const float* __restrict__ Wjp, short* __restrict__ Wb2,
    const float* __restrict__ fusedM, short* __restrict__ fMb,
    float* __restrict__ zero_region) {
    int blk = blockIdx.x, tid = threadIdx.x;
    if (blk < 96) {
        int idx = blk * 256 + tid;
        int koct = idx / DD, n = idx % DD;
        bf16x8 v;
        #pragma unroll
        for (int e = 0; e < 8; ++e)
            v[e] = f2bf(W_prot[(size_t)(koct * 8 + e) * DD + n]);
        *reinterpret_cast<bf16x8*>(Wb1 + (size_t)idx * 8) = v;
    } else if (blk < 128) {
        int idx = (blk - 96) * 256 + tid;
        int koct = idx / DD, n = idx % DD;
        bf16x8 v;
        #pragma unroll
        for (int e = 0; e < 8; ++e)
            v[e] = f2bf(Wjp[(size_t)(koct * 8 + e) * DD + n]);
        *reinterpret_cast<bf16x8*>(Wb2 + (size_t)idx * 8) = v;
    } else if (blk < 640) {
        int idx = (blk - 128) * 256 + tid;
        int oct = idx >> 10, t = idx & 1023;
        bf16x8 v;
        #pragma unroll
        for (int e = 0; e < 8; ++e) {
            int i = oct * 8 + e;
            float x = (t < NT && i < NP) ? fusedM[(size_t)t * NP + i] : 0.f;
            v[e] = f2bf(x);
        }
        *reinterpret_cast<bf16x8*>(fMb + (size_t)idx * 8) = v;
    } else {
        int idx = (blk - 640) * 256 + tid;
        if (idx < 48 + B * 600 + B * 300) zero_region[idx] = 0.f;
    }
}

// ---------------------------------------------------------------------------
// MFMA GEMM: C = act_in(A) @ Wb + bias. Block 4 waves; tile 32(M) x 128(N).
template<bool RELU_IN>
__global__ __launch_bounds__(256) void mfma_gemm_bias_kernel(
    const float* __restrict__ A, const short* __restrict__ Wb,
    const float* __restrict__ bias, float* __restrict__ C,
    int M, int N, int K) {
    int tid = threadIdx.x;
    int lane = tid & 63, w = tid >> 6;
    int m0 = blockIdx.x * 32 + (w >> 1) * 16;
    int n0 = blockIdx.y * 128 + (w & 1) * 64;
    int lrow = lane & 15, lk = lane >> 4;
    f32x4 acc[4] = {{0.f,0.f,0.f,0.f},{0.f,0.f,0.f,0.f},
                    {0.f,0.f,0.f,0.f},{0.f,0.f,0.f,0.f}};
    const float* arow = A + (size_t)(m0 + lrow) * K + lk * 8;
    for (int k0 = 0; k0 < K; k0 += 32) {
        f32x4 a0 = *reinterpret_cast<const f32x4*>(arow + k0);
        f32x4 a1 = *reinterpret_cast<const f32x4*>(arow + k0 + 4);
        bf16x8 af;
        #pragma unroll
        for (int e = 0; e < 4; ++e) {
            float v0 = a0[e], v1 = a1[e];
            if (RELU_IN) { v0 = fmaxf(v0, 0.f); v1 = fmaxf(v1, 0.f); }
            af[e] = f2bf(v0); af[4 + e] = f2bf(v1);
        }
        const short* bbase = Wb + ((size_t)((k0 >> 3) + lk) * N + n0 + lrow) * 8;
        #pragma unroll
        for (int nt = 0; nt < 4; ++nt) {
            bf16x8 bf = *reinterpret_cast<const bf16x8*>(bbase + nt * 128);
            acc[nt] = __builtin_amdgcn_mfma_f32_16x16x32_bf16(af, bf, acc[nt], 0, 0, 0);
        }
    }
    #pragma unroll
    for (int nt = 0; nt < 4; ++nt) {
        int col = n0 + nt * 16 + lrow;
        float bv = bias[col];
        #pragma unroll
        for (int r = 0; r < 4; ++r) {
            int row = m0 + lk * 4 + r;
            C[(size_t)row * N + col] = acc[nt][r] + bv;
        }
    }
}

// ---------------------------------------------------------------------------
template<bool RELU_IN>
__global__ __launch_bounds__(256) void rowmm_kernel(
    const float* __restrict__ in, const float* __restrict__ W,
    const float* __restrict__ bias, float* __restrict__ out, int K) {
    extern __shared__ float srow[];
    int r = blockIdx.x, d = threadIdx.x;
    for (int k = d; k < K; k += 256) {
        float v = in[(size_t)r * K + k];
        if (RELU_IN) v = fmaxf(v, 0.f);
        srow[k] = v;
    }
    __syncthreads();
    float acc = bias[d];
    for (int k = 0; k < K; ++k)
        acc = fmaf(srow[k], W[(size_t)k * DD + d], acc);
    out[(size_t)r * DD + d] = acc;
}

__global__ __launch_bounds__(256) void adjmul_relu_kernel(
    const float* __restrict__ adj, const float* __restrict__ t,
    float* __restrict__ y) {
    int b = blockIdx.x / NK, i = blockIdx.x % NK, d = threadIdx.x;
    __shared__ float arow[NK];
    if (d < NK) arow[d] = adj[((size_t)b * NK + i) * NK + d];
    __syncthreads();
    float acc = 0.f;
    #pragma unroll 8
    for (int j = 0; j < NK; ++j)
        acc = fmaf(arow[j], t[((size_t)b * NK + j) * DD + d], acc);
    y[((size_t)b * NK + i) * DD + d] = fmaxf(acc, 0.f);
}

// ---------------------------------------------------------------------------
// inter_all: raw inter = sigmoid(qp.qc); accumulate S,A,C,D; s_bi raw; iTb bf16.
__global__ __launch_bounds__(256) void inter_all_kernel(
    const float* __restrict__ qp, const float* __restrict__ qc,
    const float* __restrict__ prot_inter, const float* __restrict__ exist,
    float* __restrict__ inter, float* __restrict__ s_bi,
    short* __restrict__ iTb, float* __restrict__ accums) {
    int b = blockIdx.x / 125, chunk = blockIdx.x % 125;
    __shared__ float qcT[DD * 57];
    __shared__ float vS[8][57];
    __shared__ float wred[4][4];
    int tid = threadIdx.x;
    for (int l = tid; l < NK * DD; l += 256) {
        int k = l / DD, d = l % DD;
        qcT[d * 57 + k] = qc[((size_t)b * NK + k) * DD + d];
    }
    __syncthreads();
    int w = tid >> 6, lane = tid & 63;
    float ex = exist[b];
    float aV = 0.f, aA = 0.f, aC = 0.f, aD = 0.f;
    for (int ii = 0; ii < 2; ++ii) {
        int i = chunk * 8 + w * 2 + ii;
        float v = 0.f, lab = 0.f;
        if (lane < NK) {
            const float* qrow = qp + ((size_t)b * NP + i) * DD;
            float acc = 0.f;
            for (int d = 0; d < DD; ++d)
                acc = fmaf(qrow[d], qcT[d * 57 + lane], acc);
            v = 1.f / (1.f + __expf(-acc));
            lab = ex * prot_inter[((size_t)b * NP + i) * NK + lane];
            inter[((size_t)b * NP + i) * NK + lane] = v;
            vS[w * 2 + ii][lane] = v;
        }
        float v2 = v * v;
        float r = v2;
        #pragma unroll
        for (int off = 32; off; off >>= 1) r += __shfl_down(r, off);
        if (lane == 0) s_bi[(size_t)b * NP + i] = r;
        aV += v; aA += v2; aC += v * lab; aD += lab * lab;
    }
    #pragma unroll
    for (int off = 32; off; off >>= 1) {
        aV += __shfl_down(aV, off);
        aA += __shfl_down(aA, off);
        aC += __shfl_down(aC, off);
        aD += __shfl_down(aD, off);
    }
    if (lane == 0) {
        wred[w][0] = aV; wred[w][1] = aA; wred[w][2] = aC; wred[w][3] = aD;
    }
    __syncthreads();
    if (tid < 4) {
        float s = wred[0][tid] + wred[1][tid] + wred[2][tid] + wred[3][tid];
        atomicAdd(&accums[tid * 8 + b], s);
    }
    if (tid < NK) {
        bf16x8 pk;
        #pragma unroll
        for (int e = 0; e < 8; ++e) pk[e] = f2bf(vS[e][tid]);
        *reinterpret_cast<bf16x8*>(iTb + ((size_t)chunk * 448 + b * NK + tid) * 8) = pk;
        if (chunk == 124) {
            bf16x8 z = {0,0,0,0,0,0,0,0};
            #pragma unroll
            for (int oct = 125; oct < 128; ++oct)
                *reinterpret_cast<bf16x8*>(iTb + ((size_t)oct * 448 + b * NK + tid) * 8) = z;
        }
    }
}

// ---------------------------------------------------------------------------
// cp partials: raw inter (1/S folded later).  t = 1 - 2*rcp(exp2(p*2log2e*c)+1)
__global__ __launch_bounds__(128) void cp_partial_kernel(
    const float* __restrict__ prot, const float* __restrict__ comp,
    const float* __restrict__ inter, float* __restrict__ part) {
    int bc = blockIdx.x;
    int b = bc / 125, chunk = bc % 125;
    int dh = blockIdx.y;
    int tid = threadIdx.x;
    int d = dh * 128 + tid;
    __shared__ float irow[8][NK];
    float creg[NK];
    #pragma unroll
    for (int k = 0; k < NK; ++k)
        creg[k] = comp[((size_t)b * NK + k) * DD + d];
    for (int l = tid; l < 8 * NK; l += 128) {
        int ii = l / NK, k = l % NK;
        irow[ii][k] = inter[((size_t)b * NP + chunk * 8 + ii) * NK + k];
    }
    const float C2LOG2E = 2.8853900817779268f;
    float p2l[8];
    #pragma unroll
    for (int ii = 0; ii < 8; ++ii)
        p2l[ii] = C2LOG2E * prot[((size_t)b * NP + chunk * 8 + ii) * DD + d];
    __syncthreads();
    float acc0 = 0.f, acc1 = 0.f;
    #pragma unroll 1
    for (int ii = 0; ii < 8; ++ii) {
        float p = p2l[ii];
        #pragma unroll
        for (int k = 0; k < NK; k += 2) {
            float e0 = __builtin_amdgcn_exp2f(p * creg[k]);
            float e1 = __builtin_amdgcn_exp2f(p * creg[k + 1]);
            float r0 = __builtin_amdgcn_rcpf(e0 + 1.f);
            float r1 = __builtin_amdgcn_rcpf(e1 + 1.f);
            acc0 = fmaf(fmaf(-2.f, r0, 1.f), irow[ii][k],     acc0);
            acc1 = fmaf(fmaf(-2.f, r1, 1.f), irow[ii][k + 1], acc1);
        }
    }
    part[((size_t)b * 125 + chunk) * DD + d] = acc0 + acc1;
}

// ---------------------------------------------------------------------------
// fused reg MFMA: E = iT @ fM^T ; fusedAbsRaw[b] += sum|E|  (1/S folded at final)
__global__ __launch_bounds__(256) void fused_mfma_abs_kernel(
    const short* __restrict__ iTb, const short* __restrict__ fMb,
    float* __restrict__ fusedAbs) {
    __shared__ float sb[8];
    int tid = threadIdx.x;
    int lane = tid & 63, w = tid >> 6;
    if (tid < 8) sb[tid] = 0.f;
    __syncthreads();
    int m0 = blockIdx.x * 32 + (w >> 1) * 16;
    int n0 = blockIdx.y * 128 + (w & 1) * 64;
    int lrow = lane & 15, lk = lane >> 4;
    f32x4 acc[4] = {{0.f,0.f,0.f,0.f},{0.f,0.f,0.f,0.f},
                    {0.f,0.f,0.f,0.f},{0.f,0.f,0.f,0.f}};
    for (int koct0 = 0; koct0 < 128; koct0 += 4) {
        int koct = koct0 + lk;
        bf16x8 af = *reinterpret_cast<const bf16x8*>(
            iTb + ((size_t)koct * 448 + m0 + lrow) * 8);
        const short* bb = fMb + ((size_t)koct * 1024 + n0 + lrow) * 8;
        #pragma unroll
        for (int nt = 0; nt < 4; ++nt) {
            bf16x8 bf = *reinterpret_cast<const bf16x8*>(bb + nt * 128);
            acc[nt] = __builtin_amdgcn_mfma_f32_16x16x32_bf16(af, bf, acc[nt], 0, 0, 0);
        }
    }
    #pragma unroll
    for (int r = 0; r < 4; ++r) {
        float part = fabsf(acc[0][r]) + fabsf(acc[1][r]) +
                     fabsf(acc[2][r]) + fabsf(acc[3][r]);
        #pragma unroll
        for (int off = 1; off < 16; off <<= 1)
            part += __shfl_xor(part, off);
        if (lrow == 0) {
            int row = m0 + lk * 4 + r;
            atomicAdd(&sb[row / NK], part);
        }
    }
    __syncthreads();
    if (tid < 8 && sb[tid] != 0.f) atomicAdd(&fusedAbs[tid], sb[tid]);
}

// ---------------------------------------------------------------------------
// convpool: per-batch block 256 thr. cp_reduce + /S + conv + bias + leaky + pool.
__global__ __launch_bounds__(256) void convpool_kernel(
    const float* __restrict__ cp_part, const float* __restrict__ accums,
    const float* __restrict__ conv_w, const float* __restrict__ conv_b,
    float* __restrict__ pooled) {
    int b = blockIdx.x, t = threadIdx.x;
    __shared__ float xS[258];
    __shared__ float convo[8192];
    float invS = 1.f / accums[b];
    float s = 0.f;
    for (int c = 0; c < 125; ++c) s += cp_part[((size_t)b * 125 + c) * DD + t];
    xS[t + 1] = s * invS;
    if (t == 0) { xS[0] = 0.f; xS[257] = 0.f; }
    __syncthreads();
    for (int l = t; l < 8192; l += 256) {
        int o = l >> 7, pos = l & 127;
        float acc = conv_b[o];
        int base = pos * 2;
        #pragma unroll
        for (int h = 0; h < 4; ++h)
            acc = fmaf(xS[base + h], conv_w[o * 4 + h], acc);
        convo[l] = (acc > 0.f) ? acc : 0.1f * acc;
    }
    __syncthreads();
    for (int l = t; l < 2048; l += 256) {
        int o = l >> 5, p = l & 31;
        float m = convo[o * 128 + p * 4];
        m = fmaxf(m, convo[o * 128 + p * 4 + 1]);
        m = fmaxf(m, convo[o * 128 + p * 4 + 2]);
        m = fmaxf(m, convo[o * 128 + p * 4 + 3]);
        pooled[b * 2048 + l] = m;
    }
}

// ---------------------------------------------------------------------------
// FC partial: grid (o_tiles, k_splits), LDS-staged activations, atomic raw.
__global__ __launch_bounds__(256) void fc_partial_kernel(
    const float* __restrict__ in, const float* __restrict__ W,
    float* __restrict__ raw, int K, int N, int kchunk) {
    int t = threadIdx.x;
    int ol = t & 63;
    int o = blockIdx.x * 64 + ol;
    int w = t >> 6;
    int kbeg = blockIdx.y * kchunk;
    int kend = kbeg + kchunk; if (kend > K) kend = K;
    int len = kend - kbeg;
    __shared__ float sin_[B][128];
    for (int l = t; l < B * len; l += 256) {
        int b = l / len, k = l % len;
        sin_[b][k] = in[(size_t)b * K + kbeg + k];
    }
    __syncthreads();
    float acc[B];
    #pragma unroll
    for (int b = 0; b < B; ++b) acc[b] = 0.f;
    if (o < N) {
        for (int k = kbeg + w; k < kend; k += 4) {
            float wv = W[(size_t)k * N + o];
            int kl = k - kbeg;
            #pragma unroll
            for (int b = 0; b < B; ++b)
                acc[b] = fmaf(sin_[b][kl], wv, acc[b]);
        }
    }
    __shared__ float red[4][64][B];
    #pragma unroll
    for (int b = 0; b < B; ++b) red[w][ol][b] = acc[b];
    __syncthreads();
    for (int p = t; p < 64 * B; p += 256) {
        int oo = p / B, b = p % B;
        int o2 = blockIdx.x * 64 + oo;
        if (o2 < N) {
            float s = red[0][oo][b] + red[1][oo][b] + red[2][oo][b] + red[3][oo][b];
            atomicAdd(&raw[(size_t)b * N + o2], s);
        }
    }
}

template<bool LEAKY>
__global__ void fc_finish_kernel(const float* __restrict__ raw,
                                 const float* __restrict__ bias,
                                 float* __restrict__ out, int N) {
    int idx = blockIdx.x * 256 + threadIdx.x;
    if (idx < B * N) {
        int b = idx / N, o = idx % N;
        float s = raw[(size_t)b * N + o] + bias[o];
        if (LEAKY) s = (s > 0.f) ? s : 0.1f * s;
        out[(size_t)b * N + o] = s;
    }
}

__global__ __launch_bounds__(512) void fc3_kernel(
    const float* __restrict__ in, const float* __restrict__ W,
    const float* __restrict__ bias, float* __restrict__ affn) {
    int wv = threadIdx.x >> 6, lane = threadIdx.x & 63;
    float acc = 0.f;
    for (int k = lane; k < 300; k += 64)
        acc = fmaf(in[(size_t)wv * 300 + k], W[k], acc);
    #pragma unroll
    for (int off = 32; off; off >>= 1) acc += __shfl_down(acc, off);
    if (lane == 0) affn[wv] = acc + bias[0];
}

// ---------------------------------------------------------------------------
// group: g_raw = contacts.s_bi_raw ; store sqrt(g)/S*sqrt(rs) to groupv[bk].
__global__ __launch_bounds__(64) void group_kernel(
    const float* __restrict__ contacts, const float* __restrict__ s_bi,
    const float* __restrict__ accums, float* __restrict__ groupv) {
    int bk = blockIdx.x;
    int b = bk / NP, k = bk % NP;
    const float* row = contacts + ((size_t)b * NP + k) * NP;
    const float* sv = s_bi + b * NP;
    float g = 0.f, rs = 0.f;
    for (int i = threadIdx.x; i < NP; i += 64) {
        float c = row[i];
        g = fmaf(c, sv[i], g);
        rs += c;
    }
    #pragma unroll
    for (int off = 32; off; off >>= 1) {
        g += __shfl_down(g, off);
        rs += __shfl_down(rs, off);
    }
    if (threadIdx.x == 0) {
        float val;
        if (g == 0.f) val = sqrtf(1e10f) * sqrtf(rs);
        else          val = sqrtf(g) / accums[b] * sqrtf(rs);
        groupv[bk] = val;
    }
}

__global__ __launch_bounds__(256) void reduce1000_kernel(const float* in, float* out) {
    int b = blockIdx.x;
    float s = 0.f;
    for (int l = threadIdx.x; l < NP; l += 256) s += in[b * NP + l];
    __shared__ float r[256];
    r[threadIdx.x] = s;
    __syncthreads();
    for (int st = 128; st; st >>= 1) {
        if (threadIdx.x < st) r[threadIdx.x] += r[threadIdx.x + st];
        __syncthreads();
    }
    if (threadIdx.x == 0) out[b] = r[0];
}

// ---------------------------------------------------------------------------
__global__ void final_kernel(const float* __restrict__ accums,
                             const float* __restrict__ affn,
                             const float* __restrict__ label,
                             float* __restrict__ out) {
    if (threadIdx.x == 0 && blockIdx.x == 0) {
        float l0 = 0.f, l1 = 0.f, l2 = 0.f;
        for (int b = 0; b < B; ++b) {
            float S = accums[b];
            float A = accums[8 + b], C = accums[16 + b], D = accums[24 + b];
            float fA = accums[32 + b], gR = accums[40 + b];
            l0 += 1.f + fA / S + gR;
            float bind = A / (S * S) - 2.f * C / S + D;
            l1 += sqrtf(fmaxf(bind, 0.f));
            float dd = affn[b] - label[b];
            l2 += dd * dd;
        }
        out[0] = (l0 + l1 + l2) * 0.125f;
    }
}

// ---------------------------------------------------------------------------
extern "C" void kernel_launch(void* const* d_in, const int* in_sizes, int n_in,
                              void* d_out, int out_size, void* d_ws, size_t ws_size,
                              hipStream_t stream) {
    const float* prot_data   = (const float*)d_in[0];
    const float* drug_ver    = (const float*)d_in[1];
    const float* drug_adj    = (const float*)d_in[2];
    const float* contacts    = (const float*)d_in[3];
    const float* prot_inter  = (const float*)d_in[4];
    const float* exist       = (const float*)d_in[5];
    const float* label       = (const float*)d_in[6];
    const float* fused       = (const float*)d_in[7];
    const float* W_prot      = (const float*)d_in[8];
    const float* b_prot      = (const float*)d_in[9];
    const float* gcn_W0      = (const float*)d_in[10];
    const float* gcn_b0      = (const float*)d_in[11];
    const float* gcn_W1      = (const float*)d_in[12];
    const float* gcn_b1      = (const float*)d_in[13];
    const float* gcn_W2      = (const float*)d_in[14];
    const float* gcn_b2      = (const float*)d_in[15];
    const float* gcn_Wf      = (const float*)d_in[16];
    const float* gcn_bf      = (const float*)d_in[17];
    const float* Wjp         = (const float*)d_in[18];
    const float* bjp         = (const float*)d_in[19];
    const float* Wjc         = (const float*)d_in[20];
    const float* bjc         = (const float*)d_in[21];
    const float* conv_w      = (const float*)d_in[22];
    const float* conv_b      = (const float*)d_in[23];
    const float* W_r1        = (const float*)d_in[24];
    const float* b_r1        = (const float*)d_in[25];
    const float* W_r2        = (const float*)d_in[26];
    const float* b_r2        = (const float*)d_in[27];
    const float* W_r3        = (const float*)d_in[28];
    const float* b_r3        = (const float*)d_in[29];

    float* ws = (float*)d_ws;
    size_t off = 0;
    auto alloc = [&](size_t n) { float* p = ws + off; off += n; return p; };
    float* prot     = alloc((size_t)B * NP * DD);
    float* qp       = alloc((size_t)B * NP * DD);
    float* tbuf     = alloc((size_t)B * NK * DD);   // + ybuf = iTb alias
    float* ybuf     = alloc((size_t)B * NK * DD);
    float* comp     = alloc((size_t)B * NK * DD);
    float* qc       = alloc((size_t)B * NK * DD);
    float* inter    = alloc((size_t)B * NP * NK);
    float* s_bi     = alloc((size_t)B * NP);
    float* cp_part  = alloc((size_t)B * 125 * DD);
    float* pooled   = alloc((size_t)B * 2048);
    float* fc1      = alloc((size_t)B * 600);
    float* fc2      = alloc((size_t)B * 300);
    float* affn     = alloc((size_t)B);
    float* groupv   = alloc((size_t)B * NP);
    short* Wb1      = (short*)alloc((DP / 8) * DD * 8 / 2);
    short* Wb2      = (short*)alloc((DD / 8) * DD * 8 / 2);
    short* fMb      = (short*)alloc((size_t)128 * 1024 * 8 / 2);
    // zero region: accums(48) + raw1(4800) + raw2(2400), contiguous
    float* accums   = alloc(48);
    float* raw1     = alloc((size_t)B * 600);
    float* raw2     = alloc((size_t)B * 300);

    // iTb[128][448][8] bf16 = 229,376 f32-equiv, aliases tbuf+ybuf (dead after GCN)
    short* iTb = (short*)tbuf;
    (void)ybuf;

    // 1. prep: weight cvts + fused cvt + zero region
    prep_kernel<<<670, 256, 0, stream>>>(W_prot, Wb1, Wjp, Wb2, fused, fMb, accums);

    // 2. prot = prot_data @ W_prot + b_prot   (bf16 MFMA)
    mfma_gemm_bias_kernel<false><<<dim3(250, 2), 256, 0, stream>>>(
        prot_data, Wb1, b_prot, prot, B * NP, DD, DP);

    // 3-10. GCN stack
    rowmm_kernel<false><<<B * NK, 256, DV * sizeof(float), stream>>>(drug_ver, gcn_W0, gcn_b0, tbuf, DV);
    adjmul_relu_kernel<<<B * NK, 256, 0, stream>>>(drug_adj, tbuf, ybuf);
    rowmm_kernel<false><<<B * NK, 256, DD * sizeof(float), stream>>>(ybuf, gcn_W1, gcn_b1, tbuf, DD);
    adjmul_relu_kernel<<<B * NK, 256, 0, stream>>>(drug_adj, tbuf, ybuf);
    rowmm_kernel<false><<<B * NK, 256, DD * sizeof(float), stream>>>(ybuf, gcn_W2, gcn_b2, tbuf, DD);
    adjmul_relu_kernel<<<B * NK, 256, 0, stream>>>(drug_adj, tbuf, ybuf);
    rowmm_kernel<false><<<B * NK, 256, DD * sizeof(float), stream>>>(ybuf, gcn_Wf, gcn_bf, comp, DD);
    rowmm_kernel<true ><<<B * NK, 256, DD * sizeof(float), stream>>>(comp, Wjc, bjc, qc, DD);

    // 11. qp = relu(prot) @ Wjp + bjp   (bf16 MFMA)
    mfma_gemm_bias_kernel<true><<<dim3(250, 2), 256, 0, stream>>>(
        prot, Wb2, bjp, qp, B * NP, DD, DD);

    // 12. inter (raw) + moments + s_bi + iTb
    inter_all_kernel<<<B * 125, 256, 0, stream>>>(
        qp, qc, prot_inter, exist, inter, s_bi, iTb, accums);

    // 13. cp partials (raw inter)
    cp_partial_kernel<<<dim3(B * 125, 2), 128, 0, stream>>>(prot, comp, inter, cp_part);

    // 14. fused regularizer MFMA + abs
    fused_mfma_abs_kernel<<<dim3(14, 8), 256, 0, stream>>>(iTb, fMb, accums + 32);

    // 15. conv/pool (+cp reduce, /S)
    convpool_kernel<<<B, 256, 0, stream>>>(cp_part, accums, conv_w, conv_b, pooled);

    // 16-20. FC stack
    fc_partial_kernel<<<dim3(10, 16), 256, 0, stream>>>(pooled, W_r1, raw1, 2048, 600, 128);
    fc_finish_kernel<true><<<(B * 600 + 255) / 256, 256, 0, stream>>>(raw1, b_r1, fc1, 600);
    fc_partial_kernel<<<dim3(5, 8), 256, 0, stream>>>(fc1, W_r2, raw2, 600, 300, 75);
    fc_finish_kernel<true><<<(B * 300 + 255) / 256, 256, 0, stream>>>(raw2, b_r2, fc2, 300);
    fc3_kernel<<<1, 512, 0, stream>>>(fc2, W_r3, b_r3, affn);

    // 21-22. group regularizer
    group_kernel<<<B * NP, 64, 0, stream>>>(contacts, s_bi, accums, groupv);
    reduce1000_kernel<<<B, 256, 0, stream>>>(groupv, accums + 40);

    // 23. final loss
    final_kernel<<<1, 64, 0, stream>>>(accums, affn, label, (float*)d_out);
}

// Round 11
// 223.691 us; speedup vs baseline: 1.7331x; 1.0666x over previous
//
#include <hip/hip_runtime.h>
#include <hip/hip_bf16.h>
#include <math.h>

// ---------------------------------------------------------------------------
#define B 8
#define NP 1000
#define NK 56
#define DP 768
#define DV 43
#define DD 256
#define NT 999

typedef __attribute__((ext_vector_type(8))) short bf16x8;
typedef __attribute__((ext_vector_type(4))) float f32x4;

__device__ inline short f2bf(float x) {
    __hip_bfloat16 h = __float2bfloat16(x);
    return __builtin_bit_cast(short, h);
}

// ---------------------------------------------------------------------------
// prep: [0,96) wcvt W_prot ; [96,128) wcvt Wjp ; [128,640) fusedcvt (tiled,
// coalesced) ; [640,670) zero region (accums 48 + raw1 4800 + raw2 2400)
// accums layout: [0..8)S [8..16)A=Sum v^2 [16..24)C=Sum v*lab [24..32)D=Sum lab^2
//                [32..40)fusedAbsRaw [40..48)unused
__global__ __launch_bounds__(256) void prep_kernel(
    const float* __restrict__ W_prot, short* __restrict__ Wb1,
    const float* __restrict__ Wjp, short* __restrict__ Wb2,
    const float* __restrict__ fusedM, short* __restrict__ fMb,
    float* __restrict__ zero_region) {
    int blk = blockIdx.x, tid = threadIdx.x;
    __shared__ float tile[16][132];
    if (blk < 96) {
        int idx = blk * 256 + tid;
        int koct = idx / DD, n = idx % DD;
        bf16x8 v;
        #pragma unroll
        for (int e = 0; e < 8; ++e)
            v[e] = f2bf(W_prot[(size_t)(koct * 8 + e) * DD + n]);
        *reinterpret_cast<bf16x8*>(Wb1 + (size_t)idx * 8) = v;
    } else if (blk < 128) {
        int idx = (blk - 96) * 256 + tid;
        int koct = idx / DD, n = idx % DD;
        bf16x8 v;
        #pragma unroll
        for (int e = 0; e < 8; ++e)
            v[e] = f2bf(Wjp[(size_t)(koct * 8 + e) * DD + n]);
        *reinterpret_cast<bf16x8*>(Wb2 + (size_t)idx * 8) = v;
    } else if (blk < 640) {
        int blk2 = blk - 128;             // 512 blocks: 64 t-tiles x 8 i-tiles
        int t0 = (blk2 >> 3) * 16;
        int i0 = (blk2 & 7) * 128;
        for (int l = tid; l < 16 * 128; l += 256) {
            int tt = l >> 7, ii = l & 127;
            int t = t0 + tt, i = i0 + ii;
            tile[tt][ii] = (t < NT && i < NP) ? fusedM[(size_t)t * NP + i] : 0.f;
        }
        __syncthreads();
        int octl = tid >> 4, tl = tid & 15;
        bf16x8 v;
        #pragma unroll
        for (int e = 0; e < 8; ++e)
            v[e] = f2bf(tile[tl][octl * 8 + e]);
        size_t oct = i0 / 8 + octl;
        *reinterpret_cast<bf16x8*>(fMb + (oct * 1024 + t0 + tl) * 8) = v;
    } else {
        int idx = (blk - 640) * 256 + tid;
        if (idx < 48 + B * 600 + B * 300) zero_region[idx] = 0.f;
    }
}

// ---------------------------------------------------------------------------
// MFMA GEMM: C = act_in(A) @ Wb + bias. Block 4 waves; tile 32(M) x 128(N).
template<bool RELU_IN>
__global__ __launch_bounds__(256) void mfma_gemm_bias_kernel(
    const float* __restrict__ A, const short* __restrict__ Wb,
    const float* __restrict__ bias, float* __restrict__ C,
    int M, int N, int K) {
    int tid = threadIdx.x;
    int lane = tid & 63, w = tid >> 6;
    int m0 = blockIdx.x * 32 + (w >> 1) * 16;
    int n0 = blockIdx.y * 128 + (w & 1) * 64;
    int lrow = lane & 15, lk = lane >> 4;
    f32x4 acc[4] = {{0.f,0.f,0.f,0.f},{0.f,0.f,0.f,0.f},
                    {0.f,0.f,0.f,0.f},{0.f,0.f,0.f,0.f}};
    const float* arow = A + (size_t)(m0 + lrow) * K + lk * 8;
    for (int k0 = 0; k0 < K; k0 += 32) {
        f32x4 a0 = *reinterpret_cast<const f32x4*>(arow + k0);
        f32x4 a1 = *reinterpret_cast<const f32x4*>(arow + k0 + 4);
        bf16x8 af;
        #pragma unroll
        for (int e = 0; e < 4; ++e) {
            float v0 = a0[e], v1 = a1[e];
            if (RELU_IN) { v0 = fmaxf(v0, 0.f); v1 = fmaxf(v1, 0.f); }
            af[e] = f2bf(v0); af[4 + e] = f2bf(v1);
        }
        const short* bbase = Wb + ((size_t)((k0 >> 3) + lk) * N + n0 + lrow) * 8;
        #pragma unroll
        for (int nt = 0; nt < 4; ++nt) {
            bf16x8 bf = *reinterpret_cast<const bf16x8*>(bbase + nt * 128);
            acc[nt] = __builtin_amdgcn_mfma_f32_16x16x32_bf16(af, bf, acc[nt], 0, 0, 0);
        }
    }
    #pragma unroll
    for (int nt = 0; nt < 4; ++nt) {
        int col = n0 + nt * 16 + lrow;
        float bv = bias[col];
        #pragma unroll
        for (int r = 0; r < 4; ++r) {
            int row = m0 + lk * 4 + r;
            C[(size_t)row * N + col] = acc[nt][r] + bv;
        }
    }
}

// ---------------------------------------------------------------------------
// Fused GCN layer: y[b,i,:] = relu( (adj@x)[b,i,:] @ W + rowsum(adj)_i * bias )
// (order-swapped: adj@(xW+b) == (adj@x)W + rs*b).  Block = (b,i), 256 thr.
__global__ __launch_bounds__(256) void gcn_layer_kernel(
    const float* __restrict__ x, const float* __restrict__ adj,
    const float* __restrict__ W, const float* __restrict__ bias,
    float* __restrict__ y, int KIN) {
    int bi = blockIdx.x;
    int b = bi / NK, i = bi % NK;
    int tid = threadIdx.x;
    __shared__ float arow[NK];
    __shared__ float u[DD];
    if (tid < NK) arow[tid] = adj[((size_t)b * NK + i) * NK + tid];
    __syncthreads();
    if (tid < KIN) {
        float a0 = 0.f, a1 = 0.f;
        for (int j = 0; j < NK; j += 2) {
            a0 = fmaf(arow[j],     x[((size_t)b * NK + j)     * KIN + tid], a0);
            a1 = fmaf(arow[j + 1], x[((size_t)b * NK + j + 1) * KIN + tid], a1);
        }
        u[tid] = a0 + a1;
    }
    float rs = 0.f;
    for (int j = 0; j < NK; ++j) rs += arow[j];
    __syncthreads();
    float a0 = 0.f, a1 = 0.f, a2 = 0.f, a3 = 0.f;
    int kk = 0;
    for (; kk + 4 <= KIN; kk += 4) {
        a0 = fmaf(u[kk],     W[(size_t)kk * DD + tid],       a0);
        a1 = fmaf(u[kk + 1], W[(size_t)(kk + 1) * DD + tid], a1);
        a2 = fmaf(u[kk + 2], W[(size_t)(kk + 2) * DD + tid], a2);
        a3 = fmaf(u[kk + 3], W[(size_t)(kk + 3) * DD + tid], a3);
    }
    for (; kk < KIN; ++kk) a0 = fmaf(u[kk], W[(size_t)kk * DD + tid], a0);
    float v = a0 + a1 + a2 + a3 + rs * bias[tid];
    y[((size_t)b * NK + i) * DD + tid] = fmaxf(v, 0.f);
}

// Fused GCN tail: layer2 (adjmul+W2) -> comp(@Wf+bf) -> qc(relu@Wjc+bjc).
__global__ __launch_bounds__(256) void gcn_tail_kernel(
    const float* __restrict__ y1, const float* __restrict__ adj,
    const float* __restrict__ W2, const float* __restrict__ b2,
    const float* __restrict__ Wf, const float* __restrict__ bf,
    const float* __restrict__ Wjc, const float* __restrict__ bjc,
    float* __restrict__ comp, float* __restrict__ qcout) {
    int bi = blockIdx.x;
    int b = bi / NK, i = bi % NK;
    int tid = threadIdx.x;
    __shared__ float arow[NK];
    __shared__ float u[DD];
    if (tid < NK) arow[tid] = adj[((size_t)b * NK + i) * NK + tid];
    __syncthreads();
    {
        float a0 = 0.f, a1 = 0.f;
        for (int j = 0; j < NK; j += 2) {
            a0 = fmaf(arow[j],     y1[((size_t)b * NK + j)     * DD + tid], a0);
            a1 = fmaf(arow[j + 1], y1[((size_t)b * NK + j + 1) * DD + tid], a1);
        }
        u[tid] = a0 + a1;
    }
    float rs = 0.f;
    for (int j = 0; j < NK; ++j) rs += arow[j];
    __syncthreads();
    // stage: y2 = relu(u @ W2 + rs*b2)
    float a0 = 0.f, a1 = 0.f, a2 = 0.f, a3 = 0.f;
    #pragma unroll 4
    for (int kk = 0; kk < DD; kk += 4) {
        a0 = fmaf(u[kk],     W2[(size_t)kk * DD + tid],       a0);
        a1 = fmaf(u[kk + 1], W2[(size_t)(kk + 1) * DD + tid], a1);
        a2 = fmaf(u[kk + 2], W2[(size_t)(kk + 2) * DD + tid], a2);
        a3 = fmaf(u[kk + 3], W2[(size_t)(kk + 3) * DD + tid], a3);
    }
    float y2 = fmaxf(a0 + a1 + a2 + a3 + rs * b2[tid], 0.f);
    __syncthreads();
    u[tid] = y2;
    __syncthreads();
    // stage: comp = y2 @ Wf + bf
    a0 = a1 = a2 = a3 = 0.f;
    #pragma unroll 4
    for (int kk = 0; kk < DD; kk += 4) {
        a0 = fmaf(u[kk],     Wf[(size_t)kk * DD + tid],       a0);
        a1 = fmaf(u[kk + 1], Wf[(size_t)(kk + 1) * DD + tid], a1);
        a2 = fmaf(u[kk + 2], Wf[(size_t)(kk + 2) * DD + tid], a2);
        a3 = fmaf(u[kk + 3], Wf[(size_t)(kk + 3) * DD + tid], a3);
    }
    float cv = a0 + a1 + a2 + a3 + bf[tid];
    comp[((size_t)b * NK + i) * DD + tid] = cv;
    __syncthreads();
    u[tid] = fmaxf(cv, 0.f);
    __syncthreads();
    // stage: qc = relu(comp) @ Wjc + bjc
    a0 = a1 = a2 = a3 = 0.f;
    #pragma unroll 4
    for (int kk = 0; kk < DD; kk += 4) {
        a0 = fmaf(u[kk],     Wjc[(size_t)kk * DD + tid],       a0);
        a1 = fmaf(u[kk + 1], Wjc[(size_t)(kk + 1) * DD + tid], a1);
        a2 = fmaf(u[kk + 2], Wjc[(size_t)(kk + 2) * DD + tid], a2);
        a3 = fmaf(u[kk + 3], Wjc[(size_t)(kk + 3) * DD + tid], a3);
    }
    qcout[((size_t)b * NK + i) * DD + tid] = a0 + a1 + a2 + a3 + bjc[tid];
}

// ---------------------------------------------------------------------------
// inter_all: raw inter = sigmoid(qp.qc); accumulate S,A,C,D; s_bi raw; iTb bf16.
__global__ __launch_bounds__(256) void inter_all_kernel(
    const float* __restrict__ qp, const float* __restrict__ qc,
    const float* __restrict__ prot_inter, const float* __restrict__ exist,
    float* __restrict__ inter, float* __restrict__ s_bi,
    short* __restrict__ iTb, float* __restrict__ accums) {
    int b = blockIdx.x / 125, chunk = blockIdx.x % 125;
    __shared__ float qcT[DD * 57];
    __shared__ float vS[8][57];
    __shared__ float wred[4][4];
    int tid = threadIdx.x;
    for (int l = tid; l < NK * DD; l += 256) {
        int k = l / DD, d = l % DD;
        qcT[d * 57 + k] = qc[((size_t)b * NK + k) * DD + d];
    }
    __syncthreads();
    int w = tid >> 6, lane = tid & 63;
    float ex = exist[b];
    float aV = 0.f, aA = 0.f, aC = 0.f, aD = 0.f;
    for (int ii = 0; ii < 2; ++ii) {
        int i = chunk * 8 + w * 2 + ii;
        float v = 0.f, lab = 0.f;
        if (lane < NK) {
            const float* qrow = qp + ((size_t)b * NP + i) * DD;
            float acc = 0.f;
            for (int d = 0; d < DD; ++d)
                acc = fmaf(qrow[d], qcT[d * 57 + lane], acc);
            v = 1.f / (1.f + __expf(-acc));
            lab = ex * prot_inter[((size_t)b * NP + i) * NK + lane];
            inter[((size_t)b * NP + i) * NK + lane] = v;
            vS[w * 2 + ii][lane] = v;
        }
        float v2 = v * v;
        float r = v2;
        #pragma unroll
        for (int off = 32; off; off >>= 1) r += __shfl_down(r, off);
        if (lane == 0) s_bi[(size_t)b * NP + i] = r;
        aV += v; aA += v2; aC += v * lab; aD += lab * lab;
    }
    #pragma unroll
    for (int off = 32; off; off >>= 1) {
        aV += __shfl_down(aV, off);
        aA += __shfl_down(aA, off);
        aC += __shfl_down(aC, off);
        aD += __shfl_down(aD, off);
    }
    if (lane == 0) {
        wred[w][0] = aV; wred[w][1] = aA; wred[w][2] = aC; wred[w][3] = aD;
    }
    __syncthreads();
    if (tid < 4) {
        float s = wred[0][tid] + wred[1][tid] + wred[2][tid] + wred[3][tid];
        atomicAdd(&accums[tid * 8 + b], s);
    }
    if (tid < NK) {
        bf16x8 pk;
        #pragma unroll
        for (int e = 0; e < 8; ++e) pk[e] = f2bf(vS[e][tid]);
        *reinterpret_cast<bf16x8*>(iTb + ((size_t)chunk * 448 + b * NK + tid) * 8) = pk;
        if (chunk == 124) {
            bf16x8 z = {0,0,0,0,0,0,0,0};
            #pragma unroll
            for (int oct = 125; oct < 128; ++oct)
                *reinterpret_cast<bf16x8*>(iTb + ((size_t)oct * 448 + b * NK + tid) * 8) = z;
        }
    }
}

// ---------------------------------------------------------------------------
// cp partials: raw inter (1/S folded later).  t = 1 - 2*rcp(exp2(p*2log2e*c)+1)
__global__ __launch_bounds__(128) void cp_partial_kernel(
    const float* __restrict__ prot, const float* __restrict__ comp,
    const float* __restrict__ inter, float* __restrict__ part) {
    int bc = blockIdx.x;
    int b = bc / 125, chunk = bc % 125;
    int dh = blockIdx.y;
    int tid = threadIdx.x;
    int d = dh * 128 + tid;
    __shared__ float irow[8][NK];
    float creg[NK];
    #pragma unroll
    for (int k = 0; k < NK; ++k)
        creg[k] = comp[((size_t)b * NK + k) * DD + d];
    for (int l = tid; l < 8 * NK; l += 128) {
        int ii = l / NK, k = l % NK;
        irow[ii][k] = inter[((size_t)b * NP + chunk * 8 + ii) * NK + k];
    }
    const float C2LOG2E = 2.8853900817779268f;
    float p2l[8];
    #pragma unroll
    for (int ii = 0; ii < 8; ++ii)
        p2l[ii] = C2LOG2E * prot[((size_t)b * NP + chunk * 8 + ii) * DD + d];
    __syncthreads();
    float acc0 = 0.f, acc1 = 0.f;
    #pragma unroll 1
    for (int ii = 0; ii < 8; ++ii) {
        float p = p2l[ii];
        #pragma unroll
        for (int k = 0; k < NK; k += 2) {
            float e0 = __builtin_amdgcn_exp2f(p * creg[k]);
            float e1 = __builtin_amdgcn_exp2f(p * creg[k + 1]);
            float r0 = __builtin_amdgcn_rcpf(e0 + 1.f);
            float r1 = __builtin_amdgcn_rcpf(e1 + 1.f);
            acc0 = fmaf(fmaf(-2.f, r0, 1.f), irow[ii][k],     acc0);
            acc1 = fmaf(fmaf(-2.f, r1, 1.f), irow[ii][k + 1], acc1);
        }
    }
    part[((size_t)b * 125 + chunk) * DD + d] = acc0 + acc1;
}

// ---------------------------------------------------------------------------
// fused reg MFMA: E = iT @ fM^T ; fusedAbsRaw[b] += sum|E|  (1/S folded at final)
__global__ __launch_bounds__(256) void fused_mfma_abs_kernel(
    const short* __restrict__ iTb, const short* __restrict__ fMb,
    float* __restrict__ fusedAbs) {
    __shared__ float sb[8];
    int tid = threadIdx.x;
    int lane = tid & 63, w = tid >> 6;
    if (tid < 8) sb[tid] = 0.f;
    __syncthreads();
    int m0 = blockIdx.x * 32 + (w >> 1) * 16;
    int n0 = blockIdx.y * 128 + (w & 1) * 64;
    int lrow = lane & 15, lk = lane >> 4;
    f32x4 acc[4] = {{0.f,0.f,0.f,0.f},{0.f,0.f,0.f,0.f},
                    {0.f,0.f,0.f,0.f},{0.f,0.f,0.f,0.f}};
    for (int koct0 = 0; koct0 < 128; koct0 += 4) {
        int koct = koct0 + lk;
        bf16x8 af = *reinterpret_cast<const bf16x8*>(
            iTb + ((size_t)koct * 448 + m0 + lrow) * 8);
        const short* bb = fMb + ((size_t)koct * 1024 + n0 + lrow) * 8;
        #pragma unroll
        for (int nt = 0; nt < 4; ++nt) {
            bf16x8 bf = *reinterpret_cast<const bf16x8*>(bb + nt * 128);
            acc[nt] = __builtin_amdgcn_mfma_f32_16x16x32_bf16(af, bf, acc[nt], 0, 0, 0);
        }
    }
    #pragma unroll
    for (int r = 0; r < 4; ++r) {
        float part = fabsf(acc[0][r]) + fabsf(acc[1][r]) +
                     fabsf(acc[2][r]) + fabsf(acc[3][r]);
        #pragma unroll
        for (int off = 1; off < 16; off <<= 1)
            part += __shfl_xor(part, off);
        if (lrow == 0) {
            int row = m0 + lk * 4 + r;
            atomicAdd(&sb[row / NK], part);
        }
    }
    __syncthreads();
    if (tid < 8 && sb[tid] != 0.f) atomicAdd(&fusedAbs[tid], sb[tid]);
}

// ---------------------------------------------------------------------------
// convpool: per-batch block 256 thr. cp_reduce + /S + conv + bias + leaky + pool.
__global__ __launch_bounds__(256) void convpool_kernel(
    const float* __restrict__ cp_part, const float* __restrict__ accums,
    const float* __restrict__ conv_w, const float* __restrict__ conv_b,
    float* __restrict__ pooled) {
    int b = blockIdx.x, t = threadIdx.x;
    __shared__ float xS[258];
    __shared__ float convo[8192];
    float invS = 1.f / accums[b];
    float s = 0.f;
    for (int c = 0; c < 125; ++c) s += cp_part[((size_t)b * 125 + c) * DD + t];
    xS[t + 1] = s * invS;
    if (t == 0) { xS[0] = 0.f; xS[257] = 0.f; }
    __syncthreads();
    for (int l = t; l < 8192; l += 256) {
        int o = l >> 7, pos = l & 127;
        float acc = conv_b[o];
        int base = pos * 2;
        #pragma unroll
        for (int h = 0; h < 4; ++h)
            acc = fmaf(xS[base + h], conv_w[o * 4 + h], acc);
        convo[l] = (acc > 0.f) ? acc : 0.1f * acc;
    }
    __syncthreads();
    for (int l = t; l < 2048; l += 256) {
        int o = l >> 5, p = l & 31;
        float m = convo[o * 128 + p * 4];
        m = fmaxf(m, convo[o * 128 + p * 4 + 1]);
        m = fmaxf(m, convo[o * 128 + p * 4 + 2]);
        m = fmaxf(m, convo[o * 128 + p * 4 + 3]);
        pooled[b * 2048 + l] = m;
    }
}

// ---------------------------------------------------------------------------
// FC partial: grid (o_tiles, k_splits). If FIN, staging applies bias+leaky to
// the raw input (folds the former fc_finish into this kernel's load).
template<bool FIN>
__global__ __launch_bounds__(256) void fc_partial_kernel(
    const float* __restrict__ in, const float* __restrict__ bias_in,
    const float* __restrict__ W, float* __restrict__ raw,
    int K, int N, int kchunk) {
    int t = threadIdx.x;
    int ol = t & 63;
    int o = blockIdx.x * 64 + ol;
    int w = t >> 6;
    int kbeg = blockIdx.y * kchunk;
    int kend = kbeg + kchunk; if (kend > K) kend = K;
    int len = kend - kbeg;
    __shared__ float sin_[B][128];
    for (int l = t; l < B * len; l += 256) {
        int b = l / len, k = l % len;
        float v = in[(size_t)b * K + kbeg + k];
        if (FIN) {
            v += bias_in[kbeg + k];
            v = (v > 0.f) ? v : 0.1f * v;
        }
        sin_[b][k] = v;
    }
    __syncthreads();
    float acc[B];
    #pragma unroll
    for (int b = 0; b < B; ++b) acc[b] = 0.f;
    if (o < N) {
        for (int k = kbeg + w; k < kend; k += 4) {
            float wv = W[(size_t)k * N + o];
            int kl = k - kbeg;
            #pragma unroll
            for (int b = 0; b < B; ++b)
                acc[b] = fmaf(sin_[b][kl], wv, acc[b]);
        }
    }
    __shared__ float red[4][64][B];
    #pragma unroll
    for (int b = 0; b < B; ++b) red[w][ol][b] = acc[b];
    __syncthreads();
    for (int p = t; p < 64 * B; p += 256) {
        int oo = p / B, b = p % B;
        int o2 = blockIdx.x * 64 + oo;
        if (o2 < N) {
            float s = red[0][oo][b] + red[1][oo][b] + red[2][oo][b] + red[3][oo][b];
            atomicAdd(&raw[(size_t)b * N + o2], s);
        }
    }
}

// fc3: reads raw2, applies b_r2+leaky inline, dot with W_r3, + b_r3.
__global__ __launch_bounds__(512) void fc3_kernel(
    const float* __restrict__ raw2, const float* __restrict__ b_r2,
    const float* __restrict__ W3, const float* __restrict__ b3,
    float* __restrict__ affn) {
    int wv = threadIdx.x >> 6, lane = threadIdx.x & 63;
    float acc = 0.f;
    for (int k = lane; k < 300; k += 64) {
        float v = raw2[(size_t)wv * 300 + k] + b_r2[k];
        v = (v > 0.f) ? v : 0.1f * v;
        acc = fmaf(v, W3[k], acc);
    }
    #pragma unroll
    for (int off = 32; off; off >>= 1) acc += __shfl_down(acc, off);
    if (lane == 0) affn[wv] = acc + b3[0];
}

// ---------------------------------------------------------------------------
// group: g_raw = contacts.s_bi_raw ; store sqrt(g)/S*sqrt(rs) to groupv[bk].
__global__ __launch_bounds__(64) void group_kernel(
    const float* __restrict__ contacts, const float* __restrict__ s_bi,
    const float* __restrict__ accums, float* __restrict__ groupv) {
    int bk = blockIdx.x;
    int b = bk / NP, k = bk % NP;
    const float* row = contacts + ((size_t)b * NP + k) * NP;
    const float* sv = s_bi + b * NP;
    float g = 0.f, rs = 0.f;
    for (int i = threadIdx.x; i < NP; i += 64) {
        float c = row[i];
        g = fmaf(c, sv[i], g);
        rs += c;
    }
    #pragma unroll
    for (int off = 32; off; off >>= 1) {
        g += __shfl_down(g, off);
        rs += __shfl_down(rs, off);
    }
    if (threadIdx.x == 0) {
        float val;
        if (g == 0.f) val = sqrtf(1e10f) * sqrtf(rs);
        else          val = sqrtf(g) / accums[b] * sqrtf(rs);
        groupv[bk] = val;
    }
}

// ---------------------------------------------------------------------------
// final: sum groupv (8000) + per-b loss assembly.
__global__ __launch_bounds__(256) void final_kernel(
    const float* __restrict__ accums, const float* __restrict__ groupv,
    const float* __restrict__ affn, const float* __restrict__ label,
    float* __restrict__ out) {
    int tid = threadIdx.x;
    float s = 0.f;
    for (int l = tid; l < B * NP; l += 256) s += groupv[l];
    __shared__ float r[256];
    r[tid] = s;
    __syncthreads();
    for (int st = 128; st; st >>= 1) {
        if (tid < st) r[tid] += r[tid + st];
        __syncthreads();
    }
    if (tid == 0) {
        float gtot = r[0];
        float l0 = 0.f, l1 = 0.f, l2 = 0.f;
        for (int b = 0; b < B; ++b) {
            float S = accums[b];
            float A = accums[8 + b], C = accums[16 + b], D = accums[24 + b];
            float fA = accums[32 + b];
            l0 += 1.f + fA / S;
            float bind = A / (S * S) - 2.f * C / S + D;
            l1 += sqrtf(fmaxf(bind, 0.f));
            float dd = affn[b] - label[b];
            l2 += dd * dd;
        }
        out[0] = (l0 + gtot + l1 + l2) * 0.125f;
    }
}

// ---------------------------------------------------------------------------
extern "C" void kernel_launch(void* const* d_in, const int* in_sizes, int n_in,
                              void* d_out, int out_size, void* d_ws, size_t ws_size,
                              hipStream_t stream) {
    const float* prot_data   = (const float*)d_in[0];
    const float* drug_ver    = (const float*)d_in[1];
    const float* drug_adj    = (const float*)d_in[2];
    const float* contacts    = (const float*)d_in[3];
    const float* prot_inter  = (const float*)d_in[4];
    const float* exist       = (const float*)d_in[5];
    const float* label       = (const float*)d_in[6];
    const float* fused       = (const float*)d_in[7];
    const float* W_prot      = (const float*)d_in[8];
    const float* b_prot      = (const float*)d_in[9];
    const float* gcn_W0      = (const float*)d_in[10];
    const float* gcn_b0      = (const float*)d_in[11];
    const float* gcn_W1      = (const float*)d_in[12];
    const float* gcn_b1      = (const float*)d_in[13];
    const float* gcn_W2      = (const float*)d_in[14];
    const float* gcn_b2      = (const float*)d_in[15];
    const float* gcn_Wf      = (const float*)d_in[16];
    const float* gcn_bf      = (const float*)d_in[17];
    const float* Wjp         = (const float*)d_in[18];
    const float* bjp         = (const float*)d_in[19];
    const float* Wjc         = (const float*)d_in[20];
    const float* bjc         = (const float*)d_in[21];
    const float* conv_w      = (const float*)d_in[22];
    const float* conv_b      = (const float*)d_in[23];
    const float* W_r1        = (const float*)d_in[24];
    const float* b_r1        = (const float*)d_in[25];
    const float* W_r2        = (const float*)d_in[26];
    const float* b_r2        = (const float*)d_in[27];
    const float* W_r3        = (const float*)d_in[28];
    const float* b_r3        = (const float*)d_in[29];

    float* ws = (float*)d_ws;
    size_t off = 0;
    auto alloc = [&](size_t n) { float* p = ws + off; off += n; return p; };
    float* prot     = alloc((size_t)B * NP * DD);
    float* qp       = alloc((size_t)B * NP * DD);
    float* tbuf     = alloc((size_t)B * NK * DD);   // y0; +ybuf = iTb alias
    float* ybuf     = alloc((size_t)B * NK * DD);   // y1
    float* comp     = alloc((size_t)B * NK * DD);
    float* qc       = alloc((size_t)B * NK * DD);
    float* inter    = alloc((size_t)B * NP * NK);
    float* s_bi     = alloc((size_t)B * NP);
    float* cp_part  = alloc((size_t)B * 125 * DD);
    float* pooled   = alloc((size_t)B * 2048);
    float* affn     = alloc((size_t)B);
    float* groupv   = alloc((size_t)B * NP);
    short* Wb1      = (short*)alloc((DP / 8) * DD * 8 / 2);
    short* Wb2      = (short*)alloc((DD / 8) * DD * 8 / 2);
    short* fMb      = (short*)alloc((size_t)128 * 1024 * 8 / 2);
    // zero region: accums(48) + raw1(4800) + raw2(2400), contiguous
    float* accums   = alloc(48);
    float* raw1     = alloc((size_t)B * 600);
    float* raw2     = alloc((size_t)B * 300);

    // iTb[128][448][8] bf16 = 229,376 f32-equiv, aliases tbuf+ybuf (dead after GCN)
    short* iTb = (short*)tbuf;
    (void)ybuf;

    // 1. prep: weight cvts + fused cvt (coalesced) + zero region
    prep_kernel<<<670, 256, 0, stream>>>(W_prot, Wb1, Wjp, Wb2, fused, fMb, accums);

    // 2. prot = prot_data @ W_prot + b_prot   (bf16 MFMA)
    mfma_gemm_bias_kernel<false><<<dim3(250, 2), 256, 0, stream>>>(
        prot_data, Wb1, b_prot, prot, B * NP, DD, DP);

    // 3-5. GCN stack (order-swapped fused layers)
    gcn_layer_kernel<<<B * NK, 256, 0, stream>>>(drug_ver, drug_adj, gcn_W0, gcn_b0, tbuf, DV);
    gcn_layer_kernel<<<B * NK, 256, 0, stream>>>(tbuf, drug_adj, gcn_W1, gcn_b1, ybuf, DD);
    gcn_tail_kernel<<<B * NK, 256, 0, stream>>>(ybuf, drug_adj, gcn_W2, gcn_b2,
                                                gcn_Wf, gcn_bf, Wjc, bjc, comp, qc);

    // 6. qp = relu(prot) @ Wjp + bjp   (bf16 MFMA)
    mfma_gemm_bias_kernel<true><<<dim3(250, 2), 256, 0, stream>>>(
        prot, Wb2, bjp, qp, B * NP, DD, DD);

    // 7. inter (raw) + moments + s_bi + iTb
    inter_all_kernel<<<B * 125, 256, 0, stream>>>(
        qp, qc, prot_inter, exist, inter, s_bi, iTb, accums);

    // 8. cp partials (raw inter)
    cp_partial_kernel<<<dim3(B * 125, 2), 128, 0, stream>>>(prot, comp, inter, cp_part);

    // 9. fused regularizer MFMA + abs
    fused_mfma_abs_kernel<<<dim3(14, 8), 256, 0, stream>>>(iTb, fMb, accums + 32);

    // 10. conv/pool (+cp reduce, /S)
    convpool_kernel<<<B, 256, 0, stream>>>(cp_part, accums, conv_w, conv_b, pooled);

    // 11-13. FC stack (finish folded into next stage's staging)
    fc_partial_kernel<false><<<dim3(10, 16), 256, 0, stream>>>(
        pooled, nullptr, W_r1, raw1, 2048, 600, 128);
    fc_partial_kernel<true><<<dim3(5, 8), 256, 0, stream>>>(
        raw1, b_r1, W_r2, raw2, 600, 300, 75);
    fc3_kernel<<<1, 512, 0, stream>>>(raw2, b_r2, W_r3, b_r3, affn);

    // 14. group regularizer
    group_kernel<<<B * NP, 64, 0, stream>>>(contacts, s_bi, accums, groupv);

    // 15. final loss (merged group-sum + assembly)
    final_kernel<<<1, 256, 0, stream>>>(accums, groupv, affn, label, (float*)d_out);
}

// Round 12
// 216.055 us; speedup vs baseline: 1.7943x; 1.0353x over previous
//
#include <hip/hip_runtime.h>
#include <hip/hip_bf16.h>
#include <math.h>

// ---------------------------------------------------------------------------
#define B 8
#define NP 1000
#define NK 56
#define DP 768
#define DV 43
#define DD 256
#define NT 999

typedef __attribute__((ext_vector_type(8))) short bf16x8;
typedef __attribute__((ext_vector_type(4))) float f32x4;

__device__ inline short f2bf(float x) {
    __hip_bfloat16 h = __float2bfloat16(x);
    return __builtin_bit_cast(short, h);
}

// ---------------------------------------------------------------------------
// prep: [0,96) wcvt W_prot ; [96,128) wcvt Wjp ; [128,640) fusedcvt (tiled,
// coalesced) ; [640,670) zero region (accums 48 + raw1 4800 + raw2 2400)
// accums layout: [0..8)S [8..16)A=Sum v^2 [16..24)C=Sum v*lab [24..32)D=Sum lab^2
//                [32..40)fusedAbsRaw [40..48)unused
__global__ __launch_bounds__(256) void prep_kernel(
    const float* __restrict__ W_prot, short* __restrict__ Wb1,
    const float* __restrict__ Wjp, short* __restrict__ Wb2,
    const float* __restrict__ fusedM, short* __restrict__ fMb,
    float* __restrict__ zero_region) {
    int blk = blockIdx.x, tid = threadIdx.x;
    __shared__ float tile[16][132];
    if (blk < 96) {
        int idx = blk * 256 + tid;
        int koct = idx / DD, n = idx % DD;
        bf16x8 v;
        #pragma unroll
        for (int e = 0; e < 8; ++e)
            v[e] = f2bf(W_prot[(size_t)(koct * 8 + e) * DD + n]);
        *reinterpret_cast<bf16x8*>(Wb1 + (size_t)idx * 8) = v;
    } else if (blk < 128) {
        int idx = (blk - 96) * 256 + tid;
        int koct = idx / DD, n = idx % DD;
        bf16x8 v;
        #pragma unroll
        for (int e = 0; e < 8; ++e)
            v[e] = f2bf(Wjp[(size_t)(koct * 8 + e) * DD + n]);
        *reinterpret_cast<bf16x8*>(Wb2 + (size_t)idx * 8) = v;
    } else if (blk < 640) {
        int blk2 = blk - 128;             // 512 blocks: 64 t-tiles x 8 i-tiles
        int t0 = (blk2 >> 3) * 16;
        int i0 = (blk2 & 7) * 128;
        for (int l = tid; l < 16 * 128; l += 256) {
            int tt = l >> 7, ii = l & 127;
            int t = t0 + tt, i = i0 + ii;
            tile[tt][ii] = (t < NT && i < NP) ? fusedM[(size_t)t * NP + i] : 0.f;
        }
        __syncthreads();
        int octl = tid >> 4, tl = tid & 15;
        bf16x8 v;
        #pragma unroll
        for (int e = 0; e < 8; ++e)
            v[e] = f2bf(tile[tl][octl * 8 + e]);
        size_t oct = i0 / 8 + octl;
        *reinterpret_cast<bf16x8*>(fMb + (oct * 1024 + t0 + tl) * 8) = v;
    } else {
        int idx = (blk - 640) * 256 + tid;
        if (idx < 48 + B * 600 + B * 300) zero_region[idx] = 0.f;
    }
}

// ---------------------------------------------------------------------------
// MFMA GEMM: C = act_in(A) @ Wb + bias. Block 4 waves; tile 32(M) x 128(N).
template<bool RELU_IN>
__global__ __launch_bounds__(256) void mfma_gemm_bias_kernel(
    const float* __restrict__ A, const short* __restrict__ Wb,
    const float* __restrict__ bias, float* __restrict__ C,
    int M, int N, int K) {
    int tid = threadIdx.x;
    int lane = tid & 63, w = tid >> 6;
    int m0 = blockIdx.x * 32 + (w >> 1) * 16;
    int n0 = blockIdx.y * 128 + (w & 1) * 64;
    int lrow = lane & 15, lk = lane >> 4;
    f32x4 acc[4] = {{0.f,0.f,0.f,0.f},{0.f,0.f,0.f,0.f},
                    {0.f,0.f,0.f,0.f},{0.f,0.f,0.f,0.f}};
    const float* arow = A + (size_t)(m0 + lrow) * K + lk * 8;
    for (int k0 = 0; k0 < K; k0 += 32) {
        f32x4 a0 = *reinterpret_cast<const f32x4*>(arow + k0);
        f32x4 a1 = *reinterpret_cast<const f32x4*>(arow + k0 + 4);
        bf16x8 af;
        #pragma unroll
        for (int e = 0; e < 4; ++e) {
            float v0 = a0[e], v1 = a1[e];
            if (RELU_IN) { v0 = fmaxf(v0, 0.f); v1 = fmaxf(v1, 0.f); }
            af[e] = f2bf(v0); af[4 + e] = f2bf(v1);
        }
        const short* bbase = Wb + ((size_t)((k0 >> 3) + lk) * N + n0 + lrow) * 8;
        #pragma unroll
        for (int nt = 0; nt < 4; ++nt) {
            bf16x8 bf = *reinterpret_cast<const bf16x8*>(bbase + nt * 128);
            acc[nt] = __builtin_amdgcn_mfma_f32_16x16x32_bf16(af, bf, acc[nt], 0, 0, 0);
        }
    }
    #pragma unroll
    for (int nt = 0; nt < 4; ++nt) {
        int col = n0 + nt * 16 + lrow;
        float bv = bias[col];
        #pragma unroll
        for (int r = 0; r < 4; ++r) {
            int row = m0 + lk * 4 + r;
            C[(size_t)row * N + col] = acc[nt][r] + bv;
        }
    }
}

// ---------------------------------------------------------------------------
// Fused GCN layer: y[b,i,:] = relu( (adj@x)[b,i,:] @ W + rowsum(adj)_i * bias )
__global__ __launch_bounds__(256) void gcn_layer_kernel(
    const float* __restrict__ x, const float* __restrict__ adj,
    const float* __restrict__ W, const float* __restrict__ bias,
    float* __restrict__ y, int KIN) {
    int bi = blockIdx.x;
    int b = bi / NK, i = bi % NK;
    int tid = threadIdx.x;
    __shared__ float arow[NK];
    __shared__ float u[DD];
    if (tid < NK) arow[tid] = adj[((size_t)b * NK + i) * NK + tid];
    __syncthreads();
    if (tid < KIN) {
        float a0 = 0.f, a1 = 0.f;
        for (int j = 0; j < NK; j += 2) {
            a0 = fmaf(arow[j],     x[((size_t)b * NK + j)     * KIN + tid], a0);
            a1 = fmaf(arow[j + 1], x[((size_t)b * NK + j + 1) * KIN + tid], a1);
        }
        u[tid] = a0 + a1;
    }
    float rs = 0.f;
    for (int j = 0; j < NK; ++j) rs += arow[j];
    __syncthreads();
    float a0 = 0.f, a1 = 0.f, a2 = 0.f, a3 = 0.f;
    int kk = 0;
    for (; kk + 4 <= KIN; kk += 4) {
        a0 = fmaf(u[kk],     W[(size_t)kk * DD + tid],       a0);
        a1 = fmaf(u[kk + 1], W[(size_t)(kk + 1) * DD + tid], a1);
        a2 = fmaf(u[kk + 2], W[(size_t)(kk + 2) * DD + tid], a2);
        a3 = fmaf(u[kk + 3], W[(size_t)(kk + 3) * DD + tid], a3);
    }
    for (; kk < KIN; ++kk) a0 = fmaf(u[kk], W[(size_t)kk * DD + tid], a0);
    float v = a0 + a1 + a2 + a3 + rs * bias[tid];
    y[((size_t)b * NK + i) * DD + tid] = fmaxf(v, 0.f);
}

// Fused GCN tail: layer2 (adjmul+W2) -> comp(@Wf+bf) -> qc(relu@Wjc+bjc).
__global__ __launch_bounds__(256) void gcn_tail_kernel(
    const float* __restrict__ y1, const float* __restrict__ adj,
    const float* __restrict__ W2, const float* __restrict__ b2,
    const float* __restrict__ Wf, const float* __restrict__ bf,
    const float* __restrict__ Wjc, const float* __restrict__ bjc,
    float* __restrict__ comp, float* __restrict__ qcout) {
    int bi = blockIdx.x;
    int b = bi / NK, i = bi % NK;
    int tid = threadIdx.x;
    __shared__ float arow[NK];
    __shared__ float u[DD];
    if (tid < NK) arow[tid] = adj[((size_t)b * NK + i) * NK + tid];
    __syncthreads();
    {
        float a0 = 0.f, a1 = 0.f;
        for (int j = 0; j < NK; j += 2) {
            a0 = fmaf(arow[j],     y1[((size_t)b * NK + j)     * DD + tid], a0);
            a1 = fmaf(arow[j + 1], y1[((size_t)b * NK + j + 1) * DD + tid], a1);
        }
        u[tid] = a0 + a1;
    }
    float rs = 0.f;
    for (int j = 0; j < NK; ++j) rs += arow[j];
    __syncthreads();
    float a0 = 0.f, a1 = 0.f, a2 = 0.f, a3 = 0.f;
    #pragma unroll 4
    for (int kk = 0; kk < DD; kk += 4) {
        a0 = fmaf(u[kk],     W2[(size_t)kk * DD + tid],       a0);
        a1 = fmaf(u[kk + 1], W2[(size_t)(kk + 1) * DD + tid], a1);
        a2 = fmaf(u[kk + 2], W2[(size_t)(kk + 2) * DD + tid], a2);
        a3 = fmaf(u[kk + 3], W2[(size_t)(kk + 3) * DD + tid], a3);
    }
    float y2 = fmaxf(a0 + a1 + a2 + a3 + rs * b2[tid], 0.f);
    __syncthreads();
    u[tid] = y2;
    __syncthreads();
    a0 = a1 = a2 = a3 = 0.f;
    #pragma unroll 4
    for (int kk = 0; kk < DD; kk += 4) {
        a0 = fmaf(u[kk],     Wf[(size_t)kk * DD + tid],       a0);
        a1 = fmaf(u[kk + 1], Wf[(size_t)(kk + 1) * DD + tid], a1);
        a2 = fmaf(u[kk + 2], Wf[(size_t)(kk + 2) * DD + tid], a2);
        a3 = fmaf(u[kk + 3], Wf[(size_t)(kk + 3) * DD + tid], a3);
    }
    float cv = a0 + a1 + a2 + a3 + bf[tid];
    comp[((size_t)b * NK + i) * DD + tid] = cv;
    __syncthreads();
    u[tid] = fmaxf(cv, 0.f);
    __syncthreads();
    a0 = a1 = a2 = a3 = 0.f;
    #pragma unroll 4
    for (int kk = 0; kk < DD; kk += 4) {
        a0 = fmaf(u[kk],     Wjc[(size_t)kk * DD + tid],       a0);
        a1 = fmaf(u[kk + 1], Wjc[(size_t)(kk + 1) * DD + tid], a1);
        a2 = fmaf(u[kk + 2], Wjc[(size_t)(kk + 2) * DD + tid], a2);
        a3 = fmaf(u[kk + 3], Wjc[(size_t)(kk + 3) * DD + tid], a3);
    }
    qcout[((size_t)b * NK + i) * DD + tid] = a0 + a1 + a2 + a3 + bjc[tid];
}

// ---------------------------------------------------------------------------
// inter_all v2: both operands LDS-staged; d-outer loop, shared qcT read,
// 2 rows per wave. No global access in the hot loop.
__global__ __launch_bounds__(256) void inter_all_kernel(
    const float* __restrict__ qp, const float* __restrict__ qc,
    const float* __restrict__ prot_inter, const float* __restrict__ exist,
    float* __restrict__ inter, float* __restrict__ s_bi,
    short* __restrict__ iTb, float* __restrict__ accums) {
    int b = blockIdx.x / 125, chunk = blockIdx.x % 125;
    __shared__ float qcT[DD * 57];     // [d][k], pad 57
    __shared__ float qpS[8][DD];
    __shared__ float vS[8][57];
    __shared__ float wred[4][4];
    int tid = threadIdx.x;
    for (int l = tid; l < NK * DD; l += 256) {
        int k = l / DD, d = l % DD;
        qcT[d * 57 + k] = qc[((size_t)b * NK + k) * DD + d];
    }
    for (int l = tid; l < 8 * DD; l += 256) {
        int r = l >> 8, d = l & 255;
        qpS[r][d] = qp[((size_t)b * NP + chunk * 8 + r) * DD + d];
    }
    __syncthreads();
    int w = tid >> 6, lane = tid & 63;
    float ex = exist[b];
    int r0 = w * 2, r1 = w * 2 + 1;
    float acc0 = 0.f, acc1 = 0.f;
    if (lane < NK) {
        #pragma unroll 8
        for (int d = 0; d < DD; ++d) {
            float c = qcT[d * 57 + lane];
            acc0 = fmaf(qpS[r0][d], c, acc0);
            acc1 = fmaf(qpS[r1][d], c, acc1);
        }
    }
    float aV = 0.f, aA = 0.f, aC = 0.f, aD = 0.f;
    #pragma unroll
    for (int ii = 0; ii < 2; ++ii) {
        int i = chunk * 8 + w * 2 + ii;
        float v = 0.f, lab = 0.f;
        if (lane < NK) {
            float acc = (ii == 0) ? acc0 : acc1;
            v = 1.f / (1.f + __expf(-acc));
            lab = ex * prot_inter[((size_t)b * NP + i) * NK + lane];
            inter[((size_t)b * NP + i) * NK + lane] = v;
            vS[w * 2 + ii][lane] = v;
        }
        float v2 = v * v;
        float r = v2;
        #pragma unroll
        for (int off = 32; off; off >>= 1) r += __shfl_down(r, off);
        if (lane == 0) s_bi[(size_t)b * NP + i] = r;
        aV += v; aA += v2; aC += v * lab; aD += lab * lab;
    }
    #pragma unroll
    for (int off = 32; off; off >>= 1) {
        aV += __shfl_down(aV, off);
        aA += __shfl_down(aA, off);
        aC += __shfl_down(aC, off);
        aD += __shfl_down(aD, off);
    }
    if (lane == 0) {
        wred[w][0] = aV; wred[w][1] = aA; wred[w][2] = aC; wred[w][3] = aD;
    }
    __syncthreads();
    if (tid < 4) {
        float s = wred[0][tid] + wred[1][tid] + wred[2][tid] + wred[3][tid];
        atomicAdd(&accums[tid * 8 + b], s);
    }
    if (tid < NK) {
        bf16x8 pk;
        #pragma unroll
        for (int e = 0; e < 8; ++e) pk[e] = f2bf(vS[e][tid]);
        *reinterpret_cast<bf16x8*>(iTb + ((size_t)chunk * 448 + b * NK + tid) * 8) = pk;
        if (chunk == 124) {
            bf16x8 z = {0,0,0,0,0,0,0,0};
            #pragma unroll
            for (int oct = 125; oct < 128; ++oct)
                *reinterpret_cast<bf16x8*>(iTb + ((size_t)oct * 448 + b * NK + tid) * 8) = z;
        }
    }
}

// ---------------------------------------------------------------------------
// cp partials: raw inter (1/S folded later).  t = 1 - 2*rcp(exp2(p*2log2e*c)+1)
__global__ __launch_bounds__(128) void cp_partial_kernel(
    const float* __restrict__ prot, const float* __restrict__ comp,
    const float* __restrict__ inter, float* __restrict__ part) {
    int bc = blockIdx.x;
    int b = bc / 125, chunk = bc % 125;
    int dh = blockIdx.y;
    int tid = threadIdx.x;
    int d = dh * 128 + tid;
    __shared__ float irow[8][NK];
    float creg[NK];
    #pragma unroll
    for (int k = 0; k < NK; ++k)
        creg[k] = comp[((size_t)b * NK + k) * DD + d];
    for (int l = tid; l < 8 * NK; l += 128) {
        int ii = l / NK, k = l % NK;
        irow[ii][k] = inter[((size_t)b * NP + chunk * 8 + ii) * NK + k];
    }
    const float C2LOG2E = 2.8853900817779268f;
    float p2l[8];
    #pragma unroll
    for (int ii = 0; ii < 8; ++ii)
        p2l[ii] = C2LOG2E * prot[((size_t)b * NP + chunk * 8 + ii) * DD + d];
    __syncthreads();
    float acc0 = 0.f, acc1 = 0.f;
    #pragma unroll 1
    for (int ii = 0; ii < 8; ++ii) {
        float p = p2l[ii];
        #pragma unroll
        for (int k = 0; k < NK; k += 2) {
            float e0 = __builtin_amdgcn_exp2f(p * creg[k]);
            float e1 = __builtin_amdgcn_exp2f(p * creg[k + 1]);
            float r0 = __builtin_amdgcn_rcpf(e0 + 1.f);
            float r1 = __builtin_amdgcn_rcpf(e1 + 1.f);
            acc0 = fmaf(fmaf(-2.f, r0, 1.f), irow[ii][k],     acc0);
            acc1 = fmaf(fmaf(-2.f, r1, 1.f), irow[ii][k + 1], acc1);
        }
    }
    part[((size_t)b * 125 + chunk) * DD + d] = acc0 + acc1;
}

// ---------------------------------------------------------------------------
// fused reg MFMA: E = iT @ fM^T ; fusedAbsRaw[b] += sum|E|  (1/S folded at final)
__global__ __launch_bounds__(256) void fused_mfma_abs_kernel(
    const short* __restrict__ iTb, const short* __restrict__ fMb,
    float* __restrict__ fusedAbs) {
    __shared__ float sb[8];
    int tid = threadIdx.x;
    int lane = tid & 63, w = tid >> 6;
    if (tid < 8) sb[tid] = 0.f;
    __syncthreads();
    int m0 = blockIdx.x * 32 + (w >> 1) * 16;
    int n0 = blockIdx.y * 128 + (w & 1) * 64;
    int lrow = lane & 15, lk = lane >> 4;
    f32x4 acc[4] = {{0.f,0.f,0.f,0.f},{0.f,0.f,0.f,0.f},
                    {0.f,0.f,0.f,0.f},{0.f,0.f,0.f,0.f}};
    for (int koct0 = 0; koct0 < 128; koct0 += 4) {
        int koct = koct0 + lk;
        bf16x8 af = *reinterpret_cast<const bf16x8*>(
            iTb + ((size_t)koct * 448 + m0 + lrow) * 8);
        const short* bb = fMb + ((size_t)koct * 1024 + n0 + lrow) * 8;
        #pragma unroll
        for (int nt = 0; nt < 4; ++nt) {
            bf16x8 bf = *reinterpret_cast<const bf16x8*>(bb + nt * 128);
            acc[nt] = __builtin_amdgcn_mfma_f32_16x16x32_bf16(af, bf, acc[nt], 0, 0, 0);
        }
    }
    #pragma unroll
    for (int r = 0; r < 4; ++r) {
        float part = fabsf(acc[0][r]) + fabsf(acc[1][r]) +
                     fabsf(acc[2][r]) + fabsf(acc[3][r]);
        #pragma unroll
        for (int off = 1; off < 16; off <<= 1)
            part += __shfl_xor(part, off);
        if (lrow == 0) {
            int row = m0 + lk * 4 + r;
            atomicAdd(&sb[row / NK], part);
        }
    }
    __syncthreads();
    if (tid < 8 && sb[tid] != 0.f) atomicAdd(&fusedAbs[tid], sb[tid]);
}

// ---------------------------------------------------------------------------
// convpool: per-batch block 256 thr. cp_reduce + /S + conv + bias + leaky + pool.
__global__ __launch_bounds__(256) void convpool_kernel(
    const float* __restrict__ cp_part, const float* __restrict__ accums,
    const float* __restrict__ conv_w, const float* __restrict__ conv_b,
    float* __restrict__ pooled) {
    int b = blockIdx.x, t = threadIdx.x;
    __shared__ float xS[258];
    __shared__ float convo[8192];
    float invS = 1.f / accums[b];
    float s = 0.f;
    for (int c = 0; c < 125; ++c) s += cp_part[((size_t)b * 125 + c) * DD + t];
    xS[t + 1] = s * invS;
    if (t == 0) { xS[0] = 0.f; xS[257] = 0.f; }
    __syncthreads();
    for (int l = t; l < 8192; l += 256) {
        int o = l >> 7, pos = l & 127;
        float acc = conv_b[o];
        int base = pos * 2;
        #pragma unroll
        for (int h = 0; h < 4; ++h)
            acc = fmaf(xS[base + h], conv_w[o * 4 + h], acc);
        convo[l] = (acc > 0.f) ? acc : 0.1f * acc;
    }
    __syncthreads();
    for (int l = t; l < 2048; l += 256) {
        int o = l >> 5, p = l & 31;
        float m = convo[o * 128 + p * 4];
        m = fmaxf(m, convo[o * 128 + p * 4 + 1]);
        m = fmaxf(m, convo[o * 128 + p * 4 + 2]);
        m = fmaxf(m, convo[o * 128 + p * 4 + 3]);
        pooled[b * 2048 + l] = m;
    }
}

// ---------------------------------------------------------------------------
// FC partial: grid (o_tiles, k_splits). If FIN, staging applies bias+leaky.
template<bool FIN>
__global__ __launch_bounds__(256) void fc_partial_kernel(
    const float* __restrict__ in, const float* __restrict__ bias_in,
    const float* __restrict__ W, float* __restrict__ raw,
    int K, int N, int kchunk) {
    int t = threadIdx.x;
    int ol = t & 63;
    int o = blockIdx.x * 64 + ol;
    int w = t >> 6;
    int kbeg = blockIdx.y * kchunk;
    int kend = kbeg + kchunk; if (kend > K) kend = K;
    int len = kend - kbeg;
    __shared__ float sin_[B][128];
    for (int l = t; l < B * len; l += 256) {
        int b = l / len, k = l % len;
        float v = in[(size_t)b * K + kbeg + k];
        if (FIN) {
            v += bias_in[kbeg + k];
            v = (v > 0.f) ? v : 0.1f * v;
        }
        sin_[b][k] = v;
    }
    __syncthreads();
    float acc[B];
    #pragma unroll
    for (int b = 0; b < B; ++b) acc[b] = 0.f;
    if (o < N) {
        for (int k = kbeg + w; k < kend; k += 4) {
            float wv = W[(size_t)k * N + o];
            int kl = k - kbeg;
            #pragma unroll
            for (int b = 0; b < B; ++b)
                acc[b] = fmaf(sin_[b][kl], wv, acc[b]);
        }
    }
    __shared__ float red[4][64][B];
    #pragma unroll
    for (int b = 0; b < B; ++b) red[w][ol][b] = acc[b];
    __syncthreads();
    for (int p = t; p < 64 * B; p += 256) {
        int oo = p / B, b = p % B;
        int o2 = blockIdx.x * 64 + oo;
        if (o2 < N) {
            float s = red[0][oo][b] + red[1][oo][b] + red[2][oo][b] + red[3][oo][b];
            atomicAdd(&raw[(size_t)b * N + o2], s);
        }
    }
}

// fc3: reads raw2, applies b_r2+leaky inline, dot with W_r3, + b_r3.
__global__ __launch_bounds__(512) void fc3_kernel(
    const float* __restrict__ raw2, const float* __restrict__ b_r2,
    const float* __restrict__ W3, const float* __restrict__ b3,
    float* __restrict__ affn) {
    int wv = threadIdx.x >> 6, lane = threadIdx.x & 63;
    float acc = 0.f;
    for (int k = lane; k < 300; k += 64) {
        float v = raw2[(size_t)wv * 300 + k] + b_r2[k];
        v = (v > 0.f) ? v : 0.1f * v;
        acc = fmaf(v, W3[k], acc);
    }
    #pragma unroll
    for (int off = 32; off; off >>= 1) acc += __shfl_down(acc, off);
    if (lane == 0) affn[wv] = acc + b3[0];
}

// ---------------------------------------------------------------------------
// group (float4 loads): g = contacts[b,k,:].s_bi ; store sqrt(g)/S*sqrt(rs).
__global__ __launch_bounds__(64) void group_kernel(
    const float* __restrict__ contacts, const float* __restrict__ s_bi,
    const float* __restrict__ accums, float* __restrict__ groupv) {
    int bk = blockIdx.x;
    int b = bk / NP, k = bk % NP;
    const f32x4* row4 = reinterpret_cast<const f32x4*>(
        contacts + ((size_t)b * NP + k) * NP);
    const f32x4* sv4 = reinterpret_cast<const f32x4*>(s_bi + (size_t)b * NP);
    float g = 0.f, rs = 0.f;
    for (int i = threadIdx.x; i < 250; i += 64) {
        f32x4 c = row4[i];
        f32x4 s = sv4[i];
        g = fmaf(c[0], s[0], g); g = fmaf(c[1], s[1], g);
        g = fmaf(c[2], s[2], g); g = fmaf(c[3], s[3], g);
        rs += (c[0] + c[1]) + (c[2] + c[3]);
    }
    #pragma unroll
    for (int off = 32; off; off >>= 1) {
        g += __shfl_down(g, off);
        rs += __shfl_down(rs, off);
    }
    if (threadIdx.x == 0) {
        float val;
        if (g == 0.f) val = sqrtf(1e10f) * sqrtf(rs);
        else          val = sqrtf(g) / accums[b] * sqrtf(rs);
        groupv[bk] = val;
    }
}

// ---------------------------------------------------------------------------
// final: sum groupv (8000) + per-b loss assembly.
__global__ __launch_bounds__(256) void final_kernel(
    const float* __restrict__ accums, const float* __restrict__ groupv,
    const float* __restrict__ affn, const float* __restrict__ label,
    float* __restrict__ out) {
    int tid = threadIdx.x;
    float s = 0.f;
    for (int l = tid; l < B * NP; l += 256) s += groupv[l];
    __shared__ float r[256];
    r[tid] = s;
    __syncthreads();
    for (int st = 128; st; st >>= 1) {
        if (tid < st) r[tid] += r[tid + st];
        __syncthreads();
    }
    if (tid == 0) {
        float gtot = r[0];
        float l0 = 0.f, l1 = 0.f, l2 = 0.f;
        for (int b = 0; b < B; ++b) {
            float S = accums[b];
            float A = accums[8 + b], C = accums[16 + b], D = accums[24 + b];
            float fA = accums[32 + b];
            l0 += 1.f + fA / S;
            float bind = A / (S * S) - 2.f * C / S + D;
            l1 += sqrtf(fmaxf(bind, 0.f));
            float dd = affn[b] - label[b];
            l2 += dd * dd;
        }
        out[0] = (l0 + gtot + l1 + l2) * 0.125f;
    }
}

// ---------------------------------------------------------------------------
extern "C" void kernel_launch(void* const* d_in, const int* in_sizes, int n_in,
                              void* d_out, int out_size, void* d_ws, size_t ws_size,
                              hipStream_t stream) {
    const float* prot_data   = (const float*)d_in[0];
    const float* drug_ver    = (const float*)d_in[1];
    const float* drug_adj    = (const float*)d_in[2];
    const float* contacts    = (const float*)d_in[3];
    const float* prot_inter  = (const float*)d_in[4];
    const float* exist       = (const float*)d_in[5];
    const float* label       = (const float*)d_in[6];
    const float* fused       = (const float*)d_in[7];
    const float* W_prot      = (const float*)d_in[8];
    const float* b_prot      = (const float*)d_in[9];
    const float* gcn_W0      = (const float*)d_in[10];
    const float* gcn_b0      = (const float*)d_in[11];
    const float* gcn_W1      = (const float*)d_in[12];
    const float* gcn_b1      = (const float*)d_in[13];
    const float* gcn_W2      = (const float*)d_in[14];
    const float* gcn_b2      = (const float*)d_in[15];
    const float* gcn_Wf      = (const float*)d_in[16];
    const float* gcn_bf      = (const float*)d_in[17];
    const float* Wjp         = (const float*)d_in[18];
    const float* bjp         = (const float*)d_in[19];
    const float* Wjc         = (const float*)d_in[20];
    const float* bjc         = (const float*)d_in[21];
    const float* conv_w      = (const float*)d_in[22];
    const float* conv_b      = (const float*)d_in[23];
    const float* W_r1        = (const float*)d_in[24];
    const float* b_r1        = (const float*)d_in[25];
    const float* W_r2        = (const float*)d_in[26];
    const float* b_r2        = (const float*)d_in[27];
    const float* W_r3        = (const float*)d_in[28];
    const float* b_r3        = (const float*)d_in[29];

    float* ws = (float*)d_ws;
    size_t off = 0;
    auto alloc = [&](size_t n) { float* p = ws + off; off += n; return p; };
    float* prot     = alloc((size_t)B * NP * DD);
    float* qp       = alloc((size_t)B * NP * DD);
    float* tbuf     = alloc((size_t)B * NK * DD);   // y0; +ybuf = iTb alias
    float* ybuf     = alloc((size_t)B * NK * DD);   // y1
    float* comp     = alloc((size_t)B * NK * DD);
    float* qc       = alloc((size_t)B * NK * DD);
    float* inter    = alloc((size_t)B * NP * NK);
    float* s_bi     = alloc((size_t)B * NP);
    float* cp_part  = alloc((size_t)B * 125 * DD);
    float* pooled   = alloc((size_t)B * 2048);
    float* affn     = alloc((size_t)B);
    float* groupv   = alloc((size_t)B * NP);
    short* Wb1      = (short*)alloc((DP / 8) * DD * 8 / 2);
    short* Wb2      = (short*)alloc((DD / 8) * DD * 8 / 2);
    short* fMb      = (short*)alloc((size_t)128 * 1024 * 8 / 2);
    // zero region: accums(48) + raw1(4800) + raw2(2400), contiguous
    float* accums   = alloc(48);
    float* raw1     = alloc((size_t)B * 600);
    float* raw2     = alloc((size_t)B * 300);

    // iTb[128][448][8] bf16 aliases tbuf+ybuf (dead after GCN)
    short* iTb = (short*)tbuf;
    (void)ybuf;

    // 1. prep
    prep_kernel<<<670, 256, 0, stream>>>(W_prot, Wb1, Wjp, Wb2, fused, fMb, accums);

    // 2. prot = prot_data @ W_prot + b_prot   (bf16 MFMA)
    mfma_gemm_bias_kernel<false><<<dim3(250, 2), 256, 0, stream>>>(
        prot_data, Wb1, b_prot, prot, B * NP, DD, DP);

    // 3-5. GCN stack
    gcn_layer_kernel<<<B * NK, 256, 0, stream>>>(drug_ver, drug_adj, gcn_W0, gcn_b0, tbuf, DV);
    gcn_layer_kernel<<<B * NK, 256, 0, stream>>>(tbuf, drug_adj, gcn_W1, gcn_b1, ybuf, DD);
    gcn_tail_kernel<<<B * NK, 256, 0, stream>>>(ybuf, drug_adj, gcn_W2, gcn_b2,
                                                gcn_Wf, gcn_bf, Wjc, bjc, comp, qc);

    // 6. qp = relu(prot) @ Wjp + bjp   (bf16 MFMA)
    mfma_gemm_bias_kernel<true><<<dim3(250, 2), 256, 0, stream>>>(
        prot, Wb2, bjp, qp, B * NP, DD, DD);

    // 7. inter (raw) + moments + s_bi + iTb
    inter_all_kernel<<<B * 125, 256, 0, stream>>>(
        qp, qc, prot_inter, exist, inter, s_bi, iTb, accums);

    // 8. cp partials
    cp_partial_kernel<<<dim3(B * 125, 2), 128, 0, stream>>>(prot, comp, inter, cp_part);

    // 9. fused regularizer MFMA + abs
    fused_mfma_abs_kernel<<<dim3(14, 8), 256, 0, stream>>>(iTb, fMb, accums + 32);

    // 10. conv/pool
    convpool_kernel<<<B, 256, 0, stream>>>(cp_part, accums, conv_w, conv_b, pooled);

    // 11-13. FC stack
    fc_partial_kernel<false><<<dim3(10, 16), 256, 0, stream>>>(
        pooled, nullptr, W_r1, raw1, 2048, 600, 128);
    fc_partial_kernel<true><<<dim3(5, 8), 256, 0, stream>>>(
        raw1, b_r1, W_r2, raw2, 600, 300, 75);
    fc3_kernel<<<1, 512, 0, stream>>>(raw2, b_r2, W_r3, b_r3, affn);

    // 14. group regularizer
    group_kernel<<<B * NP, 64, 0, stream>>>(contacts, s_bi, accums, groupv);

    // 15. final loss
    final_kernel<<<1, 256, 0, stream>>>(accums, groupv, affn, label, (float*)d_out);
}

// Round 13
// 210.981 us; speedup vs baseline: 1.8375x; 1.0240x over previous
//
#include <hip/hip_runtime.h>
#include <hip/hip_bf16.h>
#include <math.h>

// ---------------------------------------------------------------------------
#define B 8
#define NP 1000
#define NK 56
#define DP 768
#define DV 43
#define DD 256
#define NT 999

typedef __attribute__((ext_vector_type(8))) short bf16x8;
typedef __attribute__((ext_vector_type(4))) float f32x4;

__device__ inline short f2bf(float x) {
    __hip_bfloat16 h = __float2bfloat16(x);
    return __builtin_bit_cast(short, h);
}

// ---------------------------------------------------------------------------
// prep: [0,96) wcvt W_prot ; [96,128) wcvt Wjp ; [128,640) fusedcvt (tiled,
// coalesced) ; [640,670) zero region (accums 48 + raw1 4800 + raw2 2400)
// accums layout: [0..8)S [8..16)A=Sum v^2 [16..24)C=Sum v*lab [24..32)D=Sum lab^2
//                [32..40)fusedAbsRaw [40..48)unused
__global__ __launch_bounds__(256) void prep_kernel(
    const float* __restrict__ W_prot, short* __restrict__ Wb1,
    const float* __restrict__ Wjp, short* __restrict__ Wb2,
    const float* __restrict__ fusedM, short* __restrict__ fMb,
    float* __restrict__ zero_region) {
    int blk = blockIdx.x, tid = threadIdx.x;
    __shared__ float tile[16][132];
    if (blk < 96) {
        int idx = blk * 256 + tid;
        int koct = idx / DD, n = idx % DD;
        bf16x8 v;
        #pragma unroll
        for (int e = 0; e < 8; ++e)
            v[e] = f2bf(W_prot[(size_t)(koct * 8 + e) * DD + n]);
        *reinterpret_cast<bf16x8*>(Wb1 + (size_t)idx * 8) = v;
    } else if (blk < 128) {
        int idx = (blk - 96) * 256 + tid;
        int koct = idx / DD, n = idx % DD;
        bf16x8 v;
        #pragma unroll
        for (int e = 0; e < 8; ++e)
            v[e] = f2bf(Wjp[(size_t)(koct * 8 + e) * DD + n]);
        *reinterpret_cast<bf16x8*>(Wb2 + (size_t)idx * 8) = v;
    } else if (blk < 640) {
        int blk2 = blk - 128;             // 512 blocks: 64 t-tiles x 8 i-tiles
        int t0 = (blk2 >> 3) * 16;
        int i0 = (blk2 & 7) * 128;
        for (int l = tid; l < 16 * 128; l += 256) {
            int tt = l >> 7, ii = l & 127;
            int t = t0 + tt, i = i0 + ii;
            tile[tt][ii] = (t < NT && i < NP) ? fusedM[(size_t)t * NP + i] : 0.f;
        }
        __syncthreads();
        int octl = tid >> 4, tl = tid & 15;
        bf16x8 v;
        #pragma unroll
        for (int e = 0; e < 8; ++e)
            v[e] = f2bf(tile[tl][octl * 8 + e]);
        size_t oct = i0 / 8 + octl;
        *reinterpret_cast<bf16x8*>(fMb + (oct * 1024 + t0 + tl) * 8) = v;
    } else {
        int idx = (blk - 640) * 256 + tid;
        if (idx < 48 + B * 600 + B * 300) zero_region[idx] = 0.f;
    }
}

// ---------------------------------------------------------------------------
// MFMA GEMM: C = act_in(A) @ Wb + bias. Block 4 waves; tile 32(M) x 128(N).
template<bool RELU_IN>
__global__ __launch_bounds__(256) void mfma_gemm_bias_kernel(
    const float* __restrict__ A, const short* __restrict__ Wb,
    const float* __restrict__ bias, float* __restrict__ C,
    int M, int N, int K) {
    int tid = threadIdx.x;
    int lane = tid & 63, w = tid >> 6;
    int m0 = blockIdx.x * 32 + (w >> 1) * 16;
    int n0 = blockIdx.y * 128 + (w & 1) * 64;
    int lrow = lane & 15, lk = lane >> 4;
    f32x4 acc[4] = {{0.f,0.f,0.f,0.f},{0.f,0.f,0.f,0.f},
                    {0.f,0.f,0.f,0.f},{0.f,0.f,0.f,0.f}};
    const float* arow = A + (size_t)(m0 + lrow) * K + lk * 8;
    for (int k0 = 0; k0 < K; k0 += 32) {
        f32x4 a0 = *reinterpret_cast<const f32x4*>(arow + k0);
        f32x4 a1 = *reinterpret_cast<const f32x4*>(arow + k0 + 4);
        bf16x8 af;
        #pragma unroll
        for (int e = 0; e < 4; ++e) {
            float v0 = a0[e], v1 = a1[e];
            if (RELU_IN) { v0 = fmaxf(v0, 0.f); v1 = fmaxf(v1, 0.f); }
            af[e] = f2bf(v0); af[4 + e] = f2bf(v1);
        }
        const short* bbase = Wb + ((size_t)((k0 >> 3) + lk) * N + n0 + lrow) * 8;
        #pragma unroll
        for (int nt = 0; nt < 4; ++nt) {
            bf16x8 bf = *reinterpret_cast<const bf16x8*>(bbase + nt * 128);
            acc[nt] = __builtin_amdgcn_mfma_f32_16x16x32_bf16(af, bf, acc[nt], 0, 0, 0);
        }
    }
    #pragma unroll
    for (int nt = 0; nt < 4; ++nt) {
        int col = n0 + nt * 16 + lrow;
        float bv = bias[col];
        #pragma unroll
        for (int r = 0; r < 4; ++r) {
            int row = m0 + lk * 4 + r;
            C[(size_t)row * N + col] = acc[nt][r] + bv;
        }
    }
}

// ---------------------------------------------------------------------------
// Fused GCN layer: y[b,i,:] = relu( (adj@x)[b,i,:] @ W + rowsum(adj)_i * bias )
__global__ __launch_bounds__(256) void gcn_layer_kernel(
    const float* __restrict__ x, const float* __restrict__ adj,
    const float* __restrict__ W, const float* __restrict__ bias,
    float* __restrict__ y, int KIN) {
    int bi = blockIdx.x;
    int b = bi / NK, i = bi % NK;
    int tid = threadIdx.x;
    __shared__ float arow[NK];
    __shared__ float u[DD];
    if (tid < NK) arow[tid] = adj[((size_t)b * NK + i) * NK + tid];
    __syncthreads();
    if (tid < KIN) {
        float a0 = 0.f, a1 = 0.f;
        for (int j = 0; j < NK; j += 2) {
            a0 = fmaf(arow[j],     x[((size_t)b * NK + j)     * KIN + tid], a0);
            a1 = fmaf(arow[j + 1], x[((size_t)b * NK + j + 1) * KIN + tid], a1);
        }
        u[tid] = a0 + a1;
    }
    float rs = 0.f;
    for (int j = 0; j < NK; ++j) rs += arow[j];
    __syncthreads();
    float a0 = 0.f, a1 = 0.f, a2 = 0.f, a3 = 0.f;
    int kk = 0;
    for (; kk + 4 <= KIN; kk += 4) {
        a0 = fmaf(u[kk],     W[(size_t)kk * DD + tid],       a0);
        a1 = fmaf(u[kk + 1], W[(size_t)(kk + 1) * DD + tid], a1);
        a2 = fmaf(u[kk + 2], W[(size_t)(kk + 2) * DD + tid], a2);
        a3 = fmaf(u[kk + 3], W[(size_t)(kk + 3) * DD + tid], a3);
    }
    for (; kk < KIN; ++kk) a0 = fmaf(u[kk], W[(size_t)kk * DD + tid], a0);
    float v = a0 + a1 + a2 + a3 + rs * bias[tid];
    y[((size_t)b * NK + i) * DD + tid] = fmaxf(v, 0.f);
}

// Fused GCN tail: layer2 (adjmul+W2) -> comp(@Wf+bf) -> qc(relu@Wjc+bjc).
__global__ __launch_bounds__(256) void gcn_tail_kernel(
    const float* __restrict__ y1, const float* __restrict__ adj,
    const float* __restrict__ W2, const float* __restrict__ b2,
    const float* __restrict__ Wf, const float* __restrict__ bf,
    const float* __restrict__ Wjc, const float* __restrict__ bjc,
    float* __restrict__ comp, float* __restrict__ qcout) {
    int bi = blockIdx.x;
    int b = bi / NK, i = bi % NK;
    int tid = threadIdx.x;
    __shared__ float arow[NK];
    __shared__ float u[DD];
    if (tid < NK) arow[tid] = adj[((size_t)b * NK + i) * NK + tid];
    __syncthreads();
    {
        float a0 = 0.f, a1 = 0.f;
        for (int j = 0; j < NK; j += 2) {
            a0 = fmaf(arow[j],     y1[((size_t)b * NK + j)     * DD + tid], a0);
            a1 = fmaf(arow[j + 1], y1[((size_t)b * NK + j + 1) * DD + tid], a1);
        }
        u[tid] = a0 + a1;
    }
    float rs = 0.f;
    for (int j = 0; j < NK; ++j) rs += arow[j];
    __syncthreads();
    float a0 = 0.f, a1 = 0.f, a2 = 0.f, a3 = 0.f;
    #pragma unroll 4
    for (int kk = 0; kk < DD; kk += 4) {
        a0 = fmaf(u[kk],     W2[(size_t)kk * DD + tid],       a0);
        a1 = fmaf(u[kk + 1], W2[(size_t)(kk + 1) * DD + tid], a1);
        a2 = fmaf(u[kk + 2], W2[(size_t)(kk + 2) * DD + tid], a2);
        a3 = fmaf(u[kk + 3], W2[(size_t)(kk + 3) * DD + tid], a3);
    }
    float y2 = fmaxf(a0 + a1 + a2 + a3 + rs * b2[tid], 0.f);
    __syncthreads();
    u[tid] = y2;
    __syncthreads();
    a0 = a1 = a2 = a3 = 0.f;
    #pragma unroll 4
    for (int kk = 0; kk < DD; kk += 4) {
        a0 = fmaf(u[kk],     Wf[(size_t)kk * DD + tid],       a0);
        a1 = fmaf(u[kk + 1], Wf[(size_t)(kk + 1) * DD + tid], a1);
        a2 = fmaf(u[kk + 2], Wf[(size_t)(kk + 2) * DD + tid], a2);
        a3 = fmaf(u[kk + 3], Wf[(size_t)(kk + 3) * DD + tid], a3);
    }
    float cv = a0 + a1 + a2 + a3 + bf[tid];
    comp[((size_t)b * NK + i) * DD + tid] = cv;
    __syncthreads();
    u[tid] = fmaxf(cv, 0.f);
    __syncthreads();
    a0 = a1 = a2 = a3 = 0.f;
    #pragma unroll 4
    for (int kk = 0; kk < DD; kk += 4) {
        a0 = fmaf(u[kk],     Wjc[(size_t)kk * DD + tid],       a0);
        a1 = fmaf(u[kk + 1], Wjc[(size_t)(kk + 1) * DD + tid], a1);
        a2 = fmaf(u[kk + 2], Wjc[(size_t)(kk + 2) * DD + tid], a2);
        a3 = fmaf(u[kk + 3], Wjc[(size_t)(kk + 3) * DD + tid], a3);
    }
    qcout[((size_t)b * NK + i) * DD + tid] = a0 + a1 + a2 + a3 + bjc[tid];
}

// ---------------------------------------------------------------------------
// inter_all v2: both operands LDS-staged; d-outer loop, shared qcT read,
// 2 rows per wave. No global access in the hot loop.
__global__ __launch_bounds__(256) void inter_all_kernel(
    const float* __restrict__ qp, const float* __restrict__ qc,
    const float* __restrict__ prot_inter, const float* __restrict__ exist,
    float* __restrict__ inter, float* __restrict__ s_bi,
    short* __restrict__ iTb, float* __restrict__ accums) {
    int b = blockIdx.x / 125, chunk = blockIdx.x % 125;
    __shared__ float qcT[DD * 57];     // [d][k], pad 57
    __shared__ float qpS[8][DD];
    __shared__ float vS[8][57];
    __shared__ float wred[4][4];
    int tid = threadIdx.x;
    for (int l = tid; l < NK * DD; l += 256) {
        int k = l / DD, d = l % DD;
        qcT[d * 57 + k] = qc[((size_t)b * NK + k) * DD + d];
    }
    for (int l = tid; l < 8 * DD; l += 256) {
        int r = l >> 8, d = l & 255;
        qpS[r][d] = qp[((size_t)b * NP + chunk * 8 + r) * DD + d];
    }
    __syncthreads();
    int w = tid >> 6, lane = tid & 63;
    float ex = exist[b];
    int r0 = w * 2, r1 = w * 2 + 1;
    float acc0 = 0.f, acc1 = 0.f;
    if (lane < NK) {
        #pragma unroll 8
        for (int d = 0; d < DD; ++d) {
            float c = qcT[d * 57 + lane];
            acc0 = fmaf(qpS[r0][d], c, acc0);
            acc1 = fmaf(qpS[r1][d], c, acc1);
        }
    }
    float aV = 0.f, aA = 0.f, aC = 0.f, aD = 0.f;
    #pragma unroll
    for (int ii = 0; ii < 2; ++ii) {
        int i = chunk * 8 + w * 2 + ii;
        float v = 0.f, lab = 0.f;
        if (lane < NK) {
            float acc = (ii == 0) ? acc0 : acc1;
            v = 1.f / (1.f + __expf(-acc));
            lab = ex * prot_inter[((size_t)b * NP + i) * NK + lane];
            inter[((size_t)b * NP + i) * NK + lane] = v;
            vS[w * 2 + ii][lane] = v;
        }
        float v2 = v * v;
        float r = v2;
        #pragma unroll
        for (int off = 32; off; off >>= 1) r += __shfl_down(r, off);
        if (lane == 0) s_bi[(size_t)b * NP + i] = r;
        aV += v; aA += v2; aC += v * lab; aD += lab * lab;
    }
    #pragma unroll
    for (int off = 32; off; off >>= 1) {
        aV += __shfl_down(aV, off);
        aA += __shfl_down(aA, off);
        aC += __shfl_down(aC, off);
        aD += __shfl_down(aD, off);
    }
    if (lane == 0) {
        wred[w][0] = aV; wred[w][1] = aA; wred[w][2] = aC; wred[w][3] = aD;
    }
    __syncthreads();
    if (tid < 4) {
        float s = wred[0][tid] + wred[1][tid] + wred[2][tid] + wred[3][tid];
        atomicAdd(&accums[tid * 8 + b], s);
    }
    if (tid < NK) {
        bf16x8 pk;
        #pragma unroll
        for (int e = 0; e < 8; ++e) pk[e] = f2bf(vS[e][tid]);
        *reinterpret_cast<bf16x8*>(iTb + ((size_t)chunk * 448 + b * NK + tid) * 8) = pk;
        if (chunk == 124) {
            bf16x8 z = {0,0,0,0,0,0,0,0};
            #pragma unroll
            for (int oct = 125; oct < 128; ++oct)
                *reinterpret_cast<bf16x8*>(iTb + ((size_t)oct * 448 + b * NK + tid) * 8) = z;
        }
    }
}

// ---------------------------------------------------------------------------
// cp partials: raw inter (1/S folded later).  t = 1 - 2*rcp(exp2(p*2log2e*c)+1)
__global__ __launch_bounds__(128) void cp_partial_kernel(
    const float* __restrict__ prot, const float* __restrict__ comp,
    const float* __restrict__ inter, float* __restrict__ part) {
    int bc = blockIdx.x;
    int b = bc / 125, chunk = bc % 125;
    int dh = blockIdx.y;
    int tid = threadIdx.x;
    int d = dh * 128 + tid;
    __shared__ float irow[8][NK];
    float creg[NK];
    #pragma unroll
    for (int k = 0; k < NK; ++k)
        creg[k] = comp[((size_t)b * NK + k) * DD + d];
    for (int l = tid; l < 8 * NK; l += 128) {
        int ii = l / NK, k = l % NK;
        irow[ii][k] = inter[((size_t)b * NP + chunk * 8 + ii) * NK + k];
    }
    const float C2LOG2E = 2.8853900817779268f;
    float p2l[8];
    #pragma unroll
    for (int ii = 0; ii < 8; ++ii)
        p2l[ii] = C2LOG2E * prot[((size_t)b * NP + chunk * 8 + ii) * DD + d];
    __syncthreads();
    float acc0 = 0.f, acc1 = 0.f;
    #pragma unroll 1
    for (int ii = 0; ii < 8; ++ii) {
        float p = p2l[ii];
        #pragma unroll
        for (int k = 0; k < NK; k += 2) {
            float e0 = __builtin_amdgcn_exp2f(p * creg[k]);
            float e1 = __builtin_amdgcn_exp2f(p * creg[k + 1]);
            float r0 = __builtin_amdgcn_rcpf(e0 + 1.f);
            float r1 = __builtin_amdgcn_rcpf(e1 + 1.f);
            acc0 = fmaf(fmaf(-2.f, r0, 1.f), irow[ii][k],     acc0);
            acc1 = fmaf(fmaf(-2.f, r1, 1.f), irow[ii][k + 1], acc1);
        }
    }
    part[((size_t)b * 125 + chunk) * DD + d] = acc0 + acc1;
}

// ---------------------------------------------------------------------------
// fused reg MFMA: E = iT @ fM^T ; fusedAbsRaw[b] += sum|E|  (1/S folded at final)
__global__ __launch_bounds__(256) void fused_mfma_abs_kernel(
    const short* __restrict__ iTb, const short* __restrict__ fMb,
    float* __restrict__ fusedAbs) {
    __shared__ float sb[8];
    int tid = threadIdx.x;
    int lane = tid & 63, w = tid >> 6;
    if (tid < 8) sb[tid] = 0.f;
    __syncthreads();
    int m0 = blockIdx.x * 32 + (w >> 1) * 16;
    int n0 = blockIdx.y * 128 + (w & 1) * 64;
    int lrow = lane & 15, lk = lane >> 4;
    f32x4 acc[4] = {{0.f,0.f,0.f,0.f},{0.f,0.f,0.f,0.f},
                    {0.f,0.f,0.f,0.f},{0.f,0.f,0.f,0.f}};
    for (int koct0 = 0; koct0 < 128; koct0 += 4) {
        int koct = koct0 + lk;
        bf16x8 af = *reinterpret_cast<const bf16x8*>(
            iTb + ((size_t)koct * 448 + m0 + lrow) * 8);
        const short* bb = fMb + ((size_t)koct * 1024 + n0 + lrow) * 8;
        #pragma unroll
        for (int nt = 0; nt < 4; ++nt) {
            bf16x8 bf = *reinterpret_cast<const bf16x8*>(bb + nt * 128);
            acc[nt] = __builtin_amdgcn_mfma_f32_16x16x32_bf16(af, bf, acc[nt], 0, 0, 0);
        }
    }
    #pragma unroll
    for (int r = 0; r < 4; ++r) {
        float part = fabsf(acc[0][r]) + fabsf(acc[1][r]) +
                     fabsf(acc[2][r]) + fabsf(acc[3][r]);
        #pragma unroll
        for (int off = 1; off < 16; off <<= 1)
            part += __shfl_xor(part, off);
        if (lrow == 0) {
            int row = m0 + lk * 4 + r;
            atomicAdd(&sb[row / NK], part);
        }
    }
    __syncthreads();
    if (tid < 8 && sb[tid] != 0.f) atomicAdd(&fusedAbs[tid], sb[tid]);
}

// ---------------------------------------------------------------------------
// convpool: per-batch block 256 thr. cp_reduce + /S + conv + bias + leaky + pool.
__global__ __launch_bounds__(256) void convpool_kernel(
    const float* __restrict__ cp_part, const float* __restrict__ accums,
    const float* __restrict__ conv_w, const float* __restrict__ conv_b,
    float* __restrict__ pooled) {
    int b = blockIdx.x, t = threadIdx.x;
    __shared__ float xS[258];
    __shared__ float convo[8192];
    float invS = 1.f / accums[b];
    float s = 0.f;
    for (int c = 0; c < 125; ++c) s += cp_part[((size_t)b * 125 + c) * DD + t];
    xS[t + 1] = s * invS;
    if (t == 0) { xS[0] = 0.f; xS[257] = 0.f; }
    __syncthreads();
    for (int l = t; l < 8192; l += 256) {
        int o = l >> 7, pos = l & 127;
        float acc = conv_b[o];
        int base = pos * 2;
        #pragma unroll
        for (int h = 0; h < 4; ++h)
            acc = fmaf(xS[base + h], conv_w[o * 4 + h], acc);
        convo[l] = (acc > 0.f) ? acc : 0.1f * acc;
    }
    __syncthreads();
    for (int l = t; l < 2048; l += 256) {
        int o = l >> 5, p = l & 31;
        float m = convo[o * 128 + p * 4];
        m = fmaxf(m, convo[o * 128 + p * 4 + 1]);
        m = fmaxf(m, convo[o * 128 + p * 4 + 2]);
        m = fmaxf(m, convo[o * 128 + p * 4 + 3]);
        pooled[b * 2048 + l] = m;
    }
}

// ---------------------------------------------------------------------------
// FC partial: grid (o_tiles, k_splits). If FIN, staging applies bias+leaky.
template<bool FIN>
__global__ __launch_bounds__(256) void fc_partial_kernel(
    const float* __restrict__ in, const float* __restrict__ bias_in,
    const float* __restrict__ W, float* __restrict__ raw,
    int K, int N, int kchunk) {
    int t = threadIdx.x;
    int ol = t & 63;
    int o = blockIdx.x * 64 + ol;
    int w = t >> 6;
    int kbeg = blockIdx.y * kchunk;
    int kend = kbeg + kchunk; if (kend > K) kend = K;
    int len = kend - kbeg;
    __shared__ float sin_[B][128];
    for (int l = t; l < B * len; l += 256) {
        int b = l / len, k = l % len;
        float v = in[(size_t)b * K + kbeg + k];
        if (FIN) {
            v += bias_in[kbeg + k];
            v = (v > 0.f) ? v : 0.1f * v;
        }
        sin_[b][k] = v;
    }
    __syncthreads();
    float acc[B];
    #pragma unroll
    for (int b = 0; b < B; ++b) acc[b] = 0.f;
    if (o < N) {
        for (int k = kbeg + w; k < kend; k += 4) {
            float wv = W[(size_t)k * N + o];
            int kl = k - kbeg;
            #pragma unroll
            for (int b = 0; b < B; ++b)
                acc[b] = fmaf(sin_[b][kl], wv, acc[b]);
        }
    }
    __shared__ float red[4][64][B];
    #pragma unroll
    for (int b = 0; b < B; ++b) red[w][ol][b] = acc[b];
    __syncthreads();
    for (int p = t; p < 64 * B; p += 256) {
        int oo = p / B, b = p % B;
        int o2 = blockIdx.x * 64 + oo;
        if (o2 < N) {
            float s = red[0][oo][b] + red[1][oo][b] + red[2][oo][b] + red[3][oo][b];
            atomicAdd(&raw[(size_t)b * N + o2], s);
        }
    }
}

// ---------------------------------------------------------------------------
// group v2 (ILP): all 4 float4 load-pairs issued back-to-back, independent
// accumulators -> single memory round-trip per wave.  250 = 64+64+64+58.
__global__ __launch_bounds__(64) void group_kernel(
    const float* __restrict__ contacts, const float* __restrict__ s_bi,
    const float* __restrict__ accums, float* __restrict__ groupv) {
    int bk = blockIdx.x;
    int b = bk / NP, k = bk % NP;
    const f32x4* row4 = reinterpret_cast<const f32x4*>(
        contacts + ((size_t)b * NP + k) * NP);
    const f32x4* sv4 = reinterpret_cast<const f32x4*>(s_bi + (size_t)b * NP);
    int t = threadIdx.x;
    f32x4 z = {0.f, 0.f, 0.f, 0.f};
    f32x4 c0 = row4[t];
    f32x4 c1 = row4[t + 64];
    f32x4 c2 = row4[t + 128];
    f32x4 c3 = z, s3 = z;
    f32x4 s0 = sv4[t];
    f32x4 s1 = sv4[t + 64];
    f32x4 s2 = sv4[t + 128];
    if (t + 192 < 250) { c3 = row4[t + 192]; s3 = sv4[t + 192]; }
    float g0 = 0.f, g1 = 0.f, g2 = 0.f, g3 = 0.f;
    #pragma unroll
    for (int e = 0; e < 4; ++e) {
        g0 = fmaf(c0[e], s0[e], g0);
        g1 = fmaf(c1[e], s1[e], g1);
        g2 = fmaf(c2[e], s2[e], g2);
        g3 = fmaf(c3[e], s3[e], g3);
    }
    float r0 = (c0[0] + c0[1]) + (c0[2] + c0[3]);
    float r1 = (c1[0] + c1[1]) + (c1[2] + c1[3]);
    float r2 = (c2[0] + c2[1]) + (c2[2] + c2[3]);
    float r3 = (c3[0] + c3[1]) + (c3[2] + c3[3]);
    float g = (g0 + g1) + (g2 + g3);
    float rs = (r0 + r1) + (r2 + r3);
    #pragma unroll
    for (int off = 32; off; off >>= 1) {
        g += __shfl_down(g, off);
        rs += __shfl_down(rs, off);
    }
    if (t == 0) {
        float val;
        if (g == 0.f) val = sqrtf(1e10f) * sqrtf(rs);
        else          val = sqrtf(g) / accums[b] * sqrtf(rs);
        groupv[bk] = val;
    }
}

// ---------------------------------------------------------------------------
// final: inline fc3 (raw2 + b_r2 -> leaky -> dot W3) + groupv sum + assembly.
__global__ __launch_bounds__(256) void final_kernel(
    const float* __restrict__ accums, const float* __restrict__ groupv,
    const float* __restrict__ raw2, const float* __restrict__ b_r2,
    const float* __restrict__ W3, const float* __restrict__ b3,
    const float* __restrict__ label, float* __restrict__ out) {
    int tid = threadIdx.x;
    __shared__ float affnS[8];
    {
        int b = tid >> 5, k0 = tid & 31;
        float acc = 0.f;
        for (int k = k0; k < 300; k += 32) {
            float v = raw2[(size_t)b * 300 + k] + b_r2[k];
            v = (v > 0.f) ? v : 0.1f * v;
            acc = fmaf(v, W3[k], acc);
        }
        #pragma unroll
        for (int off = 16; off; off >>= 1) acc += __shfl_down(acc, off);
        if (k0 == 0) affnS[b] = acc + b3[0];
    }
    float s = 0.f;
    for (int l = tid; l < B * NP; l += 256) s += groupv[l];
    __shared__ float r[256];
    r[tid] = s;
    __syncthreads();
    for (int st = 128; st; st >>= 1) {
        if (tid < st) r[tid] += r[tid + st];
        __syncthreads();
    }
    if (tid == 0) {
        float gtot = r[0];
        float l0 = 0.f, l1 = 0.f, l2 = 0.f;
        for (int b = 0; b < B; ++b) {
            float S = accums[b];
            float A = accums[8 + b], C = accums[16 + b], D = accums[24 + b];
            float fA = accums[32 + b];
            l0 += 1.f + fA / S;
            float bind = A / (S * S) - 2.f * C / S + D;
            l1 += sqrtf(fmaxf(bind, 0.f));
            float dd = affnS[b] - label[b];
            l2 += dd * dd;
        }
        out[0] = (l0 + gtot + l1 + l2) * 0.125f;
    }
}

// ---------------------------------------------------------------------------
extern "C" void kernel_launch(void* const* d_in, const int* in_sizes, int n_in,
                              void* d_out, int out_size, void* d_ws, size_t ws_size,
                              hipStream_t stream) {
    const float* prot_data   = (const float*)d_in[0];
    const float* drug_ver    = (const float*)d_in[1];
    const float* drug_adj    = (const float*)d_in[2];
    const float* contacts    = (const float*)d_in[3];
    const float* prot_inter  = (const float*)d_in[4];
    const float* exist       = (const float*)d_in[5];
    const float* label       = (const float*)d_in[6];
    const float* fused       = (const float*)d_in[7];
    const float* W_prot      = (const float*)d_in[8];
    const float* b_prot      = (const float*)d_in[9];
    const float* gcn_W0      = (const float*)d_in[10];
    const float* gcn_b0      = (const float*)d_in[11];
    const float* gcn_W1      = (const float*)d_in[12];
    const float* gcn_b1      = (const float*)d_in[13];
    const float* gcn_W2      = (const float*)d_in[14];
    const float* gcn_b2      = (const float*)d_in[15];
    const float* gcn_Wf      = (const float*)d_in[16];
    const float* gcn_bf      = (const float*)d_in[17];
    const float* Wjp         = (const float*)d_in[18];
    const float* bjp         = (const float*)d_in[19];
    const float* Wjc         = (const float*)d_in[20];
    const float* bjc         = (const float*)d_in[21];
    const float* conv_w      = (const float*)d_in[22];
    const float* conv_b      = (const float*)d_in[23];
    const float* W_r1        = (const float*)d_in[24];
    const float* b_r1        = (const float*)d_in[25];
    const float* W_r2        = (const float*)d_in[26];
    const float* b_r2        = (const float*)d_in[27];
    const float* W_r3        = (const float*)d_in[28];
    const float* b_r3        = (const float*)d_in[29];

    float* ws = (float*)d_ws;
    size_t off = 0;
    auto alloc = [&](size_t n) { float* p = ws + off; off += n; return p; };
    float* prot     = alloc((size_t)B * NP * DD);
    float* qp       = alloc((size_t)B * NP * DD);
    float* tbuf     = alloc((size_t)B * NK * DD);   // y0; +ybuf = iTb alias
    float* ybuf     = alloc((size_t)B * NK * DD);   // y1
    float* comp     = alloc((size_t)B * NK * DD);
    float* qc       = alloc((size_t)B * NK * DD);
    float* inter    = alloc((size_t)B * NP * NK);
    float* s_bi     = alloc((size_t)B * NP);
    float* cp_part  = alloc((size_t)B * 125 * DD);
    float* pooled   = alloc((size_t)B * 2048);
    float* groupv   = alloc((size_t)B * NP);
    short* Wb1      = (short*)alloc((DP / 8) * DD * 8 / 2);
    short* Wb2      = (short*)alloc((DD / 8) * DD * 8 / 2);
    short* fMb      = (short*)alloc((size_t)128 * 1024 * 8 / 2);
    // zero region: accums(48) + raw1(4800) + raw2(2400), contiguous
    float* accums   = alloc(48);
    float* raw1     = alloc((size_t)B * 600);
    float* raw2     = alloc((size_t)B * 300);

    // iTb[128][448][8] bf16 aliases tbuf+ybuf (dead after GCN)
    short* iTb = (short*)tbuf;
    (void)ybuf;

    // 1. prep
    prep_kernel<<<670, 256, 0, stream>>>(W_prot, Wb1, Wjp, Wb2, fused, fMb, accums);

    // 2. prot = prot_data @ W_prot + b_prot   (bf16 MFMA)
    mfma_gemm_bias_kernel<false><<<dim3(250, 2), 256, 0, stream>>>(
        prot_data, Wb1, b_prot, prot, B * NP, DD, DP);

    // 3-5. GCN stack
    gcn_layer_kernel<<<B * NK, 256, 0, stream>>>(drug_ver, drug_adj, gcn_W0, gcn_b0, tbuf, DV);
    gcn_layer_kernel<<<B * NK, 256, 0, stream>>>(tbuf, drug_adj, gcn_W1, gcn_b1, ybuf, DD);
    gcn_tail_kernel<<<B * NK, 256, 0, stream>>>(ybuf, drug_adj, gcn_W2, gcn_b2,
                                                gcn_Wf, gcn_bf, Wjc, bjc, comp, qc);

    // 6. qp = relu(prot) @ Wjp + bjp   (bf16 MFMA)
    mfma_gemm_bias_kernel<true><<<dim3(250, 2), 256, 0, stream>>>(
        prot, Wb2, bjp, qp, B * NP, DD, DD);

    // 7. inter (raw) + moments + s_bi + iTb
    inter_all_kernel<<<B * 125, 256, 0, stream>>>(
        qp, qc, prot_inter, exist, inter, s_bi, iTb, accums);

    // 8. cp partials
    cp_partial_kernel<<<dim3(B * 125, 2), 128, 0, stream>>>(prot, comp, inter, cp_part);

    // 9. fused regularizer MFMA + abs
    fused_mfma_abs_kernel<<<dim3(14, 8), 256, 0, stream>>>(iTb, fMb, accums + 32);

    // 10. conv/pool
    convpool_kernel<<<B, 256, 0, stream>>>(cp_part, accums, conv_w, conv_b, pooled);

    // 11-12. FC stack
    fc_partial_kernel<false><<<dim3(10, 16), 256, 0, stream>>>(
        pooled, nullptr, W_r1, raw1, 2048, 600, 128);
    fc_partial_kernel<true><<<dim3(5, 8), 256, 0, stream>>>(
        raw1, b_r1, W_r2, raw2, 600, 300, 75);

    // 13. group regularizer
    group_kernel<<<B * NP, 64, 0, stream>>>(contacts, s_bi, accums, groupv);

    // 14. final loss (fc3 inline + group sum + assembly)
    final_kernel<<<1, 256, 0, stream>>>(accums, groupv, raw2, b_r2,
                                        W_r3, b_r3, label, (float*)d_out);
}

// Round 14
// 162.935 us; speedup vs baseline: 2.3793x; 1.2949x over previous
//
#include <hip/hip_runtime.h>
#include <hip/hip_bf16.h>
#include <math.h>

// ---------------------------------------------------------------------------
#define B 8
#define NP 1000
#define NK 56
#define DP 768
#define DV 43
#define DD 256
#define NT 999

typedef __attribute__((ext_vector_type(8))) short bf16x8;
typedef __attribute__((ext_vector_type(4))) float f32x4;

__device__ inline short f2bf(float x) {
    __hip_bfloat16 h = __float2bfloat16(x);
    return __builtin_bit_cast(short, h);
}

// ---------------------------------------------------------------------------
// Device bodies shared by merged kernels
// ---------------------------------------------------------------------------

// MFMA GEMM body: C = act_in(A) @ Wb + bias. 4 waves; tile 32(M) x 128(N).
template<bool RELU_IN>
__device__ __forceinline__ void gemm_body(
    const float* __restrict__ A, const short* __restrict__ Wb,
    const float* __restrict__ bias, float* __restrict__ C,
    int N, int K, int bm, int bn, int tid) {
    int lane = tid & 63, w = tid >> 6;
    int m0 = bm * 32 + (w >> 1) * 16;
    int n0 = bn * 128 + (w & 1) * 64;
    int lrow = lane & 15, lk = lane >> 4;
    f32x4 acc[4] = {{0.f,0.f,0.f,0.f},{0.f,0.f,0.f,0.f},
                    {0.f,0.f,0.f,0.f},{0.f,0.f,0.f,0.f}};
    const float* arow = A + (size_t)(m0 + lrow) * K + lk * 8;
    for (int k0 = 0; k0 < K; k0 += 32) {
        f32x4 a0 = *reinterpret_cast<const f32x4*>(arow + k0);
        f32x4 a1 = *reinterpret_cast<const f32x4*>(arow + k0 + 4);
        bf16x8 af;
        #pragma unroll
        for (int e = 0; e < 4; ++e) {
            float v0 = a0[e], v1 = a1[e];
            if (RELU_IN) { v0 = fmaxf(v0, 0.f); v1 = fmaxf(v1, 0.f); }
            af[e] = f2bf(v0); af[4 + e] = f2bf(v1);
        }
        const short* bbase = Wb + ((size_t)((k0 >> 3) + lk) * N + n0 + lrow) * 8;
        #pragma unroll
        for (int nt = 0; nt < 4; ++nt) {
            bf16x8 bf = *reinterpret_cast<const bf16x8*>(bbase + nt * 128);
            acc[nt] = __builtin_amdgcn_mfma_f32_16x16x32_bf16(af, bf, acc[nt], 0, 0, 0);
        }
    }
    #pragma unroll
    for (int nt = 0; nt < 4; ++nt) {
        int col = n0 + nt * 16 + lrow;
        float bv = bias[col];
        #pragma unroll
        for (int r = 0; r < 4; ++r) {
            int row = m0 + lk * 4 + r;
            C[(size_t)row * N + col] = acc[nt][r] + bv;
        }
    }
}

// GCN layer body: y[b,i,:] = relu((adj@x)[b,i,:] @ W + rowsum(adj)_i * bias)
__device__ __forceinline__ void gcn_layer_body(
    const float* __restrict__ x, const float* __restrict__ adj,
    const float* __restrict__ W, const float* __restrict__ bias,
    float* __restrict__ y, int KIN, int bi, int tid,
    float* arow, float* u) {
    int b = bi / NK, i = bi % NK;
    if (tid < NK) arow[tid] = adj[((size_t)b * NK + i) * NK + tid];
    __syncthreads();
    if (tid < KIN) {
        float a0 = 0.f, a1 = 0.f;
        for (int j = 0; j < NK; j += 2) {
            a0 = fmaf(arow[j],     x[((size_t)b * NK + j)     * KIN + tid], a0);
            a1 = fmaf(arow[j + 1], x[((size_t)b * NK + j + 1) * KIN + tid], a1);
        }
        u[tid] = a0 + a1;
    }
    float rs = 0.f;
    for (int j = 0; j < NK; ++j) rs += arow[j];
    __syncthreads();
    float a0 = 0.f, a1 = 0.f, a2 = 0.f, a3 = 0.f;
    int kk = 0;
    for (; kk + 4 <= KIN; kk += 4) {
        a0 = fmaf(u[kk],     W[(size_t)kk * DD + tid],       a0);
        a1 = fmaf(u[kk + 1], W[(size_t)(kk + 1) * DD + tid], a1);
        a2 = fmaf(u[kk + 2], W[(size_t)(kk + 2) * DD + tid], a2);
        a3 = fmaf(u[kk + 3], W[(size_t)(kk + 3) * DD + tid], a3);
    }
    for (; kk < KIN; ++kk) a0 = fmaf(u[kk], W[(size_t)kk * DD + tid], a0);
    float v = a0 + a1 + a2 + a3 + rs * bias[tid];
    y[((size_t)b * NK + i) * DD + tid] = fmaxf(v, 0.f);
}

// GCN tail body: layer2 -> comp -> qc
__device__ __forceinline__ void gcn_tail_body(
    const float* __restrict__ y1, const float* __restrict__ adj,
    const float* __restrict__ W2, const float* __restrict__ b2,
    const float* __restrict__ Wf, const float* __restrict__ bf,
    const float* __restrict__ Wjc, const float* __restrict__ bjc,
    float* __restrict__ comp, float* __restrict__ qcout,
    int bi, int tid, float* arow, float* u) {
    int b = bi / NK, i = bi % NK;
    if (tid < NK) arow[tid] = adj[((size_t)b * NK + i) * NK + tid];
    __syncthreads();
    {
        float a0 = 0.f, a1 = 0.f;
        for (int j = 0; j < NK; j += 2) {
            a0 = fmaf(arow[j],     y1[((size_t)b * NK + j)     * DD + tid], a0);
            a1 = fmaf(arow[j + 1], y1[((size_t)b * NK + j + 1) * DD + tid], a1);
        }
        u[tid] = a0 + a1;
    }
    float rs = 0.f;
    for (int j = 0; j < NK; ++j) rs += arow[j];
    __syncthreads();
    float a0 = 0.f, a1 = 0.f, a2 = 0.f, a3 = 0.f;
    #pragma unroll 4
    for (int kk = 0; kk < DD; kk += 4) {
        a0 = fmaf(u[kk],     W2[(size_t)kk * DD + tid],       a0);
        a1 = fmaf(u[kk + 1], W2[(size_t)(kk + 1) * DD + tid], a1);
        a2 = fmaf(u[kk + 2], W2[(size_t)(kk + 2) * DD + tid], a2);
        a3 = fmaf(u[kk + 3], W2[(size_t)(kk + 3) * DD + tid], a3);
    }
    float y2 = fmaxf(a0 + a1 + a2 + a3 + rs * b2[tid], 0.f);
    __syncthreads();
    u[tid] = y2;
    __syncthreads();
    a0 = a1 = a2 = a3 = 0.f;
    #pragma unroll 4
    for (int kk = 0; kk < DD; kk += 4) {
        a0 = fmaf(u[kk],     Wf[(size_t)kk * DD + tid],       a0);
        a1 = fmaf(u[kk + 1], Wf[(size_t)(kk + 1) * DD + tid], a1);
        a2 = fmaf(u[kk + 2], Wf[(size_t)(kk + 2) * DD + tid], a2);
        a3 = fmaf(u[kk + 3], Wf[(size_t)(kk + 3) * DD + tid], a3);
    }
    float cv = a0 + a1 + a2 + a3 + bf[tid];
    comp[((size_t)b * NK + i) * DD + tid] = cv;
    __syncthreads();
    u[tid] = fmaxf(cv, 0.f);
    __syncthreads();
    a0 = a1 = a2 = a3 = 0.f;
    #pragma unroll 4
    for (int kk = 0; kk < DD; kk += 4) {
        a0 = fmaf(u[kk],     Wjc[(size_t)kk * DD + tid],       a0);
        a1 = fmaf(u[kk + 1], Wjc[(size_t)(kk + 1) * DD + tid], a1);
        a2 = fmaf(u[kk + 2], Wjc[(size_t)(kk + 2) * DD + tid], a2);
        a3 = fmaf(u[kk + 3], Wjc[(size_t)(kk + 3) * DD + tid], a3);
    }
    qcout[((size_t)b * NK + i) * DD + tid] = a0 + a1 + a2 + a3 + bjc[tid];
}

// ---------------------------------------------------------------------------
// K1: prep (wcvt x2, fusedcvt, zero) + gcn_layer0.  Grid 1125.
// zero region: accums(48) + raw1(4800) + raw2(2400) + cp(2048) = 9296
__global__ __launch_bounds__(256) void k1_kernel(
    const float* __restrict__ W_prot, short* __restrict__ Wb1,
    const float* __restrict__ Wjp, short* __restrict__ Wb2,
    const float* __restrict__ fusedM, short* __restrict__ fMb,
    float* __restrict__ zero_region,
    const float* __restrict__ drug_ver, const float* __restrict__ adj,
    const float* __restrict__ W0, const float* __restrict__ b0,
    float* __restrict__ y0) {
    __shared__ float smem[2112];           // 16*132 tile; reused by gcn0
    int blk = blockIdx.x, tid = threadIdx.x;
    if (blk < 96) {
        int idx = blk * 256 + tid;
        int koct = idx / DD, n = idx % DD;
        bf16x8 v;
        #pragma unroll
        for (int e = 0; e < 8; ++e)
            v[e] = f2bf(W_prot[(size_t)(koct * 8 + e) * DD + n]);
        *reinterpret_cast<bf16x8*>(Wb1 + (size_t)idx * 8) = v;
    } else if (blk < 128) {
        int idx = (blk - 96) * 256 + tid;
        int koct = idx / DD, n = idx % DD;
        bf16x8 v;
        #pragma unroll
        for (int e = 0; e < 8; ++e)
            v[e] = f2bf(Wjp[(size_t)(koct * 8 + e) * DD + n]);
        *reinterpret_cast<bf16x8*>(Wb2 + (size_t)idx * 8) = v;
    } else if (blk < 640) {
        int blk2 = blk - 128;              // 512 blocks: 64 t-tiles x 8 i-tiles
        int t0 = (blk2 >> 3) * 16;
        int i0 = (blk2 & 7) * 128;
        for (int l = tid; l < 16 * 128; l += 256) {
            int tt = l >> 7, ii = l & 127;
            int t = t0 + tt, i = i0 + ii;
            smem[tt * 132 + ii] = (t < NT && i < NP) ? fusedM[(size_t)t * NP + i] : 0.f;
        }
        __syncthreads();
        int octl = tid >> 4, tl = tid & 15;
        bf16x8 v;
        #pragma unroll
        for (int e = 0; e < 8; ++e)
            v[e] = f2bf(smem[tl * 132 + octl * 8 + e]);
        size_t oct = i0 / 8 + octl;
        *reinterpret_cast<bf16x8*>(fMb + (oct * 1024 + t0 + tl) * 8) = v;
    } else if (blk < 677) {
        int idx = (blk - 640) * 256 + tid;
        if (idx < 48 + B * 600 + B * 300 + B * DD) zero_region[idx] = 0.f;
    } else {
        gcn_layer_body(drug_ver, adj, W0, b0, y0, DV, blk - 677, tid,
                       smem, smem + 64);
    }
}

// ---------------------------------------------------------------------------
// K2: prot GEMM (500) + gcn_layer1 (448).  Grid 948.
__global__ __launch_bounds__(256) void k2_kernel(
    const float* __restrict__ prot_data, const short* __restrict__ Wb1,
    const float* __restrict__ b_prot, float* __restrict__ prot,
    const float* __restrict__ y0, const float* __restrict__ adj,
    const float* __restrict__ W1, const float* __restrict__ b1,
    float* __restrict__ y1) {
    __shared__ float smem[320];
    int blk = blockIdx.x, tid = threadIdx.x;
    if (blk < 500)
        gemm_body<false>(prot_data, Wb1, b_prot, prot, DD, DP, blk >> 1, blk & 1, tid);
    else
        gcn_layer_body(y0, adj, W1, b1, y1, DD, blk - 500, tid, smem, smem + 64);
}

// K3: qp GEMM (500) + gcn_tail (448).  Grid 948.
__global__ __launch_bounds__(256) void k3_kernel(
    const float* __restrict__ prot, const short* __restrict__ Wb2,
    const float* __restrict__ bjp, float* __restrict__ qp,
    const float* __restrict__ y1, const float* __restrict__ adj,
    const float* __restrict__ W2, const float* __restrict__ b2,
    const float* __restrict__ Wf, const float* __restrict__ bf,
    const float* __restrict__ Wjc, const float* __restrict__ bjc,
    float* __restrict__ comp, float* __restrict__ qc) {
    __shared__ float smem[320];
    int blk = blockIdx.x, tid = threadIdx.x;
    if (blk < 500)
        gemm_body<true>(prot, Wb2, bjp, qp, DD, DD, blk >> 1, blk & 1, tid);
    else
        gcn_tail_body(y1, adj, W2, b2, Wf, bf, Wjc, bjc, comp, qc,
                      blk - 500, tid, smem, smem + 64);
}

// ---------------------------------------------------------------------------
// inter_all: both operands LDS-staged; raw inter; moments; s_bi; iTb bf16.
__global__ __launch_bounds__(256) void inter_all_kernel(
    const float* __restrict__ qp, const float* __restrict__ qc,
    const float* __restrict__ prot_inter, const float* __restrict__ exist,
    float* __restrict__ inter, float* __restrict__ s_bi,
    short* __restrict__ iTb, float* __restrict__ accums) {
    int b = blockIdx.x / 125, chunk = blockIdx.x % 125;
    __shared__ float qcT[DD * 57];
    __shared__ float qpS[8][DD];
    __shared__ float vS[8][57];
    __shared__ float wred[4][4];
    int tid = threadIdx.x;
    for (int l = tid; l < NK * DD; l += 256) {
        int k = l / DD, d = l % DD;
        qcT[d * 57 + k] = qc[((size_t)b * NK + k) * DD + d];
    }
    for (int l = tid; l < 8 * DD; l += 256) {
        int r = l >> 8, d = l & 255;
        qpS[r][d] = qp[((size_t)b * NP + chunk * 8 + r) * DD + d];
    }
    __syncthreads();
    int w = tid >> 6, lane = tid & 63;
    float ex = exist[b];
    int r0 = w * 2, r1 = w * 2 + 1;
    float acc0 = 0.f, acc1 = 0.f;
    if (lane < NK) {
        #pragma unroll 8
        for (int d = 0; d < DD; ++d) {
            float c = qcT[d * 57 + lane];
            acc0 = fmaf(qpS[r0][d], c, acc0);
            acc1 = fmaf(qpS[r1][d], c, acc1);
        }
    }
    float aV = 0.f, aA = 0.f, aC = 0.f, aD = 0.f;
    #pragma unroll
    for (int ii = 0; ii < 2; ++ii) {
        int i = chunk * 8 + w * 2 + ii;
        float v = 0.f, lab = 0.f;
        if (lane < NK) {
            float acc = (ii == 0) ? acc0 : acc1;
            v = 1.f / (1.f + __expf(-acc));
            lab = ex * prot_inter[((size_t)b * NP + i) * NK + lane];
            inter[((size_t)b * NP + i) * NK + lane] = v;
            vS[w * 2 + ii][lane] = v;
        }
        float v2 = v * v;
        float r = v2;
        #pragma unroll
        for (int off = 32; off; off >>= 1) r += __shfl_down(r, off);
        if (lane == 0) s_bi[(size_t)b * NP + i] = r;
        aV += v; aA += v2; aC += v * lab; aD += lab * lab;
    }
    #pragma unroll
    for (int off = 32; off; off >>= 1) {
        aV += __shfl_down(aV, off);
        aA += __shfl_down(aA, off);
        aC += __shfl_down(aC, off);
        aD += __shfl_down(aD, off);
    }
    if (lane == 0) {
        wred[w][0] = aV; wred[w][1] = aA; wred[w][2] = aC; wred[w][3] = aD;
    }
    __syncthreads();
    if (tid < 4) {
        float s = wred[0][tid] + wred[1][tid] + wred[2][tid] + wred[3][tid];
        atomicAdd(&accums[tid * 8 + b], s);
    }
    if (tid < NK) {
        bf16x8 pk;
        #pragma unroll
        for (int e = 0; e < 8; ++e) pk[e] = f2bf(vS[e][tid]);
        *reinterpret_cast<bf16x8*>(iTb + ((size_t)chunk * 448 + b * NK + tid) * 8) = pk;
        if (chunk == 124) {
            bf16x8 z = {0,0,0,0,0,0,0,0};
            #pragma unroll
            for (int oct = 125; oct < 128; ++oct)
                *reinterpret_cast<bf16x8*>(iTb + ((size_t)oct * 448 + b * NK + tid) * 8) = z;
        }
    }
}

// ---------------------------------------------------------------------------
// K5: cp_partial (1000) + fused MFMA (112) + group (2000).  Grid 3112.
__global__ __launch_bounds__(256) void k5_kernel(
    const float* __restrict__ prot, const float* __restrict__ comp,
    const float* __restrict__ inter, float* __restrict__ cp,
    const short* __restrict__ iTb, const short* __restrict__ fMb,
    float* __restrict__ fusedAbs,
    const float* __restrict__ contacts, const float* __restrict__ s_bi,
    const float* __restrict__ accums, float* __restrict__ groupv) {
    __shared__ float irow[8][NK];
    __shared__ float sb[8];
    int blk = blockIdx.x, tid = threadIdx.x;
    if (blk < 1000) {
        // --- cp partial: atomicAdd into cp[b*256+d]
        int b = blk / 125, chunk = blk % 125;
        int d = tid;
        float creg[NK];
        #pragma unroll
        for (int k = 0; k < NK; ++k)
            creg[k] = comp[((size_t)b * NK + k) * DD + d];
        for (int l = tid; l < 8 * NK; l += 256) {
            int ii = l / NK, k = l % NK;
            irow[ii][k] = inter[((size_t)b * NP + chunk * 8 + ii) * NK + k];
        }
        const float C2LOG2E = 2.8853900817779268f;
        float p2l[8];
        #pragma unroll
        for (int ii = 0; ii < 8; ++ii)
            p2l[ii] = C2LOG2E * prot[((size_t)b * NP + chunk * 8 + ii) * DD + d];
        __syncthreads();
        float acc0 = 0.f, acc1 = 0.f;
        #pragma unroll 1
        for (int ii = 0; ii < 8; ++ii) {
            float p = p2l[ii];
            #pragma unroll
            for (int k = 0; k < NK; k += 2) {
                float e0 = __builtin_amdgcn_exp2f(p * creg[k]);
                float e1 = __builtin_amdgcn_exp2f(p * creg[k + 1]);
                float r0 = __builtin_amdgcn_rcpf(e0 + 1.f);
                float r1 = __builtin_amdgcn_rcpf(e1 + 1.f);
                acc0 = fmaf(fmaf(-2.f, r0, 1.f), irow[ii][k],     acc0);
                acc1 = fmaf(fmaf(-2.f, r1, 1.f), irow[ii][k + 1], acc1);
            }
        }
        atomicAdd(&cp[(size_t)b * DD + d], acc0 + acc1);
    } else if (blk < 1112) {
        // --- fused regularizer MFMA + abs
        int fblk = blk - 1000;
        int mb = fblk % 14, nb = fblk / 14;
        int lane = tid & 63, w = tid >> 6;
        if (tid < 8) sb[tid] = 0.f;
        __syncthreads();
        int m0 = mb * 32 + (w >> 1) * 16;
        int n0 = nb * 128 + (w & 1) * 64;
        int lrow = lane & 15, lk = lane >> 4;
        f32x4 acc[4] = {{0.f,0.f,0.f,0.f},{0.f,0.f,0.f,0.f},
                        {0.f,0.f,0.f,0.f},{0.f,0.f,0.f,0.f}};
        for (int koct0 = 0; koct0 < 128; koct0 += 4) {
            int koct = koct0 + lk;
            bf16x8 af = *reinterpret_cast<const bf16x8*>(
                iTb + ((size_t)koct * 448 + m0 + lrow) * 8);
            const short* bb = fMb + ((size_t)koct * 1024 + n0 + lrow) * 8;
            #pragma unroll
            for (int nt = 0; nt < 4; ++nt) {
                bf16x8 bf = *reinterpret_cast<const bf16x8*>(bb + nt * 128);
                acc[nt] = __builtin_amdgcn_mfma_f32_16x16x32_bf16(af, bf, acc[nt], 0, 0, 0);
            }
        }
        #pragma unroll
        for (int r = 0; r < 4; ++r) {
            float part = fabsf(acc[0][r]) + fabsf(acc[1][r]) +
                         fabsf(acc[2][r]) + fabsf(acc[3][r]);
            #pragma unroll
            for (int off = 1; off < 16; off <<= 1)
                part += __shfl_xor(part, off);
            if (lrow == 0) {
                int row = m0 + lk * 4 + r;
                atomicAdd(&sb[row / NK], part);
            }
        }
        __syncthreads();
        if (tid < 8 && sb[tid] != 0.f) atomicAdd(&fusedAbs[tid], sb[tid]);
    } else {
        // --- group: one wave per (b,k) row, 4 rows per block
        int w = tid >> 6, lane = tid & 63;
        int gk = (blk - 1112) * 4 + w;     // 0..7999
        int b = gk / NP;
        const f32x4* row4 = reinterpret_cast<const f32x4*>(
            contacts + (size_t)gk * NP);
        const f32x4* sv4 = reinterpret_cast<const f32x4*>(s_bi + (size_t)b * NP);
        f32x4 z = {0.f, 0.f, 0.f, 0.f};
        f32x4 c0 = row4[lane];
        f32x4 c1 = row4[lane + 64];
        f32x4 c2 = row4[lane + 128];
        f32x4 c3 = z, s3 = z;
        f32x4 s0 = sv4[lane];
        f32x4 s1 = sv4[lane + 64];
        f32x4 s2 = sv4[lane + 128];
        if (lane + 192 < 250) { c3 = row4[lane + 192]; s3 = sv4[lane + 192]; }
        float g0 = 0.f, g1 = 0.f, g2 = 0.f, g3 = 0.f;
        #pragma unroll
        for (int e = 0; e < 4; ++e) {
            g0 = fmaf(c0[e], s0[e], g0);
            g1 = fmaf(c1[e], s1[e], g1);
            g2 = fmaf(c2[e], s2[e], g2);
            g3 = fmaf(c3[e], s3[e], g3);
        }
        float r0 = (c0[0] + c0[1]) + (c0[2] + c0[3]);
        float r1 = (c1[0] + c1[1]) + (c1[2] + c1[3]);
        float r2 = (c2[0] + c2[1]) + (c2[2] + c2[3]);
        float r3 = (c3[0] + c3[1]) + (c3[2] + c3[3]);
        float g = (g0 + g1) + (g2 + g3);
        float rs = (r0 + r1) + (r2 + r3);
        #pragma unroll
        for (int off = 32; off; off >>= 1) {
            g += __shfl_down(g, off);
            rs += __shfl_down(rs, off);
        }
        if (lane == 0) {
            float val;
            if (g == 0.f) val = sqrtf(1e10f) * sqrtf(rs);
            else          val = sqrtf(g) / accums[b] * sqrtf(rs);
            groupv[gk] = val;
        }
    }
}

// ---------------------------------------------------------------------------
// convpool: per-batch block 256 thr. reads cp directly (+/S), conv+leaky+pool.
__global__ __launch_bounds__(256) void convpool_kernel(
    const float* __restrict__ cp, const float* __restrict__ accums,
    const float* __restrict__ conv_w, const float* __restrict__ conv_b,
    float* __restrict__ pooled) {
    int b = blockIdx.x, t = threadIdx.x;
    __shared__ float xS[258];
    __shared__ float convo[8192];
    float invS = 1.f / accums[b];
    xS[t + 1] = cp[(size_t)b * DD + t] * invS;
    if (t == 0) { xS[0] = 0.f; xS[257] = 0.f; }
    __syncthreads();
    for (int l = t; l < 8192; l += 256) {
        int o = l >> 7, pos = l & 127;
        float acc = conv_b[o];
        int base = pos * 2;
        #pragma unroll
        for (int h = 0; h < 4; ++h)
            acc = fmaf(xS[base + h], conv_w[o * 4 + h], acc);
        convo[l] = (acc > 0.f) ? acc : 0.1f * acc;
    }
    __syncthreads();
    for (int l = t; l < 2048; l += 256) {
        int o = l >> 5, p = l & 31;
        float m = convo[o * 128 + p * 4];
        m = fmaxf(m, convo[o * 128 + p * 4 + 1]);
        m = fmaxf(m, convo[o * 128 + p * 4 + 2]);
        m = fmaxf(m, convo[o * 128 + p * 4 + 3]);
        pooled[b * 2048 + l] = m;
    }
}

// ---------------------------------------------------------------------------
// FC partial: grid (o_tiles, k_splits). If FIN, staging applies bias+leaky.
template<bool FIN>
__global__ __launch_bounds__(256) void fc_partial_kernel(
    const float* __restrict__ in, const float* __restrict__ bias_in,
    const float* __restrict__ W, float* __restrict__ raw,
    int K, int N, int kchunk) {
    int t = threadIdx.x;
    int ol = t & 63;
    int o = blockIdx.x * 64 + ol;
    int w = t >> 6;
    int kbeg = blockIdx.y * kchunk;
    int kend = kbeg + kchunk; if (kend > K) kend = K;
    int len = kend - kbeg;
    __shared__ float sin_[B][128];
    for (int l = t; l < B * len; l += 256) {
        int b = l / len, k = l % len;
        float v = in[(size_t)b * K + kbeg + k];
        if (FIN) {
            v += bias_in[kbeg + k];
            v = (v > 0.f) ? v : 0.1f * v;
        }
        sin_[b][k] = v;
    }
    __syncthreads();
    float acc[B];
    #pragma unroll
    for (int b = 0; b < B; ++b) acc[b] = 0.f;
    if (o < N) {
        for (int k = kbeg + w; k < kend; k += 4) {
            float wv = W[(size_t)k * N + o];
            int kl = k - kbeg;
            #pragma unroll
            for (int b = 0; b < B; ++b)
                acc[b] = fmaf(sin_[b][kl], wv, acc[b]);
        }
    }
    __shared__ float red[4][64][B];
    #pragma unroll
    for (int b = 0; b < B; ++b) red[w][ol][b] = acc[b];
    __syncthreads();
    for (int p = t; p < 64 * B; p += 256) {
        int oo = p / B, b = p % B;
        int o2 = blockIdx.x * 64 + oo;
        if (o2 < N) {
            float s = red[0][oo][b] + red[1][oo][b] + red[2][oo][b] + red[3][oo][b];
            atomicAdd(&raw[(size_t)b * N + o2], s);
        }
    }
}

// ---------------------------------------------------------------------------
// final: inline fc3 (raw2 + b_r2 -> leaky -> dot W3) + groupv sum + assembly.
__global__ __launch_bounds__(256) void final_kernel(
    const float* __restrict__ accums, const float* __restrict__ groupv,
    const float* __restrict__ raw2, const float* __restrict__ b_r2,
    const float* __restrict__ W3, const float* __restrict__ b3,
    const float* __restrict__ label, float* __restrict__ out) {
    int tid = threadIdx.x;
    __shared__ float affnS[8];
    {
        int b = tid >> 5, k0 = tid & 31;
        float acc = 0.f;
        for (int k = k0; k < 300; k += 32) {
            float v = raw2[(size_t)b * 300 + k] + b_r2[k];
            v = (v > 0.f) ? v : 0.1f * v;
            acc = fmaf(v, W3[k], acc);
        }
        #pragma unroll
        for (int off = 16; off; off >>= 1) acc += __shfl_down(acc, off);
        if (k0 == 0) affnS[b] = acc + b3[0];
    }
    float s = 0.f;
    for (int l = tid; l < B * NP; l += 256) s += groupv[l];
    __shared__ float r[256];
    r[tid] = s;
    __syncthreads();
    for (int st = 128; st; st >>= 1) {
        if (tid < st) r[tid] += r[tid + st];
        __syncthreads();
    }
    if (tid == 0) {
        float gtot = r[0];
        float l0 = 0.f, l1 = 0.f, l2 = 0.f;
        for (int b = 0; b < B; ++b) {
            float S = accums[b];
            float A = accums[8 + b], C = accums[16 + b], D = accums[24 + b];
            float fA = accums[32 + b];
            l0 += 1.f + fA / S;
            float bind = A / (S * S) - 2.f * C / S + D;
            l1 += sqrtf(fmaxf(bind, 0.f));
            float dd = affnS[b] - label[b];
            l2 += dd * dd;
        }
        out[0] = (l0 + gtot + l1 + l2) * 0.125f;
    }
}

// ---------------------------------------------------------------------------
extern "C" void kernel_launch(void* const* d_in, const int* in_sizes, int n_in,
                              void* d_out, int out_size, void* d_ws, size_t ws_size,
                              hipStream_t stream) {
    const float* prot_data   = (const float*)d_in[0];
    const float* drug_ver    = (const float*)d_in[1];
    const float* drug_adj    = (const float*)d_in[2];
    const float* contacts    = (const float*)d_in[3];
    const float* prot_inter  = (const float*)d_in[4];
    const float* exist       = (const float*)d_in[5];
    const float* label       = (const float*)d_in[6];
    const float* fused       = (const float*)d_in[7];
    const float* W_prot      = (const float*)d_in[8];
    const float* b_prot      = (const float*)d_in[9];
    const float* gcn_W0      = (const float*)d_in[10];
    const float* gcn_b0      = (const float*)d_in[11];
    const float* gcn_W1      = (const float*)d_in[12];
    const float* gcn_b1      = (const float*)d_in[13];
    const float* gcn_W2      = (const float*)d_in[14];
    const float* gcn_b2      = (const float*)d_in[15];
    const float* gcn_Wf      = (const float*)d_in[16];
    const float* gcn_bf      = (const float*)d_in[17];
    const float* Wjp         = (const float*)d_in[18];
    const float* bjp         = (const float*)d_in[19];
    const float* Wjc         = (const float*)d_in[20];
    const float* bjc         = (const float*)d_in[21];
    const float* conv_w      = (const float*)d_in[22];
    const float* conv_b      = (const float*)d_in[23];
    const float* W_r1        = (const float*)d_in[24];
    const float* b_r1        = (const float*)d_in[25];
    const float* W_r2        = (const float*)d_in[26];
    const float* b_r2        = (const float*)d_in[27];
    const float* W_r3        = (const float*)d_in[28];
    const float* b_r3        = (const float*)d_in[29];

    float* ws = (float*)d_ws;
    size_t off = 0;
    auto alloc = [&](size_t n) { float* p = ws + off; off += n; return p; };
    float* prot     = alloc((size_t)B * NP * DD);
    float* qp       = alloc((size_t)B * NP * DD);
    float* tbuf     = alloc((size_t)B * NK * DD);   // y0; +ybuf = iTb alias
    float* ybuf     = alloc((size_t)B * NK * DD);   // y1
    float* comp     = alloc((size_t)B * NK * DD);
    float* qc       = alloc((size_t)B * NK * DD);
    float* inter    = alloc((size_t)B * NP * NK);
    float* s_bi     = alloc((size_t)B * NP);
    float* pooled   = alloc((size_t)B * 2048);
    float* groupv   = alloc((size_t)B * NP);
    short* Wb1      = (short*)alloc((DP / 8) * DD * 8 / 2);
    short* Wb2      = (short*)alloc((DD / 8) * DD * 8 / 2);
    short* fMb      = (short*)alloc((size_t)128 * 1024 * 8 / 2);
    // zero region: accums(48) + raw1(4800) + raw2(2400) + cp(2048)
    float* accums   = alloc(48);
    float* raw1     = alloc((size_t)B * 600);
    float* raw2     = alloc((size_t)B * 300);
    float* cp       = alloc((size_t)B * DD);

    // iTb[128][448][8] bf16 aliases tbuf+ybuf (dead after K3)
    short* iTb = (short*)tbuf;
    (void)ybuf;

    // 1. prep (+gcn layer0)
    k1_kernel<<<1125, 256, 0, stream>>>(W_prot, Wb1, Wjp, Wb2, fused, fMb,
                                        accums, drug_ver, drug_adj,
                                        gcn_W0, gcn_b0, tbuf);

    // 2. prot GEMM + gcn layer1
    k2_kernel<<<948, 256, 0, stream>>>(prot_data, Wb1, b_prot, prot,
                                       tbuf, drug_adj, gcn_W1, gcn_b1, ybuf);

    // 3. qp GEMM + gcn tail
    k3_kernel<<<948, 256, 0, stream>>>(prot, Wb2, bjp, qp,
                                       ybuf, drug_adj, gcn_W2, gcn_b2,
                                       gcn_Wf, gcn_bf, Wjc, bjc, comp, qc);

    // 4. inter (raw) + moments + s_bi + iTb
    inter_all_kernel<<<B * 125, 256, 0, stream>>>(
        qp, qc, prot_inter, exist, inter, s_bi, iTb, accums);

    // 5. cp partial + fused MFMA + group
    k5_kernel<<<3112, 256, 0, stream>>>(prot, comp, inter, cp,
                                        iTb, fMb, accums + 32,
                                        contacts, s_bi, accums, groupv);

    // 6. conv/pool
    convpool_kernel<<<B, 256, 0, stream>>>(cp, accums, conv_w, conv_b, pooled);

    // 7-8. FC stack
    fc_partial_kernel<false><<<dim3(10, 16), 256, 0, stream>>>(
        pooled, nullptr, W_r1, raw1, 2048, 600, 128);
    fc_partial_kernel<true><<<dim3(5, 8), 256, 0, stream>>>(
        raw1, b_r1, W_r2, raw2, 600, 300, 75);

    // 9. final loss (fc3 inline + group sum + assembly)
    final_kernel<<<1, 256, 0, stream>>>(accums, groupv, raw2, b_r2,
                                        W_r3, b_r3, label, (float*)d_out);
}

// Round 15
// 160.671 us; speedup vs baseline: 2.4128x; 1.0141x over previous
//
#include <hip/hip_runtime.h>
#include <hip/hip_bf16.h>
#include <math.h>

// ---------------------------------------------------------------------------
#define B 8
#define NP 1000
#define NK 56
#define DP 768
#define DV 43
#define DD 256
#define NT 999

typedef __attribute__((ext_vector_type(8))) short bf16x8;
typedef __attribute__((ext_vector_type(4))) float f32x4;

__device__ inline short f2bf(float x) {
    __hip_bfloat16 h = __float2bfloat16(x);
    return __builtin_bit_cast(short, h);
}

// ---------------------------------------------------------------------------
// Device bodies shared by merged kernels
// ---------------------------------------------------------------------------

// MFMA GEMM body with A-prefetch: C = act_in(A) @ Wb + bias.
template<bool RELU_IN>
__device__ __forceinline__ void gemm_body(
    const float* __restrict__ A, const short* __restrict__ Wb,
    const float* __restrict__ bias, float* __restrict__ C,
    int N, int K, int bm, int bn, int tid) {
    int lane = tid & 63, w = tid >> 6;
    int m0 = bm * 32 + (w >> 1) * 16;
    int n0 = bn * 128 + (w & 1) * 64;
    int lrow = lane & 15, lk = lane >> 4;
    f32x4 acc[4] = {{0.f,0.f,0.f,0.f},{0.f,0.f,0.f,0.f},
                    {0.f,0.f,0.f,0.f},{0.f,0.f,0.f,0.f}};
    const float* arow = A + (size_t)(m0 + lrow) * K + lk * 8;
    f32x4 a0 = *reinterpret_cast<const f32x4*>(arow);
    f32x4 a1 = *reinterpret_cast<const f32x4*>(arow + 4);
    for (int k0 = 0; k0 < K; k0 += 32) {
        f32x4 c0 = a0, c1 = a1;
        if (k0 + 32 < K) {          // prefetch next tile before MFMA chain
            a0 = *reinterpret_cast<const f32x4*>(arow + k0 + 32);
            a1 = *reinterpret_cast<const f32x4*>(arow + k0 + 36);
        }
        bf16x8 af;
        #pragma unroll
        for (int e = 0; e < 4; ++e) {
            float v0 = c0[e], v1 = c1[e];
            if (RELU_IN) { v0 = fmaxf(v0, 0.f); v1 = fmaxf(v1, 0.f); }
            af[e] = f2bf(v0); af[4 + e] = f2bf(v1);
        }
        const short* bbase = Wb + ((size_t)((k0 >> 3) + lk) * N + n0 + lrow) * 8;
        #pragma unroll
        for (int nt = 0; nt < 4; ++nt) {
            bf16x8 bf = *reinterpret_cast<const bf16x8*>(bbase + nt * 128);
            acc[nt] = __builtin_amdgcn_mfma_f32_16x16x32_bf16(af, bf, acc[nt], 0, 0, 0);
        }
    }
    #pragma unroll
    for (int nt = 0; nt < 4; ++nt) {
        int col = n0 + nt * 16 + lrow;
        float bv = bias[col];
        #pragma unroll
        for (int r = 0; r < 4; ++r) {
            int row = m0 + lk * 4 + r;
            C[(size_t)row * N + col] = acc[nt][r] + bv;
        }
    }
}

// GCN layer body: y[b,i,:] = relu((adj@x)[b,i,:] @ W + rowsum(adj)_i * bias)
__device__ __forceinline__ void gcn_layer_body(
    const float* __restrict__ x, const float* __restrict__ adj,
    const float* __restrict__ W, const float* __restrict__ bias,
    float* __restrict__ y, int KIN, int bi, int tid,
    float* arow, float* u) {
    int b = bi / NK, i = bi % NK;
    if (tid < NK) arow[tid] = adj[((size_t)b * NK + i) * NK + tid];
    __syncthreads();
    if (tid < KIN) {
        float a0 = 0.f, a1 = 0.f;
        for (int j = 0; j < NK; j += 2) {
            a0 = fmaf(arow[j],     x[((size_t)b * NK + j)     * KIN + tid], a0);
            a1 = fmaf(arow[j + 1], x[((size_t)b * NK + j + 1) * KIN + tid], a1);
        }
        u[tid] = a0 + a1;
    }
    float rs = 0.f;
    for (int j = 0; j < NK; ++j) rs += arow[j];
    __syncthreads();
    float a0 = 0.f, a1 = 0.f, a2 = 0.f, a3 = 0.f;
    int kk = 0;
    for (; kk + 4 <= KIN; kk += 4) {
        a0 = fmaf(u[kk],     W[(size_t)kk * DD + tid],       a0);
        a1 = fmaf(u[kk + 1], W[(size_t)(kk + 1) * DD + tid], a1);
        a2 = fmaf(u[kk + 2], W[(size_t)(kk + 2) * DD + tid], a2);
        a3 = fmaf(u[kk + 3], W[(size_t)(kk + 3) * DD + tid], a3);
    }
    for (; kk < KIN; ++kk) a0 = fmaf(u[kk], W[(size_t)kk * DD + tid], a0);
    float v = a0 + a1 + a2 + a3 + rs * bias[tid];
    y[((size_t)b * NK + i) * DD + tid] = fmaxf(v, 0.f);
}

// GCN tail body: layer2 -> comp -> qc
__device__ __forceinline__ void gcn_tail_body(
    const float* __restrict__ y1, const float* __restrict__ adj,
    const float* __restrict__ W2, const float* __restrict__ b2,
    const float* __restrict__ Wf, const float* __restrict__ bf,
    const float* __restrict__ Wjc, const float* __restrict__ bjc,
    float* __restrict__ comp, float* __restrict__ qcout,
    int bi, int tid, float* arow, float* u) {
    int b = bi / NK, i = bi % NK;
    if (tid < NK) arow[tid] = adj[((size_t)b * NK + i) * NK + tid];
    __syncthreads();
    {
        float a0 = 0.f, a1 = 0.f;
        for (int j = 0; j < NK; j += 2) {
            a0 = fmaf(arow[j],     y1[((size_t)b * NK + j)     * DD + tid], a0);
            a1 = fmaf(arow[j + 1], y1[((size_t)b * NK + j + 1) * DD + tid], a1);
        }
        u[tid] = a0 + a1;
    }
    float rs = 0.f;
    for (int j = 0; j < NK; ++j) rs += arow[j];
    __syncthreads();
    float a0 = 0.f, a1 = 0.f, a2 = 0.f, a3 = 0.f;
    #pragma unroll 4
    for (int kk = 0; kk < DD; kk += 4) {
        a0 = fmaf(u[kk],     W2[(size_t)kk * DD + tid],       a0);
        a1 = fmaf(u[kk + 1], W2[(size_t)(kk + 1) * DD + tid], a1);
        a2 = fmaf(u[kk + 2], W2[(size_t)(kk + 2) * DD + tid], a2);
        a3 = fmaf(u[kk + 3], W2[(size_t)(kk + 3) * DD + tid], a3);
    }
    float y2 = fmaxf(a0 + a1 + a2 + a3 + rs * b2[tid], 0.f);
    __syncthreads();
    u[tid] = y2;
    __syncthreads();
    a0 = a1 = a2 = a3 = 0.f;
    #pragma unroll 4
    for (int kk = 0; kk < DD; kk += 4) {
        a0 = fmaf(u[kk],     Wf[(size_t)kk * DD + tid],       a0);
        a1 = fmaf(u[kk + 1], Wf[(size_t)(kk + 1) * DD + tid], a1);
        a2 = fmaf(u[kk + 2], Wf[(size_t)(kk + 2) * DD + tid], a2);
        a3 = fmaf(u[kk + 3], Wf[(size_t)(kk + 3) * DD + tid], a3);
    }
    float cv = a0 + a1 + a2 + a3 + bf[tid];
    comp[((size_t)b * NK + i) * DD + tid] = cv;
    __syncthreads();
    u[tid] = fmaxf(cv, 0.f);
    __syncthreads();
    a0 = a1 = a2 = a3 = 0.f;
    #pragma unroll 4
    for (int kk = 0; kk < DD; kk += 4) {
        a0 = fmaf(u[kk],     Wjc[(size_t)kk * DD + tid],       a0);
        a1 = fmaf(u[kk + 1], Wjc[(size_t)(kk + 1) * DD + tid], a1);
        a2 = fmaf(u[kk + 2], Wjc[(size_t)(kk + 2) * DD + tid], a2);
        a3 = fmaf(u[kk + 3], Wjc[(size_t)(kk + 3) * DD + tid], a3);
    }
    qcout[((size_t)b * NK + i) * DD + tid] = a0 + a1 + a2 + a3 + bjc[tid];
}

// ---------------------------------------------------------------------------
// K1: prep (wcvt x2, fusedcvt, zero) + gcn_layer0.  Grid 1125.
// zero region: accums(48) + raw1(4800) + raw2(2400) + cp(2048) = 9296
__global__ __launch_bounds__(256) void k1_kernel(
    const float* __restrict__ W_prot, short* __restrict__ Wb1,
    const float* __restrict__ Wjp, short* __restrict__ Wb2,
    const float* __restrict__ fusedM, short* __restrict__ fMb,
    float* __restrict__ zero_region,
    const float* __restrict__ drug_ver, const float* __restrict__ adj,
    const float* __restrict__ W0, const float* __restrict__ b0,
    float* __restrict__ y0) {
    __shared__ float smem[2112];           // 16*132 tile; reused by gcn0
    int blk = blockIdx.x, tid = threadIdx.x;
    if (blk < 96) {
        int idx = blk * 256 + tid;
        int koct = idx / DD, n = idx % DD;
        bf16x8 v;
        #pragma unroll
        for (int e = 0; e < 8; ++e)
            v[e] = f2bf(W_prot[(size_t)(koct * 8 + e) * DD + n]);
        *reinterpret_cast<bf16x8*>(Wb1 + (size_t)idx * 8) = v;
    } else if (blk < 128) {
        int idx = (blk - 96) * 256 + tid;
        int koct = idx / DD, n = idx % DD;
        bf16x8 v;
        #pragma unroll
        for (int e = 0; e < 8; ++e)
            v[e] = f2bf(Wjp[(size_t)(koct * 8 + e) * DD + n]);
        *reinterpret_cast<bf16x8*>(Wb2 + (size_t)idx * 8) = v;
    } else if (blk < 640) {
        int blk2 = blk - 128;              // 512 blocks: 64 t-tiles x 8 i-tiles
        int t0 = (blk2 >> 3) * 16;
        int i0 = (blk2 & 7) * 128;
        for (int l = tid; l < 16 * 128; l += 256) {
            int tt = l >> 7, ii = l & 127;
            int t = t0 + tt, i = i0 + ii;
            smem[tt * 132 + ii] = (t < NT && i < NP) ? fusedM[(size_t)t * NP + i] : 0.f;
        }
        __syncthreads();
        int octl = tid >> 4, tl = tid & 15;
        bf16x8 v;
        #pragma unroll
        for (int e = 0; e < 8; ++e)
            v[e] = f2bf(smem[tl * 132 + octl * 8 + e]);
        size_t oct = i0 / 8 + octl;
        *reinterpret_cast<bf16x8*>(fMb + (oct * 1024 + t0 + tl) * 8) = v;
    } else if (blk < 677) {
        int idx = (blk - 640) * 256 + tid;
        if (idx < 48 + B * 600 + B * 300 + B * DD) zero_region[idx] = 0.f;
    } else {
        gcn_layer_body(drug_ver, adj, W0, b0, y0, DV, blk - 677, tid,
                       smem, smem + 64);
    }
}

// ---------------------------------------------------------------------------
// K2: prot GEMM (500) + gcn_layer1 (448).  Grid 948.
__global__ __launch_bounds__(256) void k2_kernel(
    const float* __restrict__ prot_data, const short* __restrict__ Wb1,
    const float* __restrict__ b_prot, float* __restrict__ prot,
    const float* __restrict__ y0, const float* __restrict__ adj,
    const float* __restrict__ W1, const float* __restrict__ b1,
    float* __restrict__ y1) {
    __shared__ float smem[320];
    int blk = blockIdx.x, tid = threadIdx.x;
    if (blk < 500)
        gemm_body<false>(prot_data, Wb1, b_prot, prot, DD, DP, blk >> 1, blk & 1, tid);
    else
        gcn_layer_body(y0, adj, W1, b1, y1, DD, blk - 500, tid, smem, smem + 64);
}

// K3: qp GEMM (500) + gcn_tail (448).  Grid 948.
__global__ __launch_bounds__(256) void k3_kernel(
    const float* __restrict__ prot, const short* __restrict__ Wb2,
    const float* __restrict__ bjp, float* __restrict__ qp,
    const float* __restrict__ y1, const float* __restrict__ adj,
    const float* __restrict__ W2, const float* __restrict__ b2,
    const float* __restrict__ Wf, const float* __restrict__ bf,
    const float* __restrict__ Wjc, const float* __restrict__ bjc,
    float* __restrict__ comp, float* __restrict__ qc) {
    __shared__ float smem[320];
    int blk = blockIdx.x, tid = threadIdx.x;
    if (blk < 500)
        gemm_body<true>(prot, Wb2, bjp, qp, DD, DD, blk >> 1, blk & 1, tid);
    else
        gcn_tail_body(y1, adj, W2, b2, Wf, bf, Wjc, bjc, comp, qc,
                      blk - 500, tid, smem, smem + 64);
}

// ---------------------------------------------------------------------------
// inter_all: both operands LDS-staged; raw inter; moments; s_bi; iTb bf16.
__global__ __launch_bounds__(256) void inter_all_kernel(
    const float* __restrict__ qp, const float* __restrict__ qc,
    const float* __restrict__ prot_inter, const float* __restrict__ exist,
    float* __restrict__ inter, float* __restrict__ s_bi,
    short* __restrict__ iTb, float* __restrict__ accums) {
    int b = blockIdx.x / 125, chunk = blockIdx.x % 125;
    __shared__ float qcT[DD * 57];
    __shared__ float qpS[8][DD];
    __shared__ float vS[8][57];
    __shared__ float wred[4][4];
    int tid = threadIdx.x;
    for (int l = tid; l < NK * DD; l += 256) {
        int k = l / DD, d = l % DD;
        qcT[d * 57 + k] = qc[((size_t)b * NK + k) * DD + d];
    }
    for (int l = tid; l < 8 * DD; l += 256) {
        int r = l >> 8, d = l & 255;
        qpS[r][d] = qp[((size_t)b * NP + chunk * 8 + r) * DD + d];
    }
    __syncthreads();
    int w = tid >> 6, lane = tid & 63;
    float ex = exist[b];
    int r0 = w * 2, r1 = w * 2 + 1;
    float acc0 = 0.f, acc1 = 0.f;
    if (lane < NK) {
        #pragma unroll 8
        for (int d = 0; d < DD; ++d) {
            float c = qcT[d * 57 + lane];
            acc0 = fmaf(qpS[r0][d], c, acc0);
            acc1 = fmaf(qpS[r1][d], c, acc1);
        }
    }
    float aV = 0.f, aA = 0.f, aC = 0.f, aD = 0.f;
    #pragma unroll
    for (int ii = 0; ii < 2; ++ii) {
        int i = chunk * 8 + w * 2 + ii;
        float v = 0.f, lab = 0.f;
        if (lane < NK) {
            float acc = (ii == 0) ? acc0 : acc1;
            v = 1.f / (1.f + __expf(-acc));
            lab = ex * prot_inter[((size_t)b * NP + i) * NK + lane];
            inter[((size_t)b * NP + i) * NK + lane] = v;
            vS[w * 2 + ii][lane] = v;
        }
        float v2 = v * v;
        float r = v2;
        #pragma unroll
        for (int off = 32; off; off >>= 1) r += __shfl_down(r, off);
        if (lane == 0) s_bi[(size_t)b * NP + i] = r;
        aV += v; aA += v2; aC += v * lab; aD += lab * lab;
    }
    #pragma unroll
    for (int off = 32; off; off >>= 1) {
        aV += __shfl_down(aV, off);
        aA += __shfl_down(aA, off);
        aC += __shfl_down(aC, off);
        aD += __shfl_down(aD, off);
    }
    if (lane == 0) {
        wred[w][0] = aV; wred[w][1] = aA; wred[w][2] = aC; wred[w][3] = aD;
    }
    __syncthreads();
    if (tid < 4) {
        float s = wred[0][tid] + wred[1][tid] + wred[2][tid] + wred[3][tid];
        atomicAdd(&accums[tid * 8 + b], s);
    }
    if (tid < NK) {
        bf16x8 pk;
        #pragma unroll
        for (int e = 0; e < 8; ++e) pk[e] = f2bf(vS[e][tid]);
        *reinterpret_cast<bf16x8*>(iTb + ((size_t)chunk * 448 + b * NK + tid) * 8) = pk;
        if (chunk == 124) {
            bf16x8 z = {0,0,0,0,0,0,0,0};
            #pragma unroll
            for (int oct = 125; oct < 128; ++oct)
                *reinterpret_cast<bf16x8*>(iTb + ((size_t)oct * 448 + b * NK + tid) * 8) = z;
        }
    }
}

// ---------------------------------------------------------------------------
// K5: cp_partial (1000) + fused MFMA (112) + group (2000).  Grid 3112.
__global__ __launch_bounds__(256) void k5_kernel(
    const float* __restrict__ prot, const float* __restrict__ comp,
    const float* __restrict__ inter, float* __restrict__ cp,
    const short* __restrict__ iTb, const short* __restrict__ fMb,
    float* __restrict__ fusedAbs,
    const float* __restrict__ contacts, const float* __restrict__ s_bi,
    const float* __restrict__ accums, float* __restrict__ groupv) {
    __shared__ float irow[8][NK];
    __shared__ float sb[8];
    int blk = blockIdx.x, tid = threadIdx.x;
    if (blk < 1000) {
        // --- cp partial: atomicAdd into cp[b*256+d]
        int b = blk / 125, chunk = blk % 125;
        int d = tid;
        float creg[NK];
        #pragma unroll
        for (int k = 0; k < NK; ++k)
            creg[k] = comp[((size_t)b * NK + k) * DD + d];
        for (int l = tid; l < 8 * NK; l += 256) {
            int ii = l / NK, k = l % NK;
            irow[ii][k] = inter[((size_t)b * NP + chunk * 8 + ii) * NK + k];
        }
        const float C2LOG2E = 2.8853900817779268f;
        float p2l[8];
        #pragma unroll
        for (int ii = 0; ii < 8; ++ii)
            p2l[ii] = C2LOG2E * prot[((size_t)b * NP + chunk * 8 + ii) * DD + d];
        __syncthreads();
        float acc0 = 0.f, acc1 = 0.f;
        #pragma unroll 1
        for (int ii = 0; ii < 8; ++ii) {
            float p = p2l[ii];
            #pragma unroll
            for (int k = 0; k < NK; k += 2) {
                float e0 = __builtin_amdgcn_exp2f(p * creg[k]);
                float e1 = __builtin_amdgcn_exp2f(p * creg[k + 1]);
                float r0 = __builtin_amdgcn_rcpf(e0 + 1.f);
                float r1 = __builtin_amdgcn_rcpf(e1 + 1.f);
                acc0 = fmaf(fmaf(-2.f, r0, 1.f), irow[ii][k],     acc0);
                acc1 = fmaf(fmaf(-2.f, r1, 1.f), irow[ii][k + 1], acc1);
            }
        }
        atomicAdd(&cp[(size_t)b * DD + d], acc0 + acc1);
    } else if (blk < 1112) {
        // --- fused regularizer MFMA + abs
        int fblk = blk - 1000;
        int mb = fblk % 14, nb = fblk / 14;
        int lane = tid & 63, w = tid >> 6;
        if (tid < 8) sb[tid] = 0.f;
        __syncthreads();
        int m0 = mb * 32 + (w >> 1) * 16;
        int n0 = nb * 128 + (w & 1) * 64;
        int lrow = lane & 15, lk = lane >> 4;
        f32x4 acc[4] = {{0.f,0.f,0.f,0.f},{0.f,0.f,0.f,0.f},
                        {0.f,0.f,0.f,0.f},{0.f,0.f,0.f,0.f}};
        for (int koct0 = 0; koct0 < 128; koct0 += 4) {
            int koct = koct0 + lk;
            bf16x8 af = *reinterpret_cast<const bf16x8*>(
                iTb + ((size_t)koct * 448 + m0 + lrow) * 8);
            const short* bb = fMb + ((size_t)koct * 1024 + n0 + lrow) * 8;
            #pragma unroll
            for (int nt = 0; nt < 4; ++nt) {
                bf16x8 bf = *reinterpret_cast<const bf16x8*>(bb + nt * 128);
                acc[nt] = __builtin_amdgcn_mfma_f32_16x16x32_bf16(af, bf, acc[nt], 0, 0, 0);
            }
        }
        #pragma unroll
        for (int r = 0; r < 4; ++r) {
            float part = fabsf(acc[0][r]) + fabsf(acc[1][r]) +
                         fabsf(acc[2][r]) + fabsf(acc[3][r]);
            #pragma unroll
            for (int off = 1; off < 16; off <<= 1)
                part += __shfl_xor(part, off);
            if (lrow == 0) {
                int row = m0 + lk * 4 + r;
                atomicAdd(&sb[row / NK], part);
            }
        }
        __syncthreads();
        if (tid < 8 && sb[tid] != 0.f) atomicAdd(&fusedAbs[tid], sb[tid]);
    } else {
        // --- group: one wave per (b,k) row, 4 rows per block
        int w = tid >> 6, lane = tid & 63;
        int gk = (blk - 1112) * 4 + w;     // 0..7999
        int b = gk / NP;
        const f32x4* row4 = reinterpret_cast<const f32x4*>(
            contacts + (size_t)gk * NP);
        const f32x4* sv4 = reinterpret_cast<const f32x4*>(s_bi + (size_t)b * NP);
        f32x4 z = {0.f, 0.f, 0.f, 0.f};
        f32x4 c0 = row4[lane];
        f32x4 c1 = row4[lane + 64];
        f32x4 c2 = row4[lane + 128];
        f32x4 c3 = z, s3 = z;
        f32x4 s0 = sv4[lane];
        f32x4 s1 = sv4[lane + 64];
        f32x4 s2 = sv4[lane + 128];
        if (lane + 192 < 250) { c3 = row4[lane + 192]; s3 = sv4[lane + 192]; }
        float g0 = 0.f, g1 = 0.f, g2 = 0.f, g3 = 0.f;
        #pragma unroll
        for (int e = 0; e < 4; ++e) {
            g0 = fmaf(c0[e], s0[e], g0);
            g1 = fmaf(c1[e], s1[e], g1);
            g2 = fmaf(c2[e], s2[e], g2);
            g3 = fmaf(c3[e], s3[e], g3);
        }
        float r0 = (c0[0] + c0[1]) + (c0[2] + c0[3]);
        float r1 = (c1[0] + c1[1]) + (c1[2] + c1[3]);
        float r2 = (c2[0] + c2[1]) + (c2[2] + c2[3]);
        float r3 = (c3[0] + c3[1]) + (c3[2] + c3[3]);
        float g = (g0 + g1) + (g2 + g3);
        float rs = (r0 + r1) + (r2 + r3);
        #pragma unroll
        for (int off = 32; off; off >>= 1) {
            g += __shfl_down(g, off);
            rs += __shfl_down(rs, off);
        }
        if (lane == 0) {
            float val;
            if (g == 0.f) val = sqrtf(1e10f) * sqrtf(rs);
            else          val = sqrtf(g) / accums[b] * sqrtf(rs);
            groupv[gk] = val;
        }
    }
}

// ---------------------------------------------------------------------------
// fc1 with inline conv/pool: stages cp (with /S) in LDS, recomputes its
// pooled chunk, then standard fc1 partial GEMV into raw1 via atomics.
// grid (10 o-tiles, 16 k-splits), kchunk=128.
__global__ __launch_bounds__(256) void fc1_conv_kernel(
    const float* __restrict__ cp, const float* __restrict__ accums,
    const float* __restrict__ conv_w, const float* __restrict__ conv_b,
    const float* __restrict__ W, float* __restrict__ raw) {
    const int K = 2048, N = 600, kchunk = 128;
    int t = threadIdx.x;
    int ol = t & 63;
    int o = blockIdx.x * 64 + ol;
    int w = t >> 6;
    int kbeg = blockIdx.y * kchunk;
    __shared__ float xS[B][258];
    __shared__ float sin_[B][128];
    // stage cp/S with halo pad
    for (int l = t; l < B * DD; l += 256) {
        int b = l >> 8, d = l & 255;
        xS[b][d + 1] = cp[(size_t)b * DD + d] / accums[b];
    }
    if (t < B) { xS[t][0] = 0.f; xS[t][257] = 0.f; }
    __syncthreads();
    // recompute pooled chunk: k = o*32+p, pooled = max_q leaky(conv[o][p*4+q])
    for (int l = t; l < B * kchunk; l += 256) {
        int b = l >> 7, kl = l & 127;
        int kg = kbeg + kl;
        int oo = kg >> 5, p = kg & 31;
        float w0 = conv_w[oo * 4 + 0], w1 = conv_w[oo * 4 + 1];
        float w2 = conv_w[oo * 4 + 2], w3 = conv_w[oo * 4 + 3];
        float cb = conv_b[oo];
        float m = -INFINITY;
        #pragma unroll
        for (int q = 0; q < 4; ++q) {
            int base = (p * 4 + q) * 2;
            float acc = cb;
            acc = fmaf(xS[b][base + 0], w0, acc);
            acc = fmaf(xS[b][base + 1], w1, acc);
            acc = fmaf(xS[b][base + 2], w2, acc);
            acc = fmaf(xS[b][base + 3], w3, acc);
            acc = (acc > 0.f) ? acc : 0.1f * acc;
            m = fmaxf(m, acc);
        }
        sin_[b][kl] = m;
    }
    __syncthreads();
    float acc[B];
    #pragma unroll
    for (int b = 0; b < B; ++b) acc[b] = 0.f;
    for (int k = kbeg + w; k < kbeg + kchunk; k += 4) {
        float wv = W[(size_t)k * N + o];
        int kl = k - kbeg;
        #pragma unroll
        for (int b = 0; b < B; ++b)
            acc[b] = fmaf(sin_[b][kl], wv, acc[b]);
    }
    __shared__ float red[4][64][B];
    #pragma unroll
    for (int b = 0; b < B; ++b) red[w][ol][b] = acc[b];
    __syncthreads();
    for (int p = t; p < 64 * B; p += 256) {
        int oo = p / B, b = p % B;
        int o2 = blockIdx.x * 64 + oo;
        float s = red[0][oo][b] + red[1][oo][b] + red[2][oo][b] + red[3][oo][b];
        atomicAdd(&raw[(size_t)b * N + o2], s);
    }
}

// ---------------------------------------------------------------------------
// fc2 partial: staging applies bias+leaky to raw1.
__global__ __launch_bounds__(256) void fc2_kernel(
    const float* __restrict__ raw1, const float* __restrict__ b_r1,
    const float* __restrict__ W, float* __restrict__ raw2) {
    const int K = 600, N = 300, kchunk = 75;
    int t = threadIdx.x;
    int ol = t & 63;
    int o = blockIdx.x * 64 + ol;
    int w = t >> 6;
    int kbeg = blockIdx.y * kchunk;
    __shared__ float sin_[B][128];
    for (int l = t; l < B * kchunk; l += 256) {
        int b = l / kchunk, k = l % kchunk;
        float v = raw1[(size_t)b * K + kbeg + k] + b_r1[kbeg + k];
        v = (v > 0.f) ? v : 0.1f * v;
        sin_[b][k] = v;
    }
    __syncthreads();
    float acc[B];
    #pragma unroll
    for (int b = 0; b < B; ++b) acc[b] = 0.f;
    if (o < N) {
        for (int k = kbeg + w; k < kbeg + kchunk; k += 4) {
            float wv = W[(size_t)k * N + o];
            int kl = k - kbeg;
            #pragma unroll
            for (int b = 0; b < B; ++b)
                acc[b] = fmaf(sin_[b][kl], wv, acc[b]);
        }
    }
    __shared__ float red[4][64][B];
    #pragma unroll
    for (int b = 0; b < B; ++b) red[w][ol][b] = acc[b];
    __syncthreads();
    for (int p = t; p < 64 * B; p += 256) {
        int oo = p / B, b = p % B;
        int o2 = blockIdx.x * 64 + oo;
        if (o2 < N) {
            float s = red[0][oo][b] + red[1][oo][b] + red[2][oo][b] + red[3][oo][b];
            atomicAdd(&raw2[(size_t)b * N + o2], s);
        }
    }
}

// ---------------------------------------------------------------------------
// final: inline fc3 (raw2 + b_r2 -> leaky -> dot W3) + groupv sum + assembly.
__global__ __launch_bounds__(256) void final_kernel(
    const float* __restrict__ accums, const float* __restrict__ groupv,
    const float* __restrict__ raw2, const float* __restrict__ b_r2,
    const float* __restrict__ W3, const float* __restrict__ b3,
    const float* __restrict__ label, float* __restrict__ out) {
    int tid = threadIdx.x;
    __shared__ float affnS[8];
    {
        int b = tid >> 5, k0 = tid & 31;
        float acc = 0.f;
        for (int k = k0; k < 300; k += 32) {
            float v = raw2[(size_t)b * 300 + k] + b_r2[k];
            v = (v > 0.f) ? v : 0.1f * v;
            acc = fmaf(v, W3[k], acc);
        }
        #pragma unroll
        for (int off = 16; off; off >>= 1) acc += __shfl_down(acc, off);
        if (k0 == 0) affnS[b] = acc + b3[0];
    }
    float s = 0.f;
    for (int l = tid; l < B * NP; l += 256) s += groupv[l];
    __shared__ float r[256];
    r[tid] = s;
    __syncthreads();
    for (int st = 128; st; st >>= 1) {
        if (tid < st) r[tid] += r[tid + st];
        __syncthreads();
    }
    if (tid == 0) {
        float gtot = r[0];
        float l0 = 0.f, l1 = 0.f, l2 = 0.f;
        for (int b = 0; b < B; ++b) {
            float S = accums[b];
            float A = accums[8 + b], C = accums[16 + b], D = accums[24 + b];
            float fA = accums[32 + b];
            l0 += 1.f + fA / S;
            float bind = A / (S * S) - 2.f * C / S + D;
            l1 += sqrtf(fmaxf(bind, 0.f));
            float dd = affnS[b] - label[b];
            l2 += dd * dd;
        }
        out[0] = (l0 + gtot + l1 + l2) * 0.125f;
    }
}

// ---------------------------------------------------------------------------
extern "C" void kernel_launch(void* const* d_in, const int* in_sizes, int n_in,
                              void* d_out, int out_size, void* d_ws, size_t ws_size,
                              hipStream_t stream) {
    const float* prot_data   = (const float*)d_in[0];
    const float* drug_ver    = (const float*)d_in[1];
    const float* drug_adj    = (const float*)d_in[2];
    const float* contacts    = (const float*)d_in[3];
    const float* prot_inter  = (const float*)d_in[4];
    const float* exist       = (const float*)d_in[5];
    const float* label       = (const float*)d_in[6];
    const float* fused       = (const float*)d_in[7];
    const float* W_prot      = (const float*)d_in[8];
    const float* b_prot      = (const float*)d_in[9];
    const float* gcn_W0      = (const float*)d_in[10];
    const float* gcn_b0      = (const float*)d_in[11];
    const float* gcn_W1      = (const float*)d_in[12];
    const float* gcn_b1      = (const float*)d_in[13];
    const float* gcn_W2      = (const float*)d_in[14];
    const float* gcn_b2      = (const float*)d_in[15];
    const float* gcn_Wf      = (const float*)d_in[16];
    const float* gcn_bf      = (const float*)d_in[17];
    const float* Wjp         = (const float*)d_in[18];
    const float* bjp         = (const float*)d_in[19];
    const float* Wjc         = (const float*)d_in[20];
    const float* bjc         = (const float*)d_in[21];
    const float* conv_w      = (const float*)d_in[22];
    const float* conv_b      = (const float*)d_in[23];
    const float* W_r1        = (const float*)d_in[24];
    const float* b_r1        = (const float*)d_in[25];
    const float* W_r2        = (const float*)d_in[26];
    const float* b_r2        = (const float*)d_in[27];
    const float* W_r3        = (const float*)d_in[28];
    const float* b_r3        = (const float*)d_in[29];

    float* ws = (float*)d_ws;
    size_t off = 0;
    auto alloc = [&](size_t n) { float* p = ws + off; off += n; return p; };
    float* prot     = alloc((size_t)B * NP * DD);
    float* qp       = alloc((size_t)B * NP * DD);
    float* tbuf     = alloc((size_t)B * NK * DD);   // y0; +ybuf = iTb alias
    float* ybuf     = alloc((size_t)B * NK * DD);   // y1
    float* comp     = alloc((size_t)B * NK * DD);
    float* qc       = alloc((size_t)B * NK * DD);
    float* inter    = alloc((size_t)B * NP * NK);
    float* s_bi     = alloc((size_t)B * NP);
    float* groupv   = alloc((size_t)B * NP);
    short* Wb1      = (short*)alloc((DP / 8) * DD * 8 / 2);
    short* Wb2      = (short*)alloc((DD / 8) * DD * 8 / 2);
    short* fMb      = (short*)alloc((size_t)128 * 1024 * 8 / 2);
    // zero region: accums(48) + raw1(4800) + raw2(2400) + cp(2048)
    float* accums   = alloc(48);
    float* raw1     = alloc((size_t)B * 600);
    float* raw2     = alloc((size_t)B * 300);
    float* cp       = alloc((size_t)B * DD);

    // iTb[128][448][8] bf16 aliases tbuf+ybuf (dead after K3)
    short* iTb = (short*)tbuf;
    (void)ybuf;

    // 1. prep (+gcn layer0)
    k1_kernel<<<1125, 256, 0, stream>>>(W_prot, Wb1, Wjp, Wb2, fused, fMb,
                                        accums, drug_ver, drug_adj,
                                        gcn_W0, gcn_b0, tbuf);

    // 2. prot GEMM + gcn layer1
    k2_kernel<<<948, 256, 0, stream>>>(prot_data, Wb1, b_prot, prot,
                                       tbuf, drug_adj, gcn_W1, gcn_b1, ybuf);

    // 3. qp GEMM + gcn tail
    k3_kernel<<<948, 256, 0, stream>>>(prot, Wb2, bjp, qp,
                                       ybuf, drug_adj, gcn_W2, gcn_b2,
                                       gcn_Wf, gcn_bf, Wjc, bjc, comp, qc);

    // 4. inter (raw) + moments + s_bi + iTb
    inter_all_kernel<<<B * 125, 256, 0, stream>>>(
        qp, qc, prot_inter, exist, inter, s_bi, iTb, accums);

    // 5. cp partial + fused MFMA + group
    k5_kernel<<<3112, 256, 0, stream>>>(prot, comp, inter, cp,
                                        iTb, fMb, accums + 32,
                                        contacts, s_bi, accums, groupv);

    // 6. fc1 with inline conv/pool
    fc1_conv_kernel<<<dim3(10, 16), 256, 0, stream>>>(
        cp, accums, conv_w, conv_b, W_r1, raw1);

    // 7. fc2
    fc2_kernel<<<dim3(5, 8), 256, 0, stream>>>(raw1, b_r1, W_r2, raw2);

    // 8. final loss (fc3 inline + group sum + assembly)
    final_kernel<<<1, 256, 0, stream>>>(accums, groupv, raw2, b_r2,
                                        W_r3, b_r3, label, (float*)d_out);
}

// Round 16
// 143.398 us; speedup vs baseline: 2.7034x; 1.1205x over previous
//
#include <hip/hip_runtime.h>
#include <hip/hip_bf16.h>
#include <math.h>

// ---------------------------------------------------------------------------
#define B 8
#define NP 1000
#define NK 56
#define DP 768
#define DV 43
#define DD 256
#define NT 999

typedef __attribute__((ext_vector_type(8))) short bf16x8;
typedef __attribute__((ext_vector_type(4))) float f32x4;

__device__ inline short f2bf(float x) {
    __hip_bfloat16 h = __float2bfloat16(x);
    return __builtin_bit_cast(short, h);
}

// ---------------------------------------------------------------------------
// MFMA GEMM body with A-prefetch: C = act_in(A) @ Wb + bias.
template<bool RELU_IN>
__device__ __forceinline__ void gemm_body(
    const float* __restrict__ A, const short* __restrict__ Wb,
    const float* __restrict__ bias, float* __restrict__ C,
    int N, int K, int bm, int bn, int tid) {
    int lane = tid & 63, w = tid >> 6;
    int m0 = bm * 32 + (w >> 1) * 16;
    int n0 = bn * 128 + (w & 1) * 64;
    int lrow = lane & 15, lk = lane >> 4;
    f32x4 acc[4] = {{0.f,0.f,0.f,0.f},{0.f,0.f,0.f,0.f},
                    {0.f,0.f,0.f,0.f},{0.f,0.f,0.f,0.f}};
    const float* arow = A + (size_t)(m0 + lrow) * K + lk * 8;
    f32x4 a0 = *reinterpret_cast<const f32x4*>(arow);
    f32x4 a1 = *reinterpret_cast<const f32x4*>(arow + 4);
    for (int k0 = 0; k0 < K; k0 += 32) {
        f32x4 c0 = a0, c1 = a1;
        if (k0 + 32 < K) {
            a0 = *reinterpret_cast<const f32x4*>(arow + k0 + 32);
            a1 = *reinterpret_cast<const f32x4*>(arow + k0 + 36);
        }
        bf16x8 af;
        #pragma unroll
        for (int e = 0; e < 4; ++e) {
            float v0 = c0[e], v1 = c1[e];
            if (RELU_IN) { v0 = fmaxf(v0, 0.f); v1 = fmaxf(v1, 0.f); }
            af[e] = f2bf(v0); af[4 + e] = f2bf(v1);
        }
        const short* bbase = Wb + ((size_t)((k0 >> 3) + lk) * N + n0 + lrow) * 8;
        #pragma unroll
        for (int nt = 0; nt < 4; ++nt) {
            bf16x8 bf = *reinterpret_cast<const bf16x8*>(bbase + nt * 128);
            acc[nt] = __builtin_amdgcn_mfma_f32_16x16x32_bf16(af, bf, acc[nt], 0, 0, 0);
        }
    }
    #pragma unroll
    for (int nt = 0; nt < 4; ++nt) {
        int col = n0 + nt * 16 + lrow;
        float bv = bias[col];
        #pragma unroll
        for (int r = 0; r < 4; ++r) {
            int row = m0 + lk * 4 + r;
            C[(size_t)row * N + col] = acc[nt][r] + bv;
        }
    }
}

// GCN layer body: y[b,i,:] = relu((adj@x)[b,i,:] @ W + rowsum(adj)_i * bias)
__device__ __forceinline__ void gcn_layer_body(
    const float* __restrict__ x, const float* __restrict__ adj,
    const float* __restrict__ W, const float* __restrict__ bias,
    float* __restrict__ y, int KIN, int bi, int tid,
    float* arow, float* u) {
    int b = bi / NK, i = bi % NK;
    if (tid < NK) arow[tid] = adj[((size_t)b * NK + i) * NK + tid];
    __syncthreads();
    if (tid < KIN) {
        float a0 = 0.f, a1 = 0.f;
        for (int j = 0; j < NK; j += 2) {
            a0 = fmaf(arow[j],     x[((size_t)b * NK + j)     * KIN + tid], a0);
            a1 = fmaf(arow[j + 1], x[((size_t)b * NK + j + 1) * KIN + tid], a1);
        }
        u[tid] = a0 + a1;
    }
    float rs = 0.f;
    for (int j = 0; j < NK; ++j) rs += arow[j];
    __syncthreads();
    float a0 = 0.f, a1 = 0.f, a2 = 0.f, a3 = 0.f;
    int kk = 0;
    for (; kk + 4 <= KIN; kk += 4) {
        a0 = fmaf(u[kk],     W[(size_t)kk * DD + tid],       a0);
        a1 = fmaf(u[kk + 1], W[(size_t)(kk + 1) * DD + tid], a1);
        a2 = fmaf(u[kk + 2], W[(size_t)(kk + 2) * DD + tid], a2);
        a3 = fmaf(u[kk + 3], W[(size_t)(kk + 3) * DD + tid], a3);
    }
    for (; kk < KIN; ++kk) a0 = fmaf(u[kk], W[(size_t)kk * DD + tid], a0);
    float v = a0 + a1 + a2 + a3 + rs * bias[tid];
    y[((size_t)b * NK + i) * DD + tid] = fmaxf(v, 0.f);
}

// GCN tail body: layer2 -> comp -> qc (qc emitted bf16 in Wb-swizzled layout)
__device__ __forceinline__ void gcn_tail_body(
    const float* __restrict__ y1, const float* __restrict__ adj,
    const float* __restrict__ W2, const float* __restrict__ b2,
    const float* __restrict__ Wf, const float* __restrict__ bf,
    const float* __restrict__ Wjc, const float* __restrict__ bjc,
    float* __restrict__ comp, short* __restrict__ qcb,
    int bi, int tid, float* arow, float* u) {
    int b = bi / NK, i = bi % NK;
    if (tid < NK) arow[tid] = adj[((size_t)b * NK + i) * NK + tid];
    __syncthreads();
    {
        float a0 = 0.f, a1 = 0.f;
        for (int j = 0; j < NK; j += 2) {
            a0 = fmaf(arow[j],     y1[((size_t)b * NK + j)     * DD + tid], a0);
            a1 = fmaf(arow[j + 1], y1[((size_t)b * NK + j + 1) * DD + tid], a1);
        }
        u[tid] = a0 + a1;
    }
    float rs = 0.f;
    for (int j = 0; j < NK; ++j) rs += arow[j];
    __syncthreads();
    float a0 = 0.f, a1 = 0.f, a2 = 0.f, a3 = 0.f;
    #pragma unroll 4
    for (int kk = 0; kk < DD; kk += 4) {
        a0 = fmaf(u[kk],     W2[(size_t)kk * DD + tid],       a0);
        a1 = fmaf(u[kk + 1], W2[(size_t)(kk + 1) * DD + tid], a1);
        a2 = fmaf(u[kk + 2], W2[(size_t)(kk + 2) * DD + tid], a2);
        a3 = fmaf(u[kk + 3], W2[(size_t)(kk + 3) * DD + tid], a3);
    }
    float y2 = fmaxf(a0 + a1 + a2 + a3 + rs * b2[tid], 0.f);
    __syncthreads();
    u[tid] = y2;
    __syncthreads();
    a0 = a1 = a2 = a3 = 0.f;
    #pragma unroll 4
    for (int kk = 0; kk < DD; kk += 4) {
        a0 = fmaf(u[kk],     Wf[(size_t)kk * DD + tid],       a0);
        a1 = fmaf(u[kk + 1], Wf[(size_t)(kk + 1) * DD + tid], a1);
        a2 = fmaf(u[kk + 2], Wf[(size_t)(kk + 2) * DD + tid], a2);
        a3 = fmaf(u[kk + 3], Wf[(size_t)(kk + 3) * DD + tid], a3);
    }
    float cv = a0 + a1 + a2 + a3 + bf[tid];
    comp[((size_t)b * NK + i) * DD + tid] = cv;
    __syncthreads();
    u[tid] = fmaxf(cv, 0.f);
    __syncthreads();
    a0 = a1 = a2 = a3 = 0.f;
    #pragma unroll 4
    for (int kk = 0; kk < DD; kk += 4) {
        a0 = fmaf(u[kk],     Wjc[(size_t)kk * DD + tid],       a0);
        a1 = fmaf(u[kk + 1], Wjc[(size_t)(kk + 1) * DD + tid], a1);
        a2 = fmaf(u[kk + 2], Wjc[(size_t)(kk + 2) * DD + tid], a2);
        a3 = fmaf(u[kk + 3], Wjc[(size_t)(kk + 3) * DD + tid], a3);
    }
    float qv = a0 + a1 + a2 + a3 + bjc[tid];
    // qcb[(b*32 + d/8)*64 + i]*8 + d%8   (n=i, koct=d/8, e=d%8)
    qcb[(((size_t)b * 32 + (tid >> 3)) * 64 + i) * 8 + (tid & 7)] = f2bf(qv);
}

// ---------------------------------------------------------------------------
// K1: prep (wcvt x2, fusedcvt, zero regions incl. qcb) + gcn_layer0. Grid 1381.
__global__ __launch_bounds__(256) void k1_kernel(
    const float* __restrict__ W_prot, short* __restrict__ Wb1,
    const float* __restrict__ Wjp, short* __restrict__ Wb2,
    const float* __restrict__ fusedM, short* __restrict__ fMb,
    float* __restrict__ zero_region, float* __restrict__ qcb_zero,
    const float* __restrict__ drug_ver, const float* __restrict__ adj,
    const float* __restrict__ W0, const float* __restrict__ b0,
    float* __restrict__ y0) {
    __shared__ float smem[2112];
    int blk = blockIdx.x, tid = threadIdx.x;
    if (blk < 96) {
        int idx = blk * 256 + tid;
        int koct = idx / DD, n = idx % DD;
        bf16x8 v;
        #pragma unroll
        for (int e = 0; e < 8; ++e)
            v[e] = f2bf(W_prot[(size_t)(koct * 8 + e) * DD + n]);
        *reinterpret_cast<bf16x8*>(Wb1 + (size_t)idx * 8) = v;
    } else if (blk < 128) {
        int idx = (blk - 96) * 256 + tid;
        int koct = idx / DD, n = idx % DD;
        bf16x8 v;
        #pragma unroll
        for (int e = 0; e < 8; ++e)
            v[e] = f2bf(Wjp[(size_t)(koct * 8 + e) * DD + n]);
        *reinterpret_cast<bf16x8*>(Wb2 + (size_t)idx * 8) = v;
    } else if (blk < 640) {
        int blk2 = blk - 128;
        int t0 = (blk2 >> 3) * 16;
        int i0 = (blk2 & 7) * 128;
        for (int l = tid; l < 16 * 128; l += 256) {
            int tt = l >> 7, ii = l & 127;
            int t = t0 + tt, i = i0 + ii;
            smem[tt * 132 + ii] = (t < NT && i < NP) ? fusedM[(size_t)t * NP + i] : 0.f;
        }
        __syncthreads();
        int octl = tid >> 4, tl = tid & 15;
        bf16x8 v;
        #pragma unroll
        for (int e = 0; e < 8; ++e)
            v[e] = f2bf(smem[tl * 132 + octl * 8 + e]);
        size_t oct = i0 / 8 + octl;
        *reinterpret_cast<bf16x8*>(fMb + (oct * 1024 + t0 + tl) * 8) = v;
    } else if (blk < 677) {
        int idx = (blk - 640) * 256 + tid;
        if (idx < 48 + B * 600 + B * 300 + B * DD) zero_region[idx] = 0.f;
    } else if (blk < 933) {
        int idx = (blk - 677) * 256 + tid;   // 65536 f32 = qcb full clear
        qcb_zero[idx] = 0.f;
    } else {
        gcn_layer_body(drug_ver, adj, W0, b0, y0, DV, blk - 933, tid,
                       smem, smem + 64);
    }
}

// ---------------------------------------------------------------------------
// K2: prot GEMM (500) + gcn_layer1 (448).  Grid 948.
__global__ __launch_bounds__(256) void k2_kernel(
    const float* __restrict__ prot_data, const short* __restrict__ Wb1,
    const float* __restrict__ b_prot, float* __restrict__ prot,
    const float* __restrict__ y0, const float* __restrict__ adj,
    const float* __restrict__ W1, const float* __restrict__ b1,
    float* __restrict__ y1) {
    __shared__ float smem[320];
    int blk = blockIdx.x, tid = threadIdx.x;
    if (blk < 500)
        gemm_body<false>(prot_data, Wb1, b_prot, prot, DD, DP, blk >> 1, blk & 1, tid);
    else
        gcn_layer_body(y0, adj, W1, b1, y1, DD, blk - 500, tid, smem, smem + 64);
}

// K3: qp GEMM (500) + gcn_tail (448).  Grid 948.
__global__ __launch_bounds__(256) void k3_kernel(
    const float* __restrict__ prot, const short* __restrict__ Wb2,
    const float* __restrict__ bjp, float* __restrict__ qp,
    const float* __restrict__ y1, const float* __restrict__ adj,
    const float* __restrict__ W2, const float* __restrict__ b2,
    const float* __restrict__ Wf, const float* __restrict__ bf,
    const float* __restrict__ Wjc, const float* __restrict__ bjc,
    float* __restrict__ comp, short* __restrict__ qcb) {
    __shared__ float smem[320];
    int blk = blockIdx.x, tid = threadIdx.x;
    if (blk < 500)
        gemm_body<true>(prot, Wb2, bjp, qp, DD, DD, blk >> 1, blk & 1, tid);
    else
        gcn_tail_body(y1, adj, W2, b2, Wf, bf, Wjc, bjc, comp, qcb,
                      blk - 500, tid, smem, smem + 64);
}

// ---------------------------------------------------------------------------
// inter via MFMA: logits = qp[b] @ qc[b]^T (1000x56, K=256), sigmoid epilogue,
// writes inter f32, iTb bf16 (incl zero pads), s_bi, moments. Grid 128 (8b x 16).
__global__ __launch_bounds__(256) void inter_mfma_kernel(
    const float* __restrict__ qp, const short* __restrict__ qcb,
    const float* __restrict__ prot_inter, const float* __restrict__ exist,
    float* __restrict__ inter, float* __restrict__ s_bi,
    short* __restrict__ iTb, float* __restrict__ accums) {
    __shared__ float wred[4][4];
    int blk = blockIdx.x;
    int b = blk >> 4, mt = blk & 15;      // 16 m-tiles of 64 rows
    int tid = threadIdx.x;
    int lane = tid & 63, w = tid >> 6;
    int m0 = mt * 64 + w * 16;            // wave owns 16 rows x 64 cols
    int lrow = lane & 15, lk = lane >> 4;
    f32x4 acc[4] = {{0.f,0.f,0.f,0.f},{0.f,0.f,0.f,0.f},
                    {0.f,0.f,0.f,0.f},{0.f,0.f,0.f,0.f}};
    int rowi = m0 + lrow;
    int rowc = (rowi < NP) ? rowi : (NP - 1);
    const float* arow = qp + ((size_t)b * NP + rowc) * DD + lk * 8;
    f32x4 a0 = *reinterpret_cast<const f32x4*>(arow);
    f32x4 a1 = *reinterpret_cast<const f32x4*>(arow + 4);
    for (int k0 = 0; k0 < DD; k0 += 32) {
        f32x4 c0 = a0, c1 = a1;
        if (k0 + 32 < DD) {
            a0 = *reinterpret_cast<const f32x4*>(arow + k0 + 32);
            a1 = *reinterpret_cast<const f32x4*>(arow + k0 + 36);
        }
        bf16x8 af;
        #pragma unroll
        for (int e = 0; e < 4; ++e) {
            af[e] = f2bf(c0[e]); af[4 + e] = f2bf(c1[e]);
        }
        const short* bb = qcb + (((size_t)b * 32 + (k0 >> 3) + lk) * 64 + lrow) * 8;
        #pragma unroll
        for (int nt = 0; nt < 4; ++nt) {
            bf16x8 bf = *reinterpret_cast<const bf16x8*>(bb + nt * 128);
            acc[nt] = __builtin_amdgcn_mfma_f32_16x16x32_bf16(af, bf, acc[nt], 0, 0, 0);
        }
    }
    float ex = exist[b];
    float aV = 0.f, aA = 0.f, aC = 0.f, aD = 0.f;
    float rowsq[4] = {0.f, 0.f, 0.f, 0.f};
    #pragma unroll
    for (int nt = 0; nt < 4; ++nt) {
        int j = nt * 16 + lrow;
        bool jv = (j < NK);
        #pragma unroll
        for (int r = 0; r < 4; ++r) {
            int i = m0 + lk * 4 + r;
            bool iv = (i < NP);
            float v = 0.f, lab = 0.f;
            if (jv) {
                if (iv) {
                    v = 1.f / (1.f + __expf(-acc[nt][r]));
                    lab = ex * prot_inter[((size_t)b * NP + i) * NK + j];
                    inter[((size_t)b * NP + i) * NK + j] = v;
                }
                // iTb[(i/8)*448 + b*56 + j][i%8] (zero for pad rows)
                iTb[(((size_t)(i >> 3) * 448 + b * NK + j) << 3) + (i & 7)] = f2bf(v);
            }
            aV += v; aA += v * v; aC += v * lab; aD += lab * lab;
            rowsq[r] += v * v;
        }
    }
    // s_bi: reduce v^2 across the 16-lane lrow group
    #pragma unroll
    for (int r = 0; r < 4; ++r) {
        float rs = rowsq[r];
        rs += __shfl_xor(rs, 1); rs += __shfl_xor(rs, 2);
        rs += __shfl_xor(rs, 4); rs += __shfl_xor(rs, 8);
        int i = m0 + lk * 4 + r;
        if (lrow == 0 && i < NP) s_bi[(size_t)b * NP + i] = rs;
    }
    #pragma unroll
    for (int off = 32; off; off >>= 1) {
        aV += __shfl_down(aV, off);
        aA += __shfl_down(aA, off);
        aC += __shfl_down(aC, off);
        aD += __shfl_down(aD, off);
    }
    if (lane == 0) {
        wred[w][0] = aV; wred[w][1] = aA; wred[w][2] = aC; wred[w][3] = aD;
    }
    __syncthreads();
    if (tid < 4) {
        float s = wred[0][tid] + wred[1][tid] + wred[2][tid] + wred[3][tid];
        atomicAdd(&accums[tid * 8 + b], s);
    }
}

// ---------------------------------------------------------------------------
// K5: cp_partial (1000) + fused MFMA (112) + group (2000).  Grid 3112.
__global__ __launch_bounds__(256) void k5_kernel(
    const float* __restrict__ prot, const float* __restrict__ comp,
    const float* __restrict__ inter, float* __restrict__ cp,
    const short* __restrict__ iTb, const short* __restrict__ fMb,
    float* __restrict__ fusedAbs,
    const float* __restrict__ contacts, const float* __restrict__ s_bi,
    const float* __restrict__ accums, float* __restrict__ groupv) {
    __shared__ float irow[8][NK];
    __shared__ float sb[8];
    int blk = blockIdx.x, tid = threadIdx.x;
    if (blk < 1000) {
        int b = blk / 125, chunk = blk % 125;
        int d = tid;
        float creg[NK];
        #pragma unroll
        for (int k = 0; k < NK; ++k)
            creg[k] = comp[((size_t)b * NK + k) * DD + d];
        for (int l = tid; l < 8 * NK; l += 256) {
            int ii = l / NK, k = l % NK;
            irow[ii][k] = inter[((size_t)b * NP + chunk * 8 + ii) * NK + k];
        }
        const float C2LOG2E = 2.8853900817779268f;
        float p2l[8];
        #pragma unroll
        for (int ii = 0; ii < 8; ++ii)
            p2l[ii] = C2LOG2E * prot[((size_t)b * NP + chunk * 8 + ii) * DD + d];
        __syncthreads();
        float acc0 = 0.f, acc1 = 0.f;
        #pragma unroll 1
        for (int ii = 0; ii < 8; ++ii) {
            float p = p2l[ii];
            #pragma unroll
            for (int k = 0; k < NK; k += 2) {
                float e0 = __builtin_amdgcn_exp2f(p * creg[k]);
                float e1 = __builtin_amdgcn_exp2f(p * creg[k + 1]);
                float r0 = __builtin_amdgcn_rcpf(e0 + 1.f);
                float r1 = __builtin_amdgcn_rcpf(e1 + 1.f);
                acc0 = fmaf(fmaf(-2.f, r0, 1.f), irow[ii][k],     acc0);
                acc1 = fmaf(fmaf(-2.f, r1, 1.f), irow[ii][k + 1], acc1);
            }
        }
        atomicAdd(&cp[(size_t)b * DD + d], acc0 + acc1);
    } else if (blk < 1112) {
        int fblk = blk - 1000;
        int mb = fblk % 14, nb = fblk / 14;
        int lane = tid & 63, w = tid >> 6;
        if (tid < 8) sb[tid] = 0.f;
        __syncthreads();
        int m0 = mb * 32 + (w >> 1) * 16;
        int n0 = nb * 128 + (w & 1) * 64;
        int lrow = lane & 15, lk = lane >> 4;
        f32x4 acc[4] = {{0.f,0.f,0.f,0.f},{0.f,0.f,0.f,0.f},
                        {0.f,0.f,0.f,0.f},{0.f,0.f,0.f,0.f}};
        for (int koct0 = 0; koct0 < 128; koct0 += 4) {
            int koct = koct0 + lk;
            bf16x8 af = *reinterpret_cast<const bf16x8*>(
                iTb + ((size_t)koct * 448 + m0 + lrow) * 8);
            const short* bb = fMb + ((size_t)koct * 1024 + n0 + lrow) * 8;
            #pragma unroll
            for (int nt = 0; nt < 4; ++nt) {
                bf16x8 bf = *reinterpret_cast<const bf16x8*>(bb + nt * 128);
                acc[nt] = __builtin_amdgcn_mfma_f32_16x16x32_bf16(af, bf, acc[nt], 0, 0, 0);
            }
        }
        #pragma unroll
        for (int r = 0; r < 4; ++r) {
            float part = fabsf(acc[0][r]) + fabsf(acc[1][r]) +
                         fabsf(acc[2][r]) + fabsf(acc[3][r]);
            #pragma unroll
            for (int off = 1; off < 16; off <<= 1)
                part += __shfl_xor(part, off);
            if (lrow == 0) {
                int row = m0 + lk * 4 + r;
                atomicAdd(&sb[row / NK], part);
            }
        }
        __syncthreads();
        if (tid < 8 && sb[tid] != 0.f) atomicAdd(&fusedAbs[tid], sb[tid]);
    } else {
        int w = tid >> 6, lane = tid & 63;
        int gk = (blk - 1112) * 4 + w;
        int b = gk / NP;
        const f32x4* row4 = reinterpret_cast<const f32x4*>(
            contacts + (size_t)gk * NP);
        const f32x4* sv4 = reinterpret_cast<const f32x4*>(s_bi + (size_t)b * NP);
        f32x4 z = {0.f, 0.f, 0.f, 0.f};
        f32x4 c0 = row4[lane];
        f32x4 c1 = row4[lane + 64];
        f32x4 c2 = row4[lane + 128];
        f32x4 c3 = z, s3 = z;
        f32x4 s0 = sv4[lane];
        f32x4 s1 = sv4[lane + 64];
        f32x4 s2 = sv4[lane + 128];
        if (lane + 192 < 250) { c3 = row4[lane + 192]; s3 = sv4[lane + 192]; }
        float g0 = 0.f, g1 = 0.f, g2 = 0.f, g3 = 0.f;
        #pragma unroll
        for (int e = 0; e < 4; ++e) {
            g0 = fmaf(c0[e], s0[e], g0);
            g1 = fmaf(c1[e], s1[e], g1);
            g2 = fmaf(c2[e], s2[e], g2);
            g3 = fmaf(c3[e], s3[e], g3);
        }
        float r0 = (c0[0] + c0[1]) + (c0[2] + c0[3]);
        float r1 = (c1[0] + c1[1]) + (c1[2] + c1[3]);
        float r2 = (c2[0] + c2[1]) + (c2[2] + c2[3]);
        float r3 = (c3[0] + c3[1]) + (c3[2] + c3[3]);
        float g = (g0 + g1) + (g2 + g3);
        float rs = (r0 + r1) + (r2 + r3);
        #pragma unroll
        for (int off = 32; off; off >>= 1) {
            g += __shfl_down(g, off);
            rs += __shfl_down(rs, off);
        }
        if (lane == 0) {
            float val;
            if (g == 0.f) val = sqrtf(1e10f) * sqrtf(rs);
            else          val = sqrtf(g) / accums[b] * sqrtf(rs);
            groupv[gk] = val;
        }
    }
}

// ---------------------------------------------------------------------------
// fc1 with inline conv/pool.
__global__ __launch_bounds__(256) void fc1_conv_kernel(
    const float* __restrict__ cp, const float* __restrict__ accums,
    const float* __restrict__ conv_w, const float* __restrict__ conv_b,
    const float* __restrict__ W, float* __restrict__ raw) {
    const int N = 600, kchunk = 128;
    int t = threadIdx.x;
    int ol = t & 63;
    int o = blockIdx.x * 64 + ol;
    int w = t >> 6;
    int kbeg = blockIdx.y * kchunk;
    __shared__ float xS[B][258];
    __shared__ float sin_[B][128];
    for (int l = t; l < B * DD; l += 256) {
        int b = l >> 8, d = l & 255;
        xS[b][d + 1] = cp[(size_t)b * DD + d] / accums[b];
    }
    if (t < B) { xS[t][0] = 0.f; xS[t][257] = 0.f; }
    __syncthreads();
    for (int l = t; l < B * kchunk; l += 256) {
        int b = l >> 7, kl = l & 127;
        int kg = kbeg + kl;
        int oo = kg >> 5, p = kg & 31;
        float w0 = conv_w[oo * 4 + 0], w1 = conv_w[oo * 4 + 1];
        float w2 = conv_w[oo * 4 + 2], w3 = conv_w[oo * 4 + 3];
        float cb = conv_b[oo];
        float m = -INFINITY;
        #pragma unroll
        for (int q = 0; q < 4; ++q) {
            int base = (p * 4 + q) * 2;
            float acc = cb;
            acc = fmaf(xS[b][base + 0], w0, acc);
            acc = fmaf(xS[b][base + 1], w1, acc);
            acc = fmaf(xS[b][base + 2], w2, acc);
            acc = fmaf(xS[b][base + 3], w3, acc);
            acc = (acc > 0.f) ? acc : 0.1f * acc;
            m = fmaxf(m, acc);
        }
        sin_[b][kl] = m;
    }
    __syncthreads();
    float acc[B];
    #pragma unroll
    for (int b = 0; b < B; ++b) acc[b] = 0.f;
    for (int k = kbeg + w; k < kbeg + kchunk; k += 4) {
        float wv = W[(size_t)k * N + o];
        int kl = k - kbeg;
        #pragma unroll
        for (int b = 0; b < B; ++b)
            acc[b] = fmaf(sin_[b][kl], wv, acc[b]);
    }
    __shared__ float red[4][64][B];
    #pragma unroll
    for (int b = 0; b < B; ++b) red[w][ol][b] = acc[b];
    __syncthreads();
    for (int p = t; p < 64 * B; p += 256) {
        int oo = p / B, b = p % B;
        int o2 = blockIdx.x * 64 + oo;
        float s = red[0][oo][b] + red[1][oo][b] + red[2][oo][b] + red[3][oo][b];
        atomicAdd(&raw[(size_t)b * N + o2], s);
    }
}

// ---------------------------------------------------------------------------
// fc2 partial: staging applies bias+leaky to raw1.
__global__ __launch_bounds__(256) void fc2_kernel(
    const float* __restrict__ raw1, const float* __restrict__ b_r1,
    const float* __restrict__ W, float* __restrict__ raw2) {
    const int K = 600, N = 300, kchunk = 75;
    int t = threadIdx.x;
    int ol = t & 63;
    int o = blockIdx.x * 64 + ol;
    int w = t >> 6;
    int kbeg = blockIdx.y * kchunk;
    __shared__ float sin_[B][128];
    for (int l = t; l < B * kchunk; l += 256) {
        int b = l / kchunk, k = l % kchunk;
        float v = raw1[(size_t)b * K + kbeg + k] + b_r1[kbeg + k];
        v = (v > 0.f) ? v : 0.1f * v;
        sin_[b][k] = v;
    }
    __syncthreads();
    float acc[B];
    #pragma unroll
    for (int b = 0; b < B; ++b) acc[b] = 0.f;
    if (o < N) {
        for (int k = kbeg + w; k < kbeg + kchunk; k += 4) {
            float wv = W[(size_t)k * N + o];
            int kl = k - kbeg;
            #pragma unroll
            for (int b = 0; b < B; ++b)
                acc[b] = fmaf(sin_[b][kl], wv, acc[b]);
        }
    }
    __shared__ float red[4][64][B];
    #pragma unroll
    for (int b = 0; b < B; ++b) red[w][ol][b] = acc[b];
    __syncthreads();
    for (int p = t; p < 64 * B; p += 256) {
        int oo = p / B, b = p % B;
        int o2 = blockIdx.x * 64 + oo;
        if (o2 < N) {
            float s = red[0][oo][b] + red[1][oo][b] + red[2][oo][b] + red[3][oo][b];
            atomicAdd(&raw2[(size_t)b * N + o2], s);
        }
    }
}

// ---------------------------------------------------------------------------
// final: inline fc3 + groupv sum + assembly.
__global__ __launch_bounds__(256) void final_kernel(
    const float* __restrict__ accums, const float* __restrict__ groupv,
    const float* __restrict__ raw2, const float* __restrict__ b_r2,
    const float* __restrict__ W3, const float* __restrict__ b3,
    const float* __restrict__ label, float* __restrict__ out) {
    int tid = threadIdx.x;
    __shared__ float affnS[8];
    {
        int b = tid >> 5, k0 = tid & 31;
        float acc = 0.f;
        for (int k = k0; k < 300; k += 32) {
            float v = raw2[(size_t)b * 300 + k] + b_r2[k];
            v = (v > 0.f) ? v : 0.1f * v;
            acc = fmaf(v, W3[k], acc);
        }
        #pragma unroll
        for (int off = 16; off; off >>= 1) acc += __shfl_down(acc, off);
        if (k0 == 0) affnS[b] = acc + b3[0];
    }
    float s = 0.f;
    for (int l = tid; l < B * NP; l += 256) s += groupv[l];
    __shared__ float r[256];
    r[tid] = s;
    __syncthreads();
    for (int st = 128; st; st >>= 1) {
        if (tid < st) r[tid] += r[tid + st];
        __syncthreads();
    }
    if (tid == 0) {
        float gtot = r[0];
        float l0 = 0.f, l1 = 0.f, l2 = 0.f;
        for (int b = 0; b < B; ++b) {
            float S = accums[b];
            float A = accums[8 + b], C = accums[16 + b], D = accums[24 + b];
            float fA = accums[32 + b];
            l0 += 1.f + fA / S;
            float bind = A / (S * S) - 2.f * C / S + D;
            l1 += sqrtf(fmaxf(bind, 0.f));
            float dd = affnS[b] - label[b];
            l2 += dd * dd;
        }
        out[0] = (l0 + gtot + l1 + l2) * 0.125f;
    }
}

// ---------------------------------------------------------------------------
extern "C" void kernel_launch(void* const* d_in, const int* in_sizes, int n_in,
                              void* d_out, int out_size, void* d_ws, size_t ws_size,
                              hipStream_t stream) {
    const float* prot_data   = (const float*)d_in[0];
    const float* drug_ver    = (const float*)d_in[1];
    const float* drug_adj    = (const float*)d_in[2];
    const float* contacts    = (const float*)d_in[3];
    const float* prot_inter  = (const float*)d_in[4];
    const float* exist       = (const float*)d_in[5];
    const float* label       = (const float*)d_in[6];
    const float* fused       = (const float*)d_in[7];
    const float* W_prot      = (const float*)d_in[8];
    const float* b_prot      = (const float*)d_in[9];
    const float* gcn_W0      = (const float*)d_in[10];
    const float* gcn_b0      = (const float*)d_in[11];
    const float* gcn_W1      = (const float*)d_in[12];
    const float* gcn_b1      = (const float*)d_in[13];
    const float* gcn_W2      = (const float*)d_in[14];
    const float* gcn_b2      = (const float*)d_in[15];
    const float* gcn_Wf      = (const float*)d_in[16];
    const float* gcn_bf      = (const float*)d_in[17];
    const float* Wjp         = (const float*)d_in[18];
    const float* bjp         = (const float*)d_in[19];
    const float* Wjc         = (const float*)d_in[20];
    const float* bjc         = (const float*)d_in[21];
    const float* conv_w      = (const float*)d_in[22];
    const float* conv_b      = (const float*)d_in[23];
    const float* W_r1        = (const float*)d_in[24];
    const float* b_r1        = (const float*)d_in[25];
    const float* W_r2        = (const float*)d_in[26];
    const float* b_r2        = (const float*)d_in[27];
    const float* W_r3        = (const float*)d_in[28];
    const float* b_r3        = (const float*)d_in[29];

    float* ws = (float*)d_ws;
    size_t off = 0;
    auto alloc = [&](size_t n) { float* p = ws + off; off += n; return p; };
    float* prot     = alloc((size_t)B * NP * DD);
    float* qp       = alloc((size_t)B * NP * DD);
    float* tbuf     = alloc((size_t)B * NK * DD);   // y0; +ybuf = iTb alias
    float* ybuf     = alloc((size_t)B * NK * DD);   // y1
    float* comp     = alloc((size_t)B * NK * DD);
    float* qcbF     = alloc((size_t)65536);         // qcb bf16 [8][32][64][8]
    float* inter    = alloc((size_t)B * NP * NK);
    float* s_bi     = alloc((size_t)B * NP);
    float* groupv   = alloc((size_t)B * NP);
    short* Wb1      = (short*)alloc((DP / 8) * DD * 8 / 2);
    short* Wb2      = (short*)alloc((DD / 8) * DD * 8 / 2);
    short* fMb      = (short*)alloc((size_t)128 * 1024 * 8 / 2);
    // zero region: accums(48) + raw1(4800) + raw2(2400) + cp(2048)
    float* accums   = alloc(48);
    float* raw1     = alloc((size_t)B * 600);
    float* raw2     = alloc((size_t)B * 300);
    float* cp       = alloc((size_t)B * DD);

    short* qcb = (short*)qcbF;
    // iTb[128][448][8] bf16 aliases tbuf+ybuf (dead after K3)
    short* iTb = (short*)tbuf;
    (void)ybuf;

    // 1. prep (+gcn layer0)
    k1_kernel<<<1381, 256, 0, stream>>>(W_prot, Wb1, Wjp, Wb2, fused, fMb,
                                        accums, qcbF, drug_ver, drug_adj,
                                        gcn_W0, gcn_b0, tbuf);

    // 2. prot GEMM + gcn layer1
    k2_kernel<<<948, 256, 0, stream>>>(prot_data, Wb1, b_prot, prot,
                                       tbuf, drug_adj, gcn_W1, gcn_b1, ybuf);

    // 3. qp GEMM + gcn tail (emits qcb bf16)
    k3_kernel<<<948, 256, 0, stream>>>(prot, Wb2, bjp, qp,
                                       ybuf, drug_adj, gcn_W2, gcn_b2,
                                       gcn_Wf, gcn_bf, Wjc, bjc, comp, qcb);

    // 4. inter via MFMA (+ moments, s_bi, iTb)
    inter_mfma_kernel<<<128, 256, 0, stream>>>(
        qp, qcb, prot_inter, exist, inter, s_bi, iTb, accums);

    // 5. cp partial + fused MFMA + group
    k5_kernel<<<3112, 256, 0, stream>>>(prot, comp, inter, cp,
                                        iTb, fMb, accums + 32,
                                        contacts, s_bi, accums, groupv);

    // 6. fc1 with inline conv/pool
    fc1_conv_kernel<<<dim3(10, 16), 256, 0, stream>>>(
        cp, accums, conv_w, conv_b, W_r1, raw1);

    // 7. fc2
    fc2_kernel<<<dim3(5, 8), 256, 0, stream>>>(raw1, b_r1, W_r2, raw2);

    // 8. final loss
    final_kernel<<<1, 256, 0, stream>>>(accums, groupv, raw2, b_r2,
                                        W_r3, b_r3, label, (float*)d_out);
}

// Round 17
// 137.692 us; speedup vs baseline: 2.8155x; 1.0414x over previous
//
#include <hip/hip_runtime.h>
#include <hip/hip_bf16.h>
#include <math.h>

// ---------------------------------------------------------------------------
#define B 8
#define NP 1000
#define NK 56
#define DP 768
#define DV 43
#define DD 256
#define NT 999

typedef __attribute__((ext_vector_type(8))) short bf16x8;
typedef __attribute__((ext_vector_type(4))) float f32x4;

__device__ inline short f2bf(float x) {
    __hip_bfloat16 h = __float2bfloat16(x);
    return __builtin_bit_cast(short, h);
}

// ---------------------------------------------------------------------------
// MFMA GEMM body, full-width N=256 tile (A read exactly once), A-prefetch.
// Block tile 32(M) x 256(N); wave: 16 x 128 (8 n-subtiles). grid = M/32.
template<bool RELU_IN>
__device__ __forceinline__ void gemm_body256(
    const float* __restrict__ A, const short* __restrict__ Wb,
    const float* __restrict__ bias, float* __restrict__ C,
    int K, int bm, int tid) {
    const int N = DD;
    int lane = tid & 63, w = tid >> 6;
    int m0 = bm * 32 + (w >> 1) * 16;
    int n0 = (w & 1) * 128;
    int lrow = lane & 15, lk = lane >> 4;
    f32x4 acc[8];
    #pragma unroll
    for (int nt = 0; nt < 8; ++nt) acc[nt] = {0.f, 0.f, 0.f, 0.f};
    const float* arow = A + (size_t)(m0 + lrow) * K + lk * 8;
    f32x4 a0 = *reinterpret_cast<const f32x4*>(arow);
    f32x4 a1 = *reinterpret_cast<const f32x4*>(arow + 4);
    for (int k0 = 0; k0 < K; k0 += 32) {
        f32x4 c0 = a0, c1 = a1;
        if (k0 + 32 < K) {
            a0 = *reinterpret_cast<const f32x4*>(arow + k0 + 32);
            a1 = *reinterpret_cast<const f32x4*>(arow + k0 + 36);
        }
        bf16x8 af;
        #pragma unroll
        for (int e = 0; e < 4; ++e) {
            float v0 = c0[e], v1 = c1[e];
            if (RELU_IN) { v0 = fmaxf(v0, 0.f); v1 = fmaxf(v1, 0.f); }
            af[e] = f2bf(v0); af[4 + e] = f2bf(v1);
        }
        const short* bbase = Wb + ((size_t)((k0 >> 3) + lk) * N + n0 + lrow) * 8;
        #pragma unroll
        for (int nt = 0; nt < 8; ++nt) {
            bf16x8 bf = *reinterpret_cast<const bf16x8*>(bbase + nt * 128);
            acc[nt] = __builtin_amdgcn_mfma_f32_16x16x32_bf16(af, bf, acc[nt], 0, 0, 0);
        }
    }
    #pragma unroll
    for (int nt = 0; nt < 8; ++nt) {
        int col = n0 + nt * 16 + lrow;
        float bv = bias[col];
        #pragma unroll
        for (int r = 0; r < 4; ++r) {
            int row = m0 + lk * 4 + r;
            C[(size_t)row * N + col] = acc[nt][r] + bv;
        }
    }
}

// GCN layer body: y[b,i,:] = relu((adj@x)[b,i,:] @ W + rowsum(adj)_i * bias)
__device__ __forceinline__ void gcn_layer_body(
    const float* __restrict__ x, const float* __restrict__ adj,
    const float* __restrict__ W, const float* __restrict__ bias,
    float* __restrict__ y, int KIN, int bi, int tid,
    float* arow, float* u) {
    int b = bi / NK, i = bi % NK;
    if (tid < NK) arow[tid] = adj[((size_t)b * NK + i) * NK + tid];
    __syncthreads();
    if (tid < KIN) {
        float a0 = 0.f, a1 = 0.f;
        for (int j = 0; j < NK; j += 2) {
            a0 = fmaf(arow[j],     x[((size_t)b * NK + j)     * KIN + tid], a0);
            a1 = fmaf(arow[j + 1], x[((size_t)b * NK + j + 1) * KIN + tid], a1);
        }
        u[tid] = a0 + a1;
    }
    float rs = 0.f;
    for (int j = 0; j < NK; ++j) rs += arow[j];
    __syncthreads();
    float a0 = 0.f, a1 = 0.f, a2 = 0.f, a3 = 0.f;
    int kk = 0;
    for (; kk + 4 <= KIN; kk += 4) {
        a0 = fmaf(u[kk],     W[(size_t)kk * DD + tid],       a0);
        a1 = fmaf(u[kk + 1], W[(size_t)(kk + 1) * DD + tid], a1);
        a2 = fmaf(u[kk + 2], W[(size_t)(kk + 2) * DD + tid], a2);
        a3 = fmaf(u[kk + 3], W[(size_t)(kk + 3) * DD + tid], a3);
    }
    for (; kk < KIN; ++kk) a0 = fmaf(u[kk], W[(size_t)kk * DD + tid], a0);
    float v = a0 + a1 + a2 + a3 + rs * bias[tid];
    y[((size_t)b * NK + i) * DD + tid] = fmaxf(v, 0.f);
}

// GCN tail body: layer2 -> comp -> qc (qc emitted bf16 in Wb-swizzled layout)
__device__ __forceinline__ void gcn_tail_body(
    const float* __restrict__ y1, const float* __restrict__ adj,
    const float* __restrict__ W2, const float* __restrict__ b2,
    const float* __restrict__ Wf, const float* __restrict__ bf,
    const float* __restrict__ Wjc, const float* __restrict__ bjc,
    float* __restrict__ comp, short* __restrict__ qcb,
    int bi, int tid, float* arow, float* u) {
    int b = bi / NK, i = bi % NK;
    if (tid < NK) arow[tid] = adj[((size_t)b * NK + i) * NK + tid];
    __syncthreads();
    {
        float a0 = 0.f, a1 = 0.f;
        for (int j = 0; j < NK; j += 2) {
            a0 = fmaf(arow[j],     y1[((size_t)b * NK + j)     * DD + tid], a0);
            a1 = fmaf(arow[j + 1], y1[((size_t)b * NK + j + 1) * DD + tid], a1);
        }
        u[tid] = a0 + a1;
    }
    float rs = 0.f;
    for (int j = 0; j < NK; ++j) rs += arow[j];
    __syncthreads();
    float a0 = 0.f, a1 = 0.f, a2 = 0.f, a3 = 0.f;
    #pragma unroll 4
    for (int kk = 0; kk < DD; kk += 4) {
        a0 = fmaf(u[kk],     W2[(size_t)kk * DD + tid],       a0);
        a1 = fmaf(u[kk + 1], W2[(size_t)(kk + 1) * DD + tid], a1);
        a2 = fmaf(u[kk + 2], W2[(size_t)(kk + 2) * DD + tid], a2);
        a3 = fmaf(u[kk + 3], W2[(size_t)(kk + 3) * DD + tid], a3);
    }
    float y2 = fmaxf(a0 + a1 + a2 + a3 + rs * b2[tid], 0.f);
    __syncthreads();
    u[tid] = y2;
    __syncthreads();
    a0 = a1 = a2 = a3 = 0.f;
    #pragma unroll 4
    for (int kk = 0; kk < DD; kk += 4) {
        a0 = fmaf(u[kk],     Wf[(size_t)kk * DD + tid],       a0);
        a1 = fmaf(u[kk + 1], Wf[(size_t)(kk + 1) * DD + tid], a1);
        a2 = fmaf(u[kk + 2], Wf[(size_t)(kk + 2) * DD + tid], a2);
        a3 = fmaf(u[kk + 3], Wf[(size_t)(kk + 3) * DD + tid], a3);
    }
    float cv = a0 + a1 + a2 + a3 + bf[tid];
    comp[((size_t)b * NK + i) * DD + tid] = cv;
    __syncthreads();
    u[tid] = fmaxf(cv, 0.f);
    __syncthreads();
    a0 = a1 = a2 = a3 = 0.f;
    #pragma unroll 4
    for (int kk = 0; kk < DD; kk += 4) {
        a0 = fmaf(u[kk],     Wjc[(size_t)kk * DD + tid],       a0);
        a1 = fmaf(u[kk + 1], Wjc[(size_t)(kk + 1) * DD + tid], a1);
        a2 = fmaf(u[kk + 2], Wjc[(size_t)(kk + 2) * DD + tid], a2);
        a3 = fmaf(u[kk + 3], Wjc[(size_t)(kk + 3) * DD + tid], a3);
    }
    float qv = a0 + a1 + a2 + a3 + bjc[tid];
    qcb[(((size_t)b * 32 + (tid >> 3)) * 64 + i) * 8 + (tid & 7)] = f2bf(qv);
}

// ---------------------------------------------------------------------------
// K1: prep (wcvt x2, fusedcvt, zero regions incl. qcb) + gcn_layer0. Grid 1381.
__global__ __launch_bounds__(256) void k1_kernel(
    const float* __restrict__ W_prot, short* __restrict__ Wb1,
    const float* __restrict__ Wjp, short* __restrict__ Wb2,
    const float* __restrict__ fusedM, short* __restrict__ fMb,
    float* __restrict__ zero_region, float* __restrict__ qcb_zero,
    const float* __restrict__ drug_ver, const float* __restrict__ adj,
    const float* __restrict__ W0, const float* __restrict__ b0,
    float* __restrict__ y0) {
    __shared__ float smem[2112];
    int blk = blockIdx.x, tid = threadIdx.x;
    if (blk < 96) {
        int idx = blk * 256 + tid;
        int koct = idx / DD, n = idx % DD;
        bf16x8 v;
        #pragma unroll
        for (int e = 0; e < 8; ++e)
            v[e] = f2bf(W_prot[(size_t)(koct * 8 + e) * DD + n]);
        *reinterpret_cast<bf16x8*>(Wb1 + (size_t)idx * 8) = v;
    } else if (blk < 128) {
        int idx = (blk - 96) * 256 + tid;
        int koct = idx / DD, n = idx % DD;
        bf16x8 v;
        #pragma unroll
        for (int e = 0; e < 8; ++e)
            v[e] = f2bf(Wjp[(size_t)(koct * 8 + e) * DD + n]);
        *reinterpret_cast<bf16x8*>(Wb2 + (size_t)idx * 8) = v;
    } else if (blk < 640) {
        int blk2 = blk - 128;
        int t0 = (blk2 >> 3) * 16;
        int i0 = (blk2 & 7) * 128;
        for (int l = tid; l < 16 * 128; l += 256) {
            int tt = l >> 7, ii = l & 127;
            int t = t0 + tt, i = i0 + ii;
            smem[tt * 132 + ii] = (t < NT && i < NP) ? fusedM[(size_t)t * NP + i] : 0.f;
        }
        __syncthreads();
        int octl = tid >> 4, tl = tid & 15;
        bf16x8 v;
        #pragma unroll
        for (int e = 0; e < 8; ++e)
            v[e] = f2bf(smem[tl * 132 + octl * 8 + e]);
        size_t oct = i0 / 8 + octl;
        *reinterpret_cast<bf16x8*>(fMb + (oct * 1024 + t0 + tl) * 8) = v;
    } else if (blk < 677) {
        int idx = (blk - 640) * 256 + tid;
        if (idx < 48 + B * 600 + B * 300 + B * DD) zero_region[idx] = 0.f;
    } else if (blk < 933) {
        int idx = (blk - 677) * 256 + tid;   // 65536 f32 = qcb full clear
        qcb_zero[idx] = 0.f;
    } else {
        gcn_layer_body(drug_ver, adj, W0, b0, y0, DV, blk - 933, tid,
                       smem, smem + 64);
    }
}

// ---------------------------------------------------------------------------
// K2: prot GEMM (250, full-N tiles) + gcn_layer1 (448).  Grid 698.
__global__ __launch_bounds__(256) void k2_kernel(
    const float* __restrict__ prot_data, const short* __restrict__ Wb1,
    const float* __restrict__ b_prot, float* __restrict__ prot,
    const float* __restrict__ y0, const float* __restrict__ adj,
    const float* __restrict__ W1, const float* __restrict__ b1,
    float* __restrict__ y1) {
    __shared__ float smem[320];
    int blk = blockIdx.x, tid = threadIdx.x;
    if (blk < 250)
        gemm_body256<false>(prot_data, Wb1, b_prot, prot, DP, blk, tid);
    else
        gcn_layer_body(y0, adj, W1, b1, y1, DD, blk - 250, tid, smem, smem + 64);
}

// K3: qp GEMM (250, full-N tiles) + gcn_tail (448).  Grid 698.
__global__ __launch_bounds__(256) void k3_kernel(
    const float* __restrict__ prot, const short* __restrict__ Wb2,
    const float* __restrict__ bjp, float* __restrict__ qp,
    const float* __restrict__ y1, const float* __restrict__ adj,
    const float* __restrict__ W2, const float* __restrict__ b2,
    const float* __restrict__ Wf, const float* __restrict__ bf,
    const float* __restrict__ Wjc, const float* __restrict__ bjc,
    float* __restrict__ comp, short* __restrict__ qcb) {
    __shared__ float smem[320];
    int blk = blockIdx.x, tid = threadIdx.x;
    if (blk < 250)
        gemm_body256<true>(prot, Wb2, bjp, qp, DD, blk, tid);
    else
        gcn_tail_body(y1, adj, W2, b2, Wf, bf, Wjc, bjc, comp, qcb,
                      blk - 250, tid, smem, smem + 64);
}

// ---------------------------------------------------------------------------
// inter via MFMA: logits = qp[b] @ qc[b]^T (1000x56, K=256), sigmoid epilogue,
// writes inter f32, iTb bf16 (incl zero pads), s_bi, moments. Grid 128.
__global__ __launch_bounds__(256) void inter_mfma_kernel(
    const float* __restrict__ qp, const short* __restrict__ qcb,
    const float* __restrict__ prot_inter, const float* __restrict__ exist,
    float* __restrict__ inter, float* __restrict__ s_bi,
    short* __restrict__ iTb, float* __restrict__ accums) {
    __shared__ float wred[4][4];
    int blk = blockIdx.x;
    int b = blk >> 4, mt = blk & 15;
    int tid = threadIdx.x;
    int lane = tid & 63, w = tid >> 6;
    int m0 = mt * 64 + w * 16;
    int lrow = lane & 15, lk = lane >> 4;
    f32x4 acc[4] = {{0.f,0.f,0.f,0.f},{0.f,0.f,0.f,0.f},
                    {0.f,0.f,0.f,0.f},{0.f,0.f,0.f,0.f}};
    int rowi = m0 + lrow;
    int rowc = (rowi < NP) ? rowi : (NP - 1);
    const float* arow = qp + ((size_t)b * NP + rowc) * DD + lk * 8;
    f32x4 a0 = *reinterpret_cast<const f32x4*>(arow);
    f32x4 a1 = *reinterpret_cast<const f32x4*>(arow + 4);
    for (int k0 = 0; k0 < DD; k0 += 32) {
        f32x4 c0 = a0, c1 = a1;
        if (k0 + 32 < DD) {
            a0 = *reinterpret_cast<const f32x4*>(arow + k0 + 32);
            a1 = *reinterpret_cast<const f32x4*>(arow + k0 + 36);
        }
        bf16x8 af;
        #pragma unroll
        for (int e = 0; e < 4; ++e) {
            af[e] = f2bf(c0[e]); af[4 + e] = f2bf(c1[e]);
        }
        const short* bb = qcb + (((size_t)b * 32 + (k0 >> 3) + lk) * 64 + lrow) * 8;
        #pragma unroll
        for (int nt = 0; nt < 4; ++nt) {
            bf16x8 bf = *reinterpret_cast<const bf16x8*>(bb + nt * 128);
            acc[nt] = __builtin_amdgcn_mfma_f32_16x16x32_bf16(af, bf, acc[nt], 0, 0, 0);
        }
    }
    float ex = exist[b];
    float aV = 0.f, aA = 0.f, aC = 0.f, aD = 0.f;
    float rowsq[4] = {0.f, 0.f, 0.f, 0.f};
    #pragma unroll
    for (int nt = 0; nt < 4; ++nt) {
        int j = nt * 16 + lrow;
        bool jv = (j < NK);
        #pragma unroll
        for (int r = 0; r < 4; ++r) {
            int i = m0 + lk * 4 + r;
            bool iv = (i < NP);
            float v = 0.f, lab = 0.f;
            if (jv) {
                if (iv) {
                    v = 1.f / (1.f + __expf(-acc[nt][r]));
                    lab = ex * prot_inter[((size_t)b * NP + i) * NK + j];
                    inter[((size_t)b * NP + i) * NK + j] = v;
                }
                iTb[(((size_t)(i >> 3) * 448 + b * NK + j) << 3) + (i & 7)] = f2bf(v);
            }
            aV += v; aA += v * v; aC += v * lab; aD += lab * lab;
            rowsq[r] += v * v;
        }
    }
    #pragma unroll
    for (int r = 0; r < 4; ++r) {
        float rs = rowsq[r];
        rs += __shfl_xor(rs, 1); rs += __shfl_xor(rs, 2);
        rs += __shfl_xor(rs, 4); rs += __shfl_xor(rs, 8);
        int i = m0 + lk * 4 + r;
        if (lrow == 0 && i < NP) s_bi[(size_t)b * NP + i] = rs;
    }
    #pragma unroll
    for (int off = 32; off; off >>= 1) {
        aV += __shfl_down(aV, off);
        aA += __shfl_down(aA, off);
        aC += __shfl_down(aC, off);
        aD += __shfl_down(aD, off);
    }
    if (lane == 0) {
        wred[w][0] = aV; wred[w][1] = aA; wred[w][2] = aC; wred[w][3] = aD;
    }
    __syncthreads();
    if (tid < 4) {
        float s = wred[0][tid] + wred[1][tid] + wred[2][tid] + wred[3][tid];
        atomicAdd(&accums[tid * 8 + b], s);
    }
}

// ---------------------------------------------------------------------------
// K5: cp_partial (1000) + fused MFMA (112) + group (2000).  Grid 3112.
__global__ __launch_bounds__(256) void k5_kernel(
    const float* __restrict__ prot, const float* __restrict__ comp,
    const float* __restrict__ inter, float* __restrict__ cp,
    const short* __restrict__ iTb, const short* __restrict__ fMb,
    float* __restrict__ fusedAbs,
    const float* __restrict__ contacts, const float* __restrict__ s_bi,
    const float* __restrict__ accums, float* __restrict__ groupv) {
    __shared__ float irow[8][NK];
    __shared__ float sb[8];
    int blk = blockIdx.x, tid = threadIdx.x;
    if (blk < 1000) {
        int b = blk / 125, chunk = blk % 125;
        int d = tid;
        float creg[NK];
        #pragma unroll
        for (int k = 0; k < NK; ++k)
            creg[k] = comp[((size_t)b * NK + k) * DD + d];
        for (int l = tid; l < 8 * NK; l += 256) {
            int ii = l / NK, k = l % NK;
            irow[ii][k] = inter[((size_t)b * NP + chunk * 8 + ii) * NK + k];
        }
        const float C2LOG2E = 2.8853900817779268f;
        float p2l[8];
        #pragma unroll
        for (int ii = 0; ii < 8; ++ii)
            p2l[ii] = C2LOG2E * prot[((size_t)b * NP + chunk * 8 + ii) * DD + d];
        __syncthreads();
        float acc0 = 0.f, acc1 = 0.f;
        #pragma unroll 1
        for (int ii = 0; ii < 8; ++ii) {
            float p = p2l[ii];
            #pragma unroll
            for (int k = 0; k < NK; k += 2) {
                float e0 = __builtin_amdgcn_exp2f(p * creg[k]);
                float e1 = __builtin_amdgcn_exp2f(p * creg[k + 1]);
                float r0 = __builtin_amdgcn_rcpf(e0 + 1.f);
                float r1 = __builtin_amdgcn_rcpf(e1 + 1.f);
                acc0 = fmaf(fmaf(-2.f, r0, 1.f), irow[ii][k],     acc0);
                acc1 = fmaf(fmaf(-2.f, r1, 1.f), irow[ii][k + 1], acc1);
            }
        }
        atomicAdd(&cp[(size_t)b * DD + d], acc0 + acc1);
    } else if (blk < 1112) {
        int fblk = blk - 1000;
        int mb = fblk % 14, nb = fblk / 14;
        int lane = tid & 63, w = tid >> 6;
        if (tid < 8) sb[tid] = 0.f;
        __syncthreads();
        int m0 = mb * 32 + (w >> 1) * 16;
        int n0 = nb * 128 + (w & 1) * 64;
        int lrow = lane & 15, lk = lane >> 4;
        f32x4 acc[4] = {{0.f,0.f,0.f,0.f},{0.f,0.f,0.f,0.f},
                        {0.f,0.f,0.f,0.f},{0.f,0.f,0.f,0.f}};
        for (int koct0 = 0; koct0 < 128; koct0 += 4) {
            int koct = koct0 + lk;
            bf16x8 af = *reinterpret_cast<const bf16x8*>(
                iTb + ((size_t)koct * 448 + m0 + lrow) * 8);
            const short* bb = fMb + ((size_t)koct * 1024 + n0 + lrow) * 8;
            #pragma unroll
            for (int nt = 0; nt < 4; ++nt) {
                bf16x8 bf = *reinterpret_cast<const bf16x8*>(bb + nt * 128);
                acc[nt] = __builtin_amdgcn_mfma_f32_16x16x32_bf16(af, bf, acc[nt], 0, 0, 0);
            }
        }
        #pragma unroll
        for (int r = 0; r < 4; ++r) {
            float part = fabsf(acc[0][r]) + fabsf(acc[1][r]) +
                         fabsf(acc[2][r]) + fabsf(acc[3][r]);
            #pragma unroll
            for (int off = 1; off < 16; off <<= 1)
                part += __shfl_xor(part, off);
            if (lrow == 0) {
                int row = m0 + lk * 4 + r;
                atomicAdd(&sb[row / NK], part);
            }
        }
        __syncthreads();
        if (tid < 8 && sb[tid] != 0.f) atomicAdd(&fusedAbs[tid], sb[tid]);
    } else {
        int w = tid >> 6, lane = tid & 63;
        int gk = (blk - 1112) * 4 + w;
        int b = gk / NP;
        const f32x4* row4 = reinterpret_cast<const f32x4*>(
            contacts + (size_t)gk * NP);
        const f32x4* sv4 = reinterpret_cast<const f32x4*>(s_bi + (size_t)b * NP);
        f32x4 z = {0.f, 0.f, 0.f, 0.f};
        f32x4 c0 = row4[lane];
        f32x4 c1 = row4[lane + 64];
        f32x4 c2 = row4[lane + 128];
        f32x4 c3 = z, s3 = z;
        f32x4 s0 = sv4[lane];
        f32x4 s1 = sv4[lane + 64];
        f32x4 s2 = sv4[lane + 128];
        if (lane + 192 < 250) { c3 = row4[lane + 192]; s3 = sv4[lane + 192]; }
        float g0 = 0.f, g1 = 0.f, g2 = 0.f, g3 = 0.f;
        #pragma unroll
        for (int e = 0; e < 4; ++e) {
            g0 = fmaf(c0[e], s0[e], g0);
            g1 = fmaf(c1[e], s1[e], g1);
            g2 = fmaf(c2[e], s2[e], g2);
            g3 = fmaf(c3[e], s3[e], g3);
        }
        float r0 = (c0[0] + c0[1]) + (c0[2] + c0[3]);
        float r1 = (c1[0] + c1[1]) + (c1[2] + c1[3]);
        float r2 = (c2[0] + c2[1]) + (c2[2] + c2[3]);
        float r3 = (c3[0] + c3[1]) + (c3[2] + c3[3]);
        float g = (g0 + g1) + (g2 + g3);
        float rs = (r0 + r1) + (r2 + r3);
        #pragma unroll
        for (int off = 32; off; off >>= 1) {
            g += __shfl_down(g, off);
            rs += __shfl_down(rs, off);
        }
        if (lane == 0) {
            float val;
            if (g == 0.f) val = sqrtf(1e10f) * sqrtf(rs);
            else          val = sqrtf(g) / accums[b] * sqrtf(rs);
            groupv[gk] = val;
        }
    }
}

// ---------------------------------------------------------------------------
// fc1 with inline conv/pool.
__global__ __launch_bounds__(256) void fc1_conv_kernel(
    const float* __restrict__ cp, const float* __restrict__ accums,
    const float* __restrict__ conv_w, const float* __restrict__ conv_b,
    const float* __restrict__ W, float* __restrict__ raw) {
    const int N = 600, kchunk = 128;
    int t = threadIdx.x;
    int ol = t & 63;
    int o = blockIdx.x * 64 + ol;
    int w = t >> 6;
    int kbeg = blockIdx.y * kchunk;
    __shared__ float xS[B][258];
    __shared__ float sin_[B][128];
    for (int l = t; l < B * DD; l += 256) {
        int b = l >> 8, d = l & 255;
        xS[b][d + 1] = cp[(size_t)b * DD + d] / accums[b];
    }
    if (t < B) { xS[t][0] = 0.f; xS[t][257] = 0.f; }
    __syncthreads();
    for (int l = t; l < B * kchunk; l += 256) {
        int b = l >> 7, kl = l & 127;
        int kg = kbeg + kl;
        int oo = kg >> 5, p = kg & 31;
        float w0 = conv_w[oo * 4 + 0], w1 = conv_w[oo * 4 + 1];
        float w2 = conv_w[oo * 4 + 2], w3 = conv_w[oo * 4 + 3];
        float cb = conv_b[oo];
        float m = -INFINITY;
        #pragma unroll
        for (int q = 0; q < 4; ++q) {
            int base = (p * 4 + q) * 2;
            float acc = cb;
            acc = fmaf(xS[b][base + 0], w0, acc);
            acc = fmaf(xS[b][base + 1], w1, acc);
            acc = fmaf(xS[b][base + 2], w2, acc);
            acc = fmaf(xS[b][base + 3], w3, acc);
            acc = (acc > 0.f) ? acc : 0.1f * acc;
            m = fmaxf(m, acc);
        }
        sin_[b][kl] = m;
    }
    __syncthreads();
    float acc[B];
    #pragma unroll
    for (int b = 0; b < B; ++b) acc[b] = 0.f;
    for (int k = kbeg + w; k < kbeg + kchunk; k += 4) {
        float wv = W[(size_t)k * N + o];
        int kl = k - kbeg;
        #pragma unroll
        for (int b = 0; b < B; ++b)
            acc[b] = fmaf(sin_[b][kl], wv, acc[b]);
    }
    __shared__ float red[4][64][B];
    #pragma unroll
    for (int b = 0; b < B; ++b) red[w][ol][b] = acc[b];
    __syncthreads();
    for (int p = t; p < 64 * B; p += 256) {
        int oo = p / B, b = p % B;
        int o2 = blockIdx.x * 64 + oo;
        float s = red[0][oo][b] + red[1][oo][b] + red[2][oo][b] + red[3][oo][b];
        atomicAdd(&raw[(size_t)b * N + o2], s);
    }
}

// ---------------------------------------------------------------------------
// fc2 partial: staging applies bias+leaky to raw1.
__global__ __launch_bounds__(256) void fc2_kernel(
    const float* __restrict__ raw1, const float* __restrict__ b_r1,
    const float* __restrict__ W, float* __restrict__ raw2) {
    const int K = 600, N = 300, kchunk = 75;
    int t = threadIdx.x;
    int ol = t & 63;
    int o = blockIdx.x * 64 + ol;
    int w = t >> 6;
    int kbeg = blockIdx.y * kchunk;
    __shared__ float sin_[B][128];
    for (int l = t; l < B * kchunk; l += 256) {
        int b = l / kchunk, k = l % kchunk;
        float v = raw1[(size_t)b * K + kbeg + k] + b_r1[kbeg + k];
        v = (v > 0.f) ? v : 0.1f * v;
        sin_[b][k] = v;
    }
    __syncthreads();
    float acc[B];
    #pragma unroll
    for (int b = 0; b < B; ++b) acc[b] = 0.f;
    if (o < N) {
        for (int k = kbeg + w; k < kbeg + kchunk; k += 4) {
            float wv = W[(size_t)k * N + o];
            int kl = k - kbeg;
            #pragma unroll
            for (int b = 0; b < B; ++b)
                acc[b] = fmaf(sin_[b][kl], wv, acc[b]);
        }
    }
    __shared__ float red[4][64][B];
    #pragma unroll
    for (int b = 0; b < B; ++b) red[w][ol][b] = acc[b];
    __syncthreads();
    for (int p = t; p < 64 * B; p += 256) {
        int oo = p / B, b = p % B;
        int o2 = blockIdx.x * 64 + oo;
        if (o2 < N) {
            float s = red[0][oo][b] + red[1][oo][b] + red[2][oo][b] + red[3][oo][b];
            atomicAdd(&raw2[(size_t)b * N + o2], s);
        }
    }
}

// ---------------------------------------------------------------------------
// final: inline fc3 + groupv sum + assembly.
__global__ __launch_bounds__(256) void final_kernel(
    const float* __restrict__ accums, const float* __restrict__ groupv,
    const float* __restrict__ raw2, const float* __restrict__ b_r2,
    const float* __restrict__ W3, const float* __restrict__ b3,
    const float* __restrict__ label, float* __restrict__ out) {
    int tid = threadIdx.x;
    __shared__ float affnS[8];
    {
        int b = tid >> 5, k0 = tid & 31;
        float acc = 0.f;
        for (int k = k0; k < 300; k += 32) {
            float v = raw2[(size_t)b * 300 + k] + b_r2[k];
            v = (v > 0.f) ? v : 0.1f * v;
            acc = fmaf(v, W3[k], acc);
        }
        #pragma unroll
        for (int off = 16; off; off >>= 1) acc += __shfl_down(acc, off);
        if (k0 == 0) affnS[b] = acc + b3[0];
    }
    float s = 0.f;
    for (int l = tid; l < B * NP; l += 256) s += groupv[l];
    __shared__ float r[256];
    r[tid] = s;
    __syncthreads();
    for (int st = 128; st; st >>= 1) {
        if (tid < st) r[tid] += r[tid + st];
        __syncthreads();
    }
    if (tid == 0) {
        float gtot = r[0];
        float l0 = 0.f, l1 = 0.f, l2 = 0.f;
        for (int b = 0; b < B; ++b) {
            float S = accums[b];
            float A = accums[8 + b], C = accums[16 + b], D = accums[24 + b];
            float fA = accums[32 + b];
            l0 += 1.f + fA / S;
            float bind = A / (S * S) - 2.f * C / S + D;
            l1 += sqrtf(fmaxf(bind, 0.f));
            float dd = affnS[b] - label[b];
            l2 += dd * dd;
        }
        out[0] = (l0 + gtot + l1 + l2) * 0.125f;
    }
}

// ---------------------------------------------------------------------------
extern "C" void kernel_launch(void* const* d_in, const int* in_sizes, int n_in,
                              void* d_out, int out_size, void* d_ws, size_t ws_size,
                              hipStream_t stream) {
    const float* prot_data   = (const float*)d_in[0];
    const float* drug_ver    = (const float*)d_in[1];
    const float* drug_adj    = (const float*)d_in[2];
    const float* contacts    = (const float*)d_in[3];
    const float* prot_inter  = (const float*)d_in[4];
    const float* exist       = (const float*)d_in[5];
    const float* label       = (const float*)d_in[6];
    const float* fused       = (const float*)d_in[7];
    const float* W_prot      = (const float*)d_in[8];
    const float* b_prot      = (const float*)d_in[9];
    const float* gcn_W0      = (const float*)d_in[10];
    const float* gcn_b0      = (const float*)d_in[11];
    const float* gcn_W1      = (const float*)d_in[12];
    const float* gcn_b1      = (const float*)d_in[13];
    const float* gcn_W2      = (const float*)d_in[14];
    const float* gcn_b2      = (const float*)d_in[15];
    const float* gcn_Wf      = (const float*)d_in[16];
    const float* gcn_bf      = (const float*)d_in[17];
    const float* Wjp         = (const float*)d_in[18];
    const float* bjp         = (const float*)d_in[19];
    const float* Wjc         = (const float*)d_in[20];
    const float* bjc         = (const float*)d_in[21];
    const float* conv_w      = (const float*)d_in[22];
    const float* conv_b      = (const float*)d_in[23];
    const float* W_r1        = (const float*)d_in[24];
    const float* b_r1        = (const float*)d_in[25];
    const float* W_r2        = (const float*)d_in[26];
    const float* b_r2        = (const float*)d_in[27];
    const float* W_r3        = (const float*)d_in[28];
    const float* b_r3        = (const float*)d_in[29];

    float* ws = (float*)d_ws;
    size_t off = 0;
    auto alloc = [&](size_t n) { float* p = ws + off; off += n; return p; };
    float* prot     = alloc((size_t)B * NP * DD);
    float* qp       = alloc((size_t)B * NP * DD);
    float* tbuf     = alloc((size_t)B * NK * DD);   // y0; +ybuf = iTb alias
    float* ybuf     = alloc((size_t)B * NK * DD);   // y1
    float* comp     = alloc((size_t)B * NK * DD);
    float* qcbF     = alloc((size_t)65536);         // qcb bf16 [8][32][64][8]
    float* inter    = alloc((size_t)B * NP * NK);
    float* s_bi     = alloc((size_t)B * NP);
    float* groupv   = alloc((size_t)B * NP);
    short* Wb1      = (short*)alloc((DP / 8) * DD * 8 / 2);
    short* Wb2      = (short*)alloc((DD / 8) * DD * 8 / 2);
    short* fMb      = (short*)alloc((size_t)128 * 1024 * 8 / 2);
    // zero region: accums(48) + raw1(4800) + raw2(2400) + cp(2048)
    float* accums   = alloc(48);
    float* raw1     = alloc((size_t)B * 600);
    float* raw2     = alloc((size_t)B * 300);
    float* cp       = alloc((size_t)B * DD);

    short* qcb = (short*)qcbF;
    // iTb[128][448][8] bf16 aliases tbuf+ybuf (dead after K3)
    short* iTb = (short*)tbuf;
    (void)ybuf;

    // 1. prep (+gcn layer0)
    k1_kernel<<<1381, 256, 0, stream>>>(W_prot, Wb1, Wjp, Wb2, fused, fMb,
                                        accums, qcbF, drug_ver, drug_adj,
                                        gcn_W0, gcn_b0, tbuf);

    // 2. prot GEMM (full-N tiles) + gcn layer1
    k2_kernel<<<698, 256, 0, stream>>>(prot_data, Wb1, b_prot, prot,
                                       tbuf, drug_adj, gcn_W1, gcn_b1, ybuf);

    // 3. qp GEMM (full-N tiles) + gcn tail (emits qcb bf16)
    k3_kernel<<<698, 256, 0, stream>>>(prot, Wb2, bjp, qp,
                                       ybuf, drug_adj, gcn_W2, gcn_b2,
                                       gcn_Wf, gcn_bf, Wjc, bjc, comp, qcb);

    // 4. inter via MFMA (+ moments, s_bi, iTb)
    inter_mfma_kernel<<<128, 256, 0, stream>>>(
        qp, qcb, prot_inter, exist, inter, s_bi, iTb, accums);

    // 5. cp partial + fused MFMA + group
    k5_kernel<<<3112, 256, 0, stream>>>(prot, comp, inter, cp,
                                        iTb, fMb, accums + 32,
                                        contacts, s_bi, accums, groupv);

    // 6. fc1 with inline conv/pool
    fc1_conv_kernel<<<dim3(10, 16), 256, 0, stream>>>(
        cp, accums, conv_w, conv_b, W_r1, raw1);

    // 7. fc2
    fc2_kernel<<<dim3(5, 8), 256, 0, stream>>>(raw1, b_r1, W_r2, raw2);

    // 8. final loss
    final_kernel<<<1, 256, 0, stream>>>(accums, groupv, raw2, b_r2,
                                        W_r3, b_r3, label, (float*)d_out);
}